// Round 3
// baseline (1821.599 us; speedup 1.0000x reference)
//
#include <hip/hip_runtime.h>
#include <math.h>

typedef _Float16 f16x8 __attribute__((ext_vector_type(8)));
typedef _Float16 f16x4 __attribute__((ext_vector_type(4)));
typedef float    f32x4 __attribute__((ext_vector_type(4)));
typedef unsigned long long u64;
typedef unsigned int u32;

// ---------------- conversion f32 -> f16 ----------------
__global__ __launch_bounds__(256) void k_f32_to_f16(const float* __restrict__ src,
                                                    _Float16* __restrict__ dst, int n4) {
  int i = blockIdx.x * 256 + threadIdx.x;
  int stride = gridDim.x * 256;
  for (; i < n4; i += stride) {
    float4 v = ((const float4*)src)[i];
    f16x4 o;
    o.x = (_Float16)v.x; o.y = (_Float16)v.y; o.z = (_Float16)v.z; o.w = (_Float16)v.w;
    ((f16x4*)dst)[i] = o;
  }
}

// ---------------- embedding + relu ----------------
__global__ __launch_bounds__(256) void k_embed(const int* __restrict__ dec,
                                               const float* __restrict__ emb,
                                               float* __restrict__ xf,
                                               _Float16* __restrict__ xh) {
  int i = blockIdx.x * 256 + threadIdx.x;  // 524288 float4 units
  int r = i >> 8;
  int c4 = i & 255;
  int b = r & 31, t = r >> 5;
  int tok = dec[b * 64 + t];
  float4 v = ((const float4*)(emb + (size_t)tok * 1024))[c4];
  v.x = fmaxf(v.x, 0.f); v.y = fmaxf(v.y, 0.f); v.z = fmaxf(v.z, 0.f); v.w = fmaxf(v.w, 0.f);
  ((float4*)(xf + (size_t)r * 1024))[c4] = v;
  f16x4 o;
  o.x = (_Float16)v.x; o.y = (_Float16)v.y; o.z = (_Float16)v.z; o.w = (_Float16)v.w;
  ((f16x4*)(xh + (size_t)r * 1024))[c4] = o;
}

// ---------------- state init (+ barrier reset) ----------------
__global__ __launch_bounds__(256) void k_init(const float* __restrict__ h0, const float* __restrict__ c0,
                                              float* __restrict__ c,
                                              _Float16* __restrict__ h0B, _Float16* __restrict__ h1B,
                                              int* __restrict__ cnt, int* __restrict__ gen) {
  int i = blockIdx.x * 256 + threadIdx.x;  // 65536
  float hv = h0[i];
  c[i] = c0[i];
  if (i < 32768) h0B[i] = (_Float16)hv;
  else           h1B[i - 32768] = (_Float16)hv;
  if (i == 0) { *cnt = 0; *gen = 0; }
}

// ---------------- tiled MFMA GEMM: C[M,N] = A[M,1024] * B[N,1024]^T ----------------
template <int MODE>
__global__ __launch_bounds__(256) void k_gemm(const _Float16* __restrict__ A,
                                              const _Float16* __restrict__ Bm,
                                              const float* __restrict__ bias0,
                                              const float* __restrict__ bias1,
                                              float* __restrict__ C) {
  __shared__ _Float16 As[128 * 32];
  __shared__ _Float16 Bs[128 * 32];
  const int tid = threadIdx.x;
  const int lane = tid & 63;
  const int w = tid >> 6;
  const int wm = w >> 1, wn = w & 1;
  const _Float16* Ab = A + (size_t)blockIdx.y * 128 * 1024;
  const _Float16* Bb = Bm + (size_t)blockIdx.x * 128 * 1024;
  f32x4 acc[4][4] = {};
  for (int kc = 0; kc < 32; ++kc) {
#pragma unroll
    for (int ii = 0; ii < 2; ++ii) {
      int idx = tid + ii * 256;
      int row = idx >> 2, kb = idx & 3;
      int gofs = row * 1024 + kc * 32 + kb * 8;
      int sofs = row * 32 + ((kb ^ (row & 3)) * 8);
      *(f16x8*)(As + sofs) = *(const f16x8*)(Ab + gofs);
      *(f16x8*)(Bs + sofs) = *(const f16x8*)(Bb + gofs);
    }
    __syncthreads();
    const int kq = ((lane >> 4) ^ (lane & 3)) * 8;
    f16x8 af[4], bfv[4];
#pragma unroll
    for (int mf = 0; mf < 4; ++mf) {
      int row = wm * 64 + mf * 16 + (lane & 15);
      af[mf] = *(const f16x8*)(As + row * 32 + kq);
    }
#pragma unroll
    for (int nf = 0; nf < 4; ++nf) {
      int row = wn * 64 + nf * 16 + (lane & 15);
      bfv[nf] = *(const f16x8*)(Bs + row * 32 + kq);
    }
#pragma unroll
    for (int mf = 0; mf < 4; ++mf)
#pragma unroll
      for (int nf = 0; nf < 4; ++nf)
        acc[mf][nf] = __builtin_amdgcn_mfma_f32_16x16x32_f16(af[mf], bfv[nf], acc[mf][nf], 0, 0, 0);
    __syncthreads();
  }
  const int rl = (lane >> 4) * 4;
#pragma unroll
  for (int mf = 0; mf < 4; ++mf) {
#pragma unroll
    for (int nf = 0; nf < 4; ++nf) {
#pragma unroll
      for (int j = 0; j < 4; ++j) {
        int m = wm * 64 + mf * 16 + rl + j;
        int n = wn * 64 + nf * 16 + (lane & 15);
        int rg = blockIdx.y * 128 + m;
        int ng = blockIdx.x * 128 + n;
        float v = acc[mf][nf][j];
        if constexpr (MODE == 0) {
          C[(size_t)rg * 8192 + ng] = v + bias0[ng] + bias1[ng];
        } else {
          int tt = rg >> 5, b = rg & 31;
          C[(size_t)(b * 64 + tt) * 32000 + ng] = v + bias0[ng];
        }
      }
    }
  }
}

// ---------------- device-scope generation barrier ----------------
// Data visibility contract: cross-block state is exchanged ONLY via agent-scope
// atomic ops (coherent point), which are drained (vmcnt) by __syncthreads before
// arrival. No __threadfence() -> no L2 invalidate -> weights stay L2-resident.
__device__ __forceinline__ void gbar(int* cnt, int* gen, int nblk) {
  __syncthreads();
  if (threadIdx.x == 0) {
    int g = __hip_atomic_load(gen, __ATOMIC_RELAXED, __HIP_MEMORY_SCOPE_AGENT);
    int a = __hip_atomic_fetch_add(cnt, 1, __ATOMIC_ACQ_REL, __HIP_MEMORY_SCOPE_AGENT);
    if (a == nblk - 1) {
      __hip_atomic_store(cnt, 0, __ATOMIC_RELAXED, __HIP_MEMORY_SCOPE_AGENT);
      __hip_atomic_fetch_add(gen, 1, __ATOMIC_RELEASE, __HIP_MEMORY_SCOPE_AGENT);
    } else {
      while (__hip_atomic_load(gen, __ATOMIC_RELAXED, __HIP_MEMORY_SCOPE_AGENT) == g)
        __builtin_amdgcn_s_sleep(2);
    }
  }
  __syncthreads();
}

// ---------------- persistent pipelined LSTM ----------------
// 128 blocks resident for the whole recurrence. Phase p: blocks 0..63 = layer0
// of t=p; blocks 64..127 = layer1 of t=p-1. One gbar between phases. Each block
// re-reads the SAME weight rows every phase from its own XCD's L2 (hot).
__global__ __launch_bounds__(256) void k_lstm_persist(
    const _Float16* __restrict__ Wih_h, const _Float16* __restrict__ Whh_h,
    const float* __restrict__ gx, const float* __restrict__ x_f,
    float* __restrict__ c_f,
    _Float16* __restrict__ h0A, _Float16* __restrict__ h0B,
    _Float16* __restrict__ h1A, _Float16* __restrict__ h1B,
    float* __restrict__ ipfA, float* __restrict__ ipfB,
    float* __restrict__ outs_f, _Float16* __restrict__ outs_h,
    float* __restrict__ outHT, float* __restrict__ outCT,
    int* cnt, int* gen) {
  const int role = blockIdx.x >> 6;
  const int jb = blockIdx.x & 63;
  const int u0 = jb * 16;
  const int tid = threadIdx.x;
  const int lane = tid & 63;
  const int w = tid >> 6;
  const int col = lane & 15;
  const int kq = (lane >> 4) * 8;

  __shared__ _Float16 As[2][32 * 264];
  __shared__ float gs[32][66];

  // fixed per-block weight row pointers (stay hot in this CU's XCD L2)
  const _Float16* bp0;
  const _Float16* bp1 = nullptr;
  if (role == 0) {
    bp0 = Whh_h + (size_t)(w * 1024 + u0 + col) * 1024 + kq;
  } else {
    bp0 = Wih_h + (size_t)(4096 + w * 1024 + u0 + col) * 1024 + kq;
    bp1 = Whh_h + (size_t)(4096 + w * 1024 + u0 + col) * 1024 + kq;
  }
  const int NC = role ? 8 : 4;
  float* cst = c_f + role * 32768;
  const float* gxbase = gx + (role ? 4096 : 0);

  for (int p = 0; p <= 64; ++p) {
    const bool active = !(role == 0 && p == 64) && !(role == 1 && p == 0);
    if (active) {
      const int t = (role == 0) ? p : p - 1;
      const _Float16 *h0r, *h1r;
      _Float16 *h0w, *h1w;
      const float* ipfr; float* ipfw;
      if (p & 1) { h0r = h0A; h0w = h0B; ipfr = ipfA; ipfw = ipfB; h1r = h1B; h1w = h1A; }
      else       { h0r = h0B; h0w = h0A; ipfr = ipfB; ipfw = ipfA; h1r = h1A; h1w = h1B; }

      auto stage_issue = [&](int c, u64* regs) {
#pragma unroll
        for (int q = 0; q < 4; ++q) {
          int id = q * 256 + tid;
          int row = id >> 5, k8 = id & 31;
          int k = c * 256 + k8 * 8;
          const _Float16* s = (k < 1024) ? (h0r + row * 1024 + k)
                                         : (h1r + row * 1024 + (k - 1024));
          const u64* qq = (const u64*)s;
          regs[2 * q]     = __hip_atomic_load(qq,     __ATOMIC_RELAXED, __HIP_MEMORY_SCOPE_AGENT);
          regs[2 * q + 1] = __hip_atomic_load(qq + 1, __ATOMIC_RELAXED, __HIP_MEMORY_SCOPE_AGENT);
        }
      };
      auto stage_write = [&](int c, const u64* regs) {
#pragma unroll
        for (int q = 0; q < 4; ++q) {
          int id = q * 256 + tid;
          int row = id >> 5, k8 = id & 31;
          *(u64*)(&As[c & 1][row * 264 + k8 * 8])     = regs[2 * q];
          *(u64*)(&As[c & 1][row * 264 + k8 * 8 + 4]) = regs[2 * q + 1];
        }
      };

      f32x4 acc0 = {}, acc1 = {};
      u64 sreg[8];
      stage_issue(0, sreg);
      stage_write(0, sreg);
      __syncthreads();
      for (int c = 0; c < NC; ++c) {
        f16x8 bf[8];
#pragma unroll
        for (int kk = 0; kk < 8; ++kk) {
          int kc = c * 8 + kk;
          const _Float16* bsrc = (kc >= 32) ? (bp1 + (size_t)(kc - 32) * 32)
                                            : (bp0 + (size_t)kc * 32);
          bf[kk] = *(const f16x8*)bsrc;
        }
        if (c + 1 < NC) stage_issue(c + 1, sreg);
#pragma unroll
        for (int kk = 0; kk < 8; ++kk) {
          f16x8 a0 = *(const f16x8*)(&As[c & 1][(col) * 264 + kk * 32 + kq]);
          f16x8 a1 = *(const f16x8*)(&As[c & 1][(16 + col) * 264 + kk * 32 + kq]);
          acc0 = __builtin_amdgcn_mfma_f32_16x16x32_f16(a0, bf[kk], acc0, 0, 0, 0);
          acc1 = __builtin_amdgcn_mfma_f32_16x16x32_f16(a1, bf[kk], acc1, 0, 0, 0);
        }
        if (c + 1 < NC) stage_write(c + 1, sreg);
        __syncthreads();
      }

      const int rl = (lane >> 4) * 4;
#pragma unroll
      for (int j = 0; j < 4; ++j) {
        gs[rl + j][w * 16 + col] = acc0[j];
        gs[16 + rl + j][w * 16 + col] = acc1[j];
      }
      __syncthreads();

      // fused cell: 256 threads x 2 adjacent units
      {
        int b = tid >> 3;
        int ul = (tid & 7) << 1;
        int u = u0 + ul;
        const float* gxr = gxbase + (size_t)(t * 32 + b) * 8192;
        float hi2[2], ci2[2];
#pragma unroll
        for (int q = 0; q < 2; ++q) {
          int uq = u + q, ulq = ul + q;
          float ig = gs[b][ulq]      + gxr[uq];
          float fg = gs[b][16 + ulq] + gxr[1024 + uq];
          float gg = gs[b][32 + ulq] + gxr[2048 + uq];
          float og = gs[b][48 + ulq] + gxr[3072 + uq];
          float cp = cst[b * 1024 + uq];
          float si = 1.f / (1.f + expf(-ig));
          float sf = 1.f / (1.f + expf(-fg));
          float so = 1.f / (1.f + expf(-og));
          float ci = sf * cp + si * tanhf(gg);
          float hi = so * tanhf(ci);
          cst[b * 1024 + uq] = ci;
          ci2[q] = ci; hi2[q] = hi;
        }
        if (t == 63) {
          outHT[role * 32768 + b * 1024 + u]     = hi2[0];
          outHT[role * 32768 + b * 1024 + u + 1] = hi2[1];
          outCT[role * 32768 + b * 1024 + u]     = ci2[0];
          outCT[role * 32768 + b * 1024 + u + 1] = ci2[1];
        }
        if (role == 0) {
          union { _Float16 h[2]; u32 v; } ph;
          ph.h[0] = (_Float16)hi2[0]; ph.h[1] = (_Float16)hi2[1];
          __hip_atomic_store((u32*)(h0w + b * 1024 + u), ph.v, __ATOMIC_RELAXED, __HIP_MEMORY_SCOPE_AGENT);
          const float* xr = x_f + (size_t)(t * 32 + b) * 1024;
          union { float f[2]; u64 v; } pi;
          pi.f[0] = hi2[0] + xr[u]; pi.f[1] = hi2[1] + xr[u + 1];
          __hip_atomic_store((u64*)(ipfw + b * 1024 + u), pi.v, __ATOMIC_RELAXED, __HIP_MEMORY_SCOPE_AGENT);
        } else {
          union { _Float16 h[2]; u32 v; } ph;
          ph.h[0] = (_Float16)hi2[0]; ph.h[1] = (_Float16)hi2[1];
          __hip_atomic_store((u32*)(h1w + b * 1024 + u), ph.v, __ATOMIC_RELAXED, __HIP_MEMORY_SCOPE_AGENT);
          union { float f[2]; u64 v; } pr;
          pr.v = __hip_atomic_load((const u64*)(ipfr + b * 1024 + u), __ATOMIC_RELAXED, __HIP_MEMORY_SCOPE_AGENT);
          float ro0 = hi2[0] + pr.f[0];
          float ro1 = hi2[1] + pr.f[1];
          float* of = outs_f + (size_t)(t * 32 + b) * 1024 + u;
          of[0] = ro0; of[1] = ro1;
          union { _Float16 h[2]; u32 v; } po;
          po.h[0] = (_Float16)ro0; po.h[1] = (_Float16)ro1;
          *(u32*)(outs_h + (size_t)(t * 32 + b) * 1024 + u) = po.v;
        }
      }
    }
    gbar(cnt, gen, 128);
  }
}

// ---------------- batched dot-attention + softmax ----------------
__global__ __launch_bounds__(256) void k_attn(const float* __restrict__ outs,
                                              const float* __restrict__ enc,
                                              float* __restrict__ att) {
  __shared__ float o_s[8][1024];
  __shared__ float sc[8][128];
  const int tid = threadIdx.x;
  const int lane = tid & 63;
  const int w = tid >> 6;
  const int b = blockIdx.x >> 3;
  const int t0 = (blockIdx.x & 7) * 8;
#pragma unroll
  for (int ii = 0; ii < 8; ++ii) {
    int idx = tid + ii * 256;
    int tt = idx >> 8, c4 = idx & 255;
    ((float4*)&o_s[tt][0])[c4] =
        *(const float4*)(outs + (size_t)((t0 + tt) * 32 + b) * 1024 + (size_t)c4 * 4);
  }
  __syncthreads();
  for (int si = 0; si < 32; ++si) {
    int s = w * 32 + si;
    float av[8] = {0, 0, 0, 0, 0, 0, 0, 0};
    const float* er = enc + (size_t)(b * 128 + s) * 1024;
#pragma unroll
    for (int i = 0; i < 4; ++i) {
      int k = i * 256 + lane * 4;
      float4 e = *(const float4*)(er + k);
#pragma unroll
      for (int tt = 0; tt < 8; ++tt) {
        float4 o = *(const float4*)&o_s[tt][k];
        av[tt] += e.x * o.x + e.y * o.y + e.z * o.z + e.w * o.w;
      }
    }
#pragma unroll
    for (int tt = 0; tt < 8; ++tt) {
      float v = av[tt];
#pragma unroll
      for (int off = 32; off > 0; off >>= 1) v += __shfl_down(v, off);
      if (lane == 0) sc[tt][s] = v;
    }
  }
  __syncthreads();
#pragma unroll
  for (int pp = 0; pp < 2; ++pp) {
    int tt = w + pp * 4;
    float a = sc[tt][lane], b2 = sc[tt][64 + lane];
    float m = fmaxf(a, b2);
#pragma unroll
    for (int off = 32; off > 0; off >>= 1) m = fmaxf(m, __shfl_xor(m, off));
    float e0 = expf(a - m), e1 = expf(b2 - m);
    float ss = e0 + e1;
#pragma unroll
    for (int off = 32; off > 0; off >>= 1) ss += __shfl_xor(ss, off);
    float r = 1.f / ss;
    att[(size_t)b * 8192 + (size_t)lane * 64 + t0 + tt] = e0 * r;
    att[(size_t)b * 8192 + (size_t)(64 + lane) * 64 + t0 + tt] = e1 * r;
  }
}

extern "C" void kernel_launch(void* const* d_in, const int* in_sizes, int n_in,
                              void* d_out, int out_size, void* d_ws, size_t ws_size,
                              hipStream_t stream) {
  const int*   dec   = (const int*)d_in[0];
  const float* h0    = (const float*)d_in[1];
  const float* c0    = (const float*)d_in[2];
  const float* enc   = (const float*)d_in[3];
  const float* emb   = (const float*)d_in[4];
  const float* W_ih  = (const float*)d_in[5];
  const float* W_hh  = (const float*)d_in[6];
  const float* b_ih  = (const float*)d_in[7];
  const float* b_hh  = (const float*)d_in[8];
  const float* cls_W = (const float*)d_in[9];
  const float* cls_b = (const float*)d_in[10];
  float* out = (float*)d_out;
  char* ws = (char*)d_ws;

  float*    x_f    = (float*)(ws + 0);                // [2048][1024] f32
  _Float16* x_h    = (_Float16*)(ws + 8388608);       // [2048][1024] f16 (dead after gx gemm)
  float*    ipfA   = (float*)(ws + 8388608);          // reuses x_h region (stream-ordered)
  float*    ipfB   = (float*)(ws + 8519680);
  _Float16* Wih_h  = (_Float16*)(ws + 12582912);      // [8192][1024] f16
  _Float16* Whh_h  = (_Float16*)(ws + 29360128);      // [8192][1024] f16
  _Float16* clsW_h = (_Float16*)(ws + 46137344);      // [32000][1024] f16
  float*    gx     = (float*)(ws + 111673344);        // [2048][8192] f32
  float*    outs_f = (float*)(ws + 178782208);        // [2048][1024] f32
  _Float16* outs_h = (_Float16*)(ws + 187170816);     // [2048][1024] f16
  float*    c_f    = (float*)(ws + 191627264);        // [2][32][1024] f32
  _Float16* h0A    = (_Float16*)(ws + 191889408);     // [32][1024] f16
  _Float16* h0B    = (_Float16*)(ws + 191954944);
  _Float16* h1A    = (_Float16*)(ws + 192020480);
  _Float16* h1B    = (_Float16*)(ws + 192086016);
  int*      bcnt   = (int*)(ws + 192151552);
  int*      bgen   = (int*)(ws + 192151616);

  k_f32_to_f16<<<2048, 256, 0, stream>>>(W_ih, Wih_h, 2097152);
  k_f32_to_f16<<<2048, 256, 0, stream>>>(W_hh, Whh_h, 2097152);
  k_f32_to_f16<<<4096, 256, 0, stream>>>(cls_W, clsW_h, 8192000);
  k_embed<<<2048, 256, 0, stream>>>(dec, emb, x_f, x_h);
  k_init<<<256, 256, 0, stream>>>(h0, c0, c_f, h0B, h1B, bcnt, bgen);
  k_gemm<0><<<dim3(64, 16), 256, 0, stream>>>(x_h, Wih_h, b_ih, b_hh, gx);

  k_lstm_persist<<<128, 256, 0, stream>>>(Wih_h, Whh_h, gx, x_f, c_f,
                                          h0A, h0B, h1A, h1B, ipfA, ipfB,
                                          outs_f, outs_h,
                                          out + (size_t)65536000, out + (size_t)65601536,
                                          bcnt, bgen);

  k_attn<<<256, 256, 0, stream>>>(outs_f, enc, out + (size_t)65667072);
  k_gemm<1><<<dim3(250, 16), 256, 0, stream>>>(outs_h, clsW_h, cls_b, (const float*)nullptr, out);
}

// Round 4
// 1568.501 us; speedup vs baseline: 1.1614x; 1.1614x over previous
//
#include <hip/hip_runtime.h>
#include <math.h>

typedef _Float16 f16x8 __attribute__((ext_vector_type(8)));
typedef _Float16 f16x4 __attribute__((ext_vector_type(4)));
typedef float    f32x4 __attribute__((ext_vector_type(4)));
typedef unsigned long long u64;
typedef unsigned int u32;

#define ALOAD(p)    __hip_atomic_load((p), __ATOMIC_RELAXED, __HIP_MEMORY_SCOPE_AGENT)
#define ASTORE(p,v) __hip_atomic_store((p), (v), __ATOMIC_RELAXED, __HIP_MEMORY_SCOPE_AGENT)

// ---------------- conversion f32 -> f16 ----------------
__global__ __launch_bounds__(256) void k_f32_to_f16(const float* __restrict__ src,
                                                    _Float16* __restrict__ dst, int n4) {
  int i = blockIdx.x * 256 + threadIdx.x;
  int stride = gridDim.x * 256;
  for (; i < n4; i += stride) {
    float4 v = ((const float4*)src)[i];
    f16x4 o;
    o.x = (_Float16)v.x; o.y = (_Float16)v.y; o.z = (_Float16)v.z; o.w = (_Float16)v.w;
    ((f16x4*)dst)[i] = o;
  }
}

// ---------------- embedding + relu ----------------
__global__ __launch_bounds__(256) void k_embed(const int* __restrict__ dec,
                                               const float* __restrict__ emb,
                                               float* __restrict__ xf,
                                               _Float16* __restrict__ xh) {
  int i = blockIdx.x * 256 + threadIdx.x;  // 524288 float4 units
  int r = i >> 8;
  int c4 = i & 255;
  int b = r & 31, t = r >> 5;
  int tok = dec[b * 64 + t];
  float4 v = ((const float4*)(emb + (size_t)tok * 1024))[c4];
  v.x = fmaxf(v.x, 0.f); v.y = fmaxf(v.y, 0.f); v.z = fmaxf(v.z, 0.f); v.w = fmaxf(v.w, 0.f);
  ((float4*)(xf + (size_t)r * 1024))[c4] = v;
  f16x4 o;
  o.x = (_Float16)v.x; o.y = (_Float16)v.y; o.z = (_Float16)v.z; o.w = (_Float16)v.w;
  ((f16x4*)(xh + (size_t)r * 1024))[c4] = o;
}

// ---------------- state init (+ barrier reset) ----------------
__global__ __launch_bounds__(256) void k_init(const float* __restrict__ h0, const float* __restrict__ c0,
                                              float* __restrict__ c,
                                              _Float16* __restrict__ h0B, _Float16* __restrict__ h1B,
                                              int* __restrict__ cnt, int* __restrict__ gen) {
  int i = blockIdx.x * 256 + threadIdx.x;  // 65536
  float hv = h0[i];
  c[i] = c0[i];
  if (i < 32768) h0B[i] = (_Float16)hv;
  else           h1B[i - 32768] = (_Float16)hv;
  if (i == 0) { *cnt = 0; *gen = 0; }
}

// ---------------- tiled MFMA GEMM: C[M,N] = A[M,1024] * B[N,1024]^T ----------------
// blockIdx.x = A row-tile (fast-varying -> consecutive blocks share the SAME B tile,
// keeping the B column panel L2-hot); blockIdx.y = B col-tile.
// LDS layout [kb][row][8halves]: conflict-free b128 reads and writes.
template <int MODE>
__global__ __launch_bounds__(256) void k_gemm(const _Float16* __restrict__ A,
                                              const _Float16* __restrict__ Bm,
                                              const float* __restrict__ bias0,
                                              const float* __restrict__ bias1,
                                              float* __restrict__ C) {
  __shared__ _Float16 As[4 * 128 * 8];
  __shared__ _Float16 Bs[4 * 128 * 8];
  const int tid = threadIdx.x;
  const int lane = tid & 63;
  const int w = tid >> 6;
  const int wm = w >> 1, wn = w & 1;
  const _Float16* Ab = A + (size_t)blockIdx.x * 128 * 1024;
  const _Float16* Bb = Bm + (size_t)blockIdx.y * 128 * 1024;
  f32x4 acc[4][4] = {};
  for (int kc = 0; kc < 32; ++kc) {
#pragma unroll
    for (int ii = 0; ii < 2; ++ii) {
      int idx = tid + ii * 256;
      int kb = idx >> 7, row = idx & 127;
      int gofs = row * 1024 + kc * 32 + kb * 8;
      int sofs = kb * 1024 + row * 8;
      *(f16x8*)(As + sofs) = *(const f16x8*)(Ab + gofs);
      *(f16x8*)(Bs + sofs) = *(const f16x8*)(Bb + gofs);
    }
    __syncthreads();
    const int kb = lane >> 4;
    f16x8 af[4], bfv[4];
#pragma unroll
    for (int mf = 0; mf < 4; ++mf) {
      int row = wm * 64 + mf * 16 + (lane & 15);
      af[mf] = *(const f16x8*)(As + kb * 1024 + row * 8);
    }
#pragma unroll
    for (int nf = 0; nf < 4; ++nf) {
      int row = wn * 64 + nf * 16 + (lane & 15);
      bfv[nf] = *(const f16x8*)(Bs + kb * 1024 + row * 8);
    }
#pragma unroll
    for (int mf = 0; mf < 4; ++mf)
#pragma unroll
      for (int nf = 0; nf < 4; ++nf)
        acc[mf][nf] = __builtin_amdgcn_mfma_f32_16x16x32_f16(af[mf], bfv[nf], acc[mf][nf], 0, 0, 0);
    __syncthreads();
  }
  const int rl = (lane >> 4) * 4;
#pragma unroll
  for (int mf = 0; mf < 4; ++mf) {
#pragma unroll
    for (int nf = 0; nf < 4; ++nf) {
#pragma unroll
      for (int j = 0; j < 4; ++j) {
        int m = wm * 64 + mf * 16 + rl + j;
        int n = wn * 64 + nf * 16 + (lane & 15);
        int rg = blockIdx.x * 128 + m;
        int ng = blockIdx.y * 128 + n;
        float v = acc[mf][nf][j];
        if constexpr (MODE == 0) {
          C[(size_t)rg * 8192 + ng] = v + bias0[ng] + bias1[ng];
        } else {
          int tt = rg >> 5, b = rg & 31;
          C[(size_t)(b * 64 + tt) * 32000 + ng] = v + bias0[ng];
        }
      }
    }
  }
}

// ---------------- device-scope generation barrier: RELAXED-only ----------------
// No acquire/release -> NO buffer_inv / buffer_wbl2 -> L2 (weights) never invalidated.
// Visibility: all cross-block state is written via sc1 (agent-scope, L2-bypassing)
// relaxed atomics, drained to the coherence point by the vmcnt(0) wait inside
// __syncthreads() BEFORE the counter bump; readers access the same coherence point.
__device__ __forceinline__ void gbar(int* cnt, int* gen, int nblk) {
  __syncthreads();
  if (threadIdx.x == 0) {
    int g = ALOAD(gen);
    int a = __hip_atomic_fetch_add(cnt, 1, __ATOMIC_RELAXED, __HIP_MEMORY_SCOPE_AGENT);
    if (a == nblk - 1) {
      ASTORE(cnt, 0);
      ASTORE(gen, g + 1);
    } else {
      while (ALOAD(gen) == g) __builtin_amdgcn_s_sleep(1);
    }
  }
  __syncthreads();
}

// ---------------- persistent pipelined LSTM (role-templated body) ----------------
template <int ROLE>
__device__ __forceinline__ void run_phases(
    int jb, const _Float16* __restrict__ Wih_h, const _Float16* __restrict__ Whh_h,
    const float* __restrict__ gx, const float* __restrict__ x_f,
    float* __restrict__ c_f,
    _Float16* __restrict__ h0A, _Float16* __restrict__ h0B,
    _Float16* __restrict__ h1A, _Float16* __restrict__ h1B,
    float* __restrict__ ipfA, float* __restrict__ ipfB,
    float* __restrict__ outs_f, _Float16* __restrict__ outs_h,
    float* __restrict__ outHT, float* __restrict__ outCT,
    int* cnt, int* gen, _Float16* As /* [2][32*264] */, float (*gs)[66]) {
  constexpr int NC = ROLE ? 8 : 4;
  const int u0 = jb * 16;
  const int tid = threadIdx.x;
  const int lane = tid & 63;
  const int w = tid >> 6;
  const int col = lane & 15;
  const int kq = (lane >> 4) * 8;

  // fixed per-block weight rows -> stay hot in this XCD's L2 (normal cached loads)
  const _Float16* bp0;
  const _Float16* bp1 = nullptr;
  if (ROLE == 0) {
    bp0 = Whh_h + (size_t)(w * 1024 + u0 + col) * 1024 + kq;
  } else {
    bp0 = Wih_h + (size_t)(4096 + w * 1024 + u0 + col) * 1024 + kq;
    bp1 = Whh_h + (size_t)(4096 + w * 1024 + u0 + col) * 1024 + kq;
  }
  float* cst = c_f + ROLE * 32768;
  const float* gxbase = gx + (ROLE ? 4096 : 0);

  const int row_s = tid >> 5;        // staging row (0..31) handled by 4 q-slices... see below
  for (int p = 0; p <= 64; ++p) {
    const bool active = (ROLE == 0) ? (p < 64) : (p > 0);
    if (active) {
      const int t = (ROLE == 0) ? p : p - 1;
      const _Float16 *h0r, *h1r;
      _Float16 *h0w, *h1w;
      const float* ipfr; float* ipfw;
      if (p & 1) { h0r = h0A; h0w = h0B; ipfr = ipfA; ipfw = ipfB; h1r = h1B; h1w = h1A; }
      else       { h0r = h0B; h0w = h0A; ipfr = ipfB; ipfw = ipfA; h1r = h1A; h1w = h1B; }

      // ---- issue ALL state loads for the phase (sc1, bypass L2; fully unrolled) ----
      u64 sreg[NC * 8];
#pragma unroll
      for (int c = 0; c < NC; ++c) {
#pragma unroll
        for (int q = 0; q < 4; ++q) {
          int id = q * 256 + tid;
          int row = id >> 5, k8 = id & 31;
          int k = c * 256 + k8 * 8;
          const _Float16* s;
          if (ROLE == 0) s = h0r + row * 1024 + k;
          else           s = (k < 1024) ? (h0r + row * 1024 + k) : (h1r + row * 1024 + (k - 1024));
          const u64* qq = (const u64*)s;
          sreg[c * 8 + 2 * q]     = ALOAD(qq);
          sreg[c * 8 + 2 * q + 1] = ALOAD(qq + 1);
        }
      }

      f32x4 acc0 = {}, acc1 = {};
#pragma unroll
      for (int c = 0; c < NC; ++c) {
        _Float16* buf = As + (c & 1) * (32 * 264);
#pragma unroll
        for (int q = 0; q < 4; ++q) {
          int id = q * 256 + tid;
          int row = id >> 5, k8 = id & 31;
          *(u64*)(buf + row * 264 + k8 * 8)     = sreg[c * 8 + 2 * q];
          *(u64*)(buf + row * 264 + k8 * 8 + 4) = sreg[c * 8 + 2 * q + 1];
        }
        f16x8 bf[8];
#pragma unroll
        for (int kk = 0; kk < 8; ++kk) {
          int kc = c * 8 + kk;
          const _Float16* bsrc = (ROLE == 1 && kc >= 32) ? (bp1 + (size_t)(kc - 32) * 32)
                                                         : (bp0 + (size_t)kc * 32);
          bf[kk] = *(const f16x8*)bsrc;
        }
        __syncthreads();
#pragma unroll
        for (int kk = 0; kk < 8; ++kk) {
          f16x8 a0 = *(const f16x8*)(buf + col * 264 + kk * 32 + kq);
          f16x8 a1 = *(const f16x8*)(buf + (16 + col) * 264 + kk * 32 + kq);
          acc0 = __builtin_amdgcn_mfma_f32_16x16x32_f16(a0, bf[kk], acc0, 0, 0, 0);
          acc1 = __builtin_amdgcn_mfma_f32_16x16x32_f16(a1, bf[kk], acc1, 0, 0, 0);
        }
      }

      const int rl = (lane >> 4) * 4;
#pragma unroll
      for (int j = 0; j < 4; ++j) {
        gs[rl + j][w * 16 + col] = acc0[j];
        gs[16 + rl + j][w * 16 + col] = acc1[j];
      }
      __syncthreads();

      // ---- fused cell: 256 threads x 2 adjacent units ----
      {
        int b = tid >> 3;
        int ul = (tid & 7) << 1;
        int u = u0 + ul;
        const float* gxr = gxbase + (size_t)(t * 32 + b) * 8192;
        float hi2[2], ci2[2];
#pragma unroll
        for (int q = 0; q < 2; ++q) {
          int uq = u + q, ulq = ul + q;
          float ig = gs[b][ulq]      + gxr[uq];
          float fg = gs[b][16 + ulq] + gxr[1024 + uq];
          float gg = gs[b][32 + ulq] + gxr[2048 + uq];
          float og = gs[b][48 + ulq] + gxr[3072 + uq];
          float cp = cst[b * 1024 + uq];
          float si = 1.f / (1.f + expf(-ig));
          float sf = 1.f / (1.f + expf(-fg));
          float so = 1.f / (1.f + expf(-og));
          float ci = sf * cp + si * tanhf(gg);
          float hi = so * tanhf(ci);
          cst[b * 1024 + uq] = ci;
          ci2[q] = ci; hi2[q] = hi;
        }
        if (t == 63) {
          outHT[ROLE * 32768 + b * 1024 + u]     = hi2[0];
          outHT[ROLE * 32768 + b * 1024 + u + 1] = hi2[1];
          outCT[ROLE * 32768 + b * 1024 + u]     = ci2[0];
          outCT[ROLE * 32768 + b * 1024 + u + 1] = ci2[1];
        }
        if (ROLE == 0) {
          union { _Float16 h[2]; u32 v; } ph;
          ph.h[0] = (_Float16)hi2[0]; ph.h[1] = (_Float16)hi2[1];
          ASTORE((u32*)(h0w + b * 1024 + u), ph.v);
          const float* xr = x_f + (size_t)(t * 32 + b) * 1024;
          union { float f[2]; u64 v; } pi;
          pi.f[0] = hi2[0] + xr[u]; pi.f[1] = hi2[1] + xr[u + 1];
          ASTORE((u64*)(ipfw + b * 1024 + u), pi.v);
        } else {
          union { _Float16 h[2]; u32 v; } ph;
          ph.h[0] = (_Float16)hi2[0]; ph.h[1] = (_Float16)hi2[1];
          ASTORE((u32*)(h1w + b * 1024 + u), ph.v);
          union { float f[2]; u64 v; } pr;
          pr.v = ALOAD((const u64*)(ipfr + b * 1024 + u));
          float ro0 = hi2[0] + pr.f[0];
          float ro1 = hi2[1] + pr.f[1];
          float* of = outs_f + (size_t)(t * 32 + b) * 1024 + u;
          of[0] = ro0; of[1] = ro1;
          union { _Float16 h[2]; u32 v; } po;
          po.h[0] = (_Float16)ro0; po.h[1] = (_Float16)ro1;
          *(u32*)(outs_h + (size_t)(t * 32 + b) * 1024 + u) = po.v;
        }
      }
    }
    gbar(cnt, gen, 128);
  }
}

__global__ __launch_bounds__(256, 1) void k_lstm_persist(
    const _Float16* __restrict__ Wih_h, const _Float16* __restrict__ Whh_h,
    const float* __restrict__ gx, const float* __restrict__ x_f,
    float* __restrict__ c_f,
    _Float16* __restrict__ h0A, _Float16* __restrict__ h0B,
    _Float16* __restrict__ h1A, _Float16* __restrict__ h1B,
    float* __restrict__ ipfA, float* __restrict__ ipfB,
    float* __restrict__ outs_f, _Float16* __restrict__ outs_h,
    float* __restrict__ outHT, float* __restrict__ outCT,
    int* cnt, int* gen) {
  __shared__ _Float16 As[2][32 * 264];
  __shared__ float gs[32][66];
  const int jb = blockIdx.x & 63;
  if (blockIdx.x < 64)
    run_phases<0>(jb, Wih_h, Whh_h, gx, x_f, c_f, h0A, h0B, h1A, h1B,
                  ipfA, ipfB, outs_f, outs_h, outHT, outCT, cnt, gen, &As[0][0], gs);
  else
    run_phases<1>(jb, Wih_h, Whh_h, gx, x_f, c_f, h0A, h0B, h1A, h1B,
                  ipfA, ipfB, outs_f, outs_h, outHT, outCT, cnt, gen, &As[0][0], gs);
}

// ---------------- batched dot-attention + softmax ----------------
__global__ __launch_bounds__(256) void k_attn(const float* __restrict__ outs,
                                              const float* __restrict__ enc,
                                              float* __restrict__ att) {
  __shared__ float o_s[8][1024];
  __shared__ float sc[8][128];
  const int tid = threadIdx.x;
  const int lane = tid & 63;
  const int w = tid >> 6;
  const int b = blockIdx.x >> 3;
  const int t0 = (blockIdx.x & 7) * 8;
#pragma unroll
  for (int ii = 0; ii < 8; ++ii) {
    int idx = tid + ii * 256;
    int tt = idx >> 8, c4 = idx & 255;
    ((float4*)&o_s[tt][0])[c4] =
        *(const float4*)(outs + (size_t)((t0 + tt) * 32 + b) * 1024 + (size_t)c4 * 4);
  }
  __syncthreads();
  for (int si = 0; si < 32; ++si) {
    int s = w * 32 + si;
    float av[8] = {0, 0, 0, 0, 0, 0, 0, 0};
    const float* er = enc + (size_t)(b * 128 + s) * 1024;
#pragma unroll
    for (int i = 0; i < 4; ++i) {
      int k = i * 256 + lane * 4;
      float4 e = *(const float4*)(er + k);
#pragma unroll
      for (int tt = 0; tt < 8; ++tt) {
        float4 o = *(const float4*)&o_s[tt][k];
        av[tt] += e.x * o.x + e.y * o.y + e.z * o.z + e.w * o.w;
      }
    }
#pragma unroll
    for (int tt = 0; tt < 8; ++tt) {
      float v = av[tt];
#pragma unroll
      for (int off = 32; off > 0; off >>= 1) v += __shfl_down(v, off);
      if (lane == 0) sc[tt][s] = v;
    }
  }
  __syncthreads();
#pragma unroll
  for (int pp = 0; pp < 2; ++pp) {
    int tt = w + pp * 4;
    float a = sc[tt][lane], b2 = sc[tt][64 + lane];
    float m = fmaxf(a, b2);
#pragma unroll
    for (int off = 32; off > 0; off >>= 1) m = fmaxf(m, __shfl_xor(m, off));
    float e0 = expf(a - m), e1 = expf(b2 - m);
    float ss = e0 + e1;
#pragma unroll
    for (int off = 32; off > 0; off >>= 1) ss += __shfl_xor(ss, off);
    float r = 1.f / ss;
    att[(size_t)b * 8192 + (size_t)lane * 64 + t0 + tt] = e0 * r;
    att[(size_t)b * 8192 + (size_t)(64 + lane) * 64 + t0 + tt] = e1 * r;
  }
}

extern "C" void kernel_launch(void* const* d_in, const int* in_sizes, int n_in,
                              void* d_out, int out_size, void* d_ws, size_t ws_size,
                              hipStream_t stream) {
  const int*   dec   = (const int*)d_in[0];
  const float* h0    = (const float*)d_in[1];
  const float* c0    = (const float*)d_in[2];
  const float* enc   = (const float*)d_in[3];
  const float* emb   = (const float*)d_in[4];
  const float* W_ih  = (const float*)d_in[5];
  const float* W_hh  = (const float*)d_in[6];
  const float* b_ih  = (const float*)d_in[7];
  const float* b_hh  = (const float*)d_in[8];
  const float* cls_W = (const float*)d_in[9];
  const float* cls_b = (const float*)d_in[10];
  float* out = (float*)d_out;
  char* ws = (char*)d_ws;

  float*    x_f    = (float*)(ws + 0);                // [2048][1024] f32
  _Float16* x_h    = (_Float16*)(ws + 8388608);       // [2048][1024] f16 (dead after gx gemm)
  float*    ipfA   = (float*)(ws + 8388608);          // reuses x_h region (stream-ordered)
  float*    ipfB   = (float*)(ws + 8519680);
  _Float16* Wih_h  = (_Float16*)(ws + 12582912);      // [8192][1024] f16
  _Float16* Whh_h  = (_Float16*)(ws + 29360128);      // [8192][1024] f16
  _Float16* clsW_h = (_Float16*)(ws + 46137344);      // [32000][1024] f16
  float*    gx     = (float*)(ws + 111673344);        // [2048][8192] f32
  float*    outs_f = (float*)(ws + 178782208);        // [2048][1024] f32
  _Float16* outs_h = (_Float16*)(ws + 187170816);     // [2048][1024] f16
  float*    c_f    = (float*)(ws + 191627264);        // [2][32][1024] f32
  _Float16* h0A    = (_Float16*)(ws + 191889408);     // [32][1024] f16
  _Float16* h0B    = (_Float16*)(ws + 191954944);
  _Float16* h1A    = (_Float16*)(ws + 192020480);
  _Float16* h1B    = (_Float16*)(ws + 192086016);
  int*      bcnt   = (int*)(ws + 192151552);
  int*      bgen   = (int*)(ws + 192151616);

  k_f32_to_f16<<<2048, 256, 0, stream>>>(W_ih, Wih_h, 2097152);
  k_f32_to_f16<<<2048, 256, 0, stream>>>(W_hh, Whh_h, 2097152);
  k_f32_to_f16<<<4096, 256, 0, stream>>>(cls_W, clsW_h, 8192000);
  k_embed<<<2048, 256, 0, stream>>>(dec, emb, x_f, x_h);
  k_init<<<256, 256, 0, stream>>>(h0, c0, c_f, h0B, h1B, bcnt, bgen);
  k_gemm<0><<<dim3(16, 64), 256, 0, stream>>>(x_h, Wih_h, b_ih, b_hh, gx);

  k_lstm_persist<<<128, 256, 0, stream>>>(Wih_h, Whh_h, gx, x_f, c_f,
                                          h0A, h0B, h1A, h1B, ipfA, ipfB,
                                          outs_f, outs_h,
                                          out + (size_t)65536000, out + (size_t)65601536,
                                          bcnt, bgen);

  k_attn<<<256, 256, 0, stream>>>(outs_f, enc, out + (size_t)65667072);
  k_gemm<1><<<dim3(16, 250), 256, 0, stream>>>(outs_h, clsW_h, cls_b, (const float*)nullptr, out);
}

// Round 5
// 1182.878 us; speedup vs baseline: 1.5400x; 1.3260x over previous
//
#include <hip/hip_runtime.h>
#include <math.h>

typedef _Float16 f16x8 __attribute__((ext_vector_type(8)));
typedef _Float16 f16x4 __attribute__((ext_vector_type(4)));
typedef float    f32x4 __attribute__((ext_vector_type(4)));
typedef unsigned long long u64;
typedef unsigned int u32;

#define ALOAD(p)    __hip_atomic_load((p), __ATOMIC_RELAXED, __HIP_MEMORY_SCOPE_AGENT)
#define ASTORE(p,v) __hip_atomic_store((p), (v), __ATOMIC_RELAXED, __HIP_MEMORY_SCOPE_AGENT)

// ---------------- conversion f32 -> f16 ----------------
__global__ __launch_bounds__(256) void k_f32_to_f16(const float* __restrict__ src,
                                                    _Float16* __restrict__ dst, int n4) {
  int i = blockIdx.x * 256 + threadIdx.x;
  int stride = gridDim.x * 256;
  for (; i < n4; i += stride) {
    float4 v = ((const float4*)src)[i];
    f16x4 o;
    o.x = (_Float16)v.x; o.y = (_Float16)v.y; o.z = (_Float16)v.z; o.w = (_Float16)v.w;
    ((f16x4*)dst)[i] = o;
  }
}

// ---------------- weight packing into per-wave fragment-stream order ----------------
// Persist kernel reads, per (jb, wave kh, step s, gate g): 64 lanes x 16B contiguous.
// frag idx = (((jb*8+kh)*S + s)*4 + g)*64 + kslot*16 + col ; source row = g*1024+jb*16+col,
// k = kh*(S*32) + s*32 + kslot*8.
// ROLE0: S=4, source Whh0. ROLE1: S=8, khalf0 = Wih1 (k 0..1023), khalf1 = Whh1.
__global__ __launch_bounds__(256) void k_pack0(const float* __restrict__ Whh0,
                                               _Float16* __restrict__ P) {
  int li = blockIdx.x * 256 + threadIdx.x;  // 524288
  int row = li >> 7, k8 = li & 127;
  const float* s = Whh0 + (size_t)row * 1024 + k8 * 8;
  int g = row >> 10, u = row & 1023, jb = u >> 4, col = u & 15;
  int kh = k8 >> 4, rem = k8 & 15, st = rem >> 2, kslot = rem & 3;
  size_t idx = ((size_t)(((jb * 8 + kh) * 4 + st) * 4 + g)) * 64 + kslot * 16 + col;
  f16x8 o;
#pragma unroll
  for (int j = 0; j < 8; ++j) o[j] = (_Float16)s[j];
  *(f16x8*)(P + idx * 8) = o;
}

__global__ __launch_bounds__(256) void k_pack1(const float* __restrict__ Wih1,
                                               const float* __restrict__ Whh1,
                                               _Float16* __restrict__ P) {
  int li = blockIdx.x * 256 + threadIdx.x;  // 1048576
  int mat = li >> 19;
  int li2 = li & 524287;
  int row = li2 >> 7, k8l = li2 & 127;
  const float* s = (mat ? Whh1 : Wih1) + (size_t)row * 1024 + k8l * 8;
  int g = row >> 10, u = row & 1023, jb = u >> 4, col = u & 15;
  int k8g = mat * 128 + k8l;
  int kh = k8g >> 5, rem = k8g & 31, st = rem >> 2, kslot = rem & 3;
  size_t idx = ((size_t)(((jb * 8 + kh) * 8 + st) * 4 + g)) * 64 + kslot * 16 + col;
  f16x8 o;
#pragma unroll
  for (int j = 0; j < 8; ++j) o[j] = (_Float16)s[j];
  *(f16x8*)(P + idx * 8) = o;
}

// ---------------- embedding + relu ----------------
__global__ __launch_bounds__(256) void k_embed(const int* __restrict__ dec,
                                               const float* __restrict__ emb,
                                               float* __restrict__ xf,
                                               _Float16* __restrict__ xh) {
  int i = blockIdx.x * 256 + threadIdx.x;  // 524288 float4 units
  int r = i >> 8;
  int c4 = i & 255;
  int b = r & 31, t = r >> 5;
  int tok = dec[b * 64 + t];
  float4 v = ((const float4*)(emb + (size_t)tok * 1024))[c4];
  v.x = fmaxf(v.x, 0.f); v.y = fmaxf(v.y, 0.f); v.z = fmaxf(v.z, 0.f); v.w = fmaxf(v.w, 0.f);
  ((float4*)(xf + (size_t)r * 1024))[c4] = v;
  f16x4 o;
  o.x = (_Float16)v.x; o.y = (_Float16)v.y; o.z = (_Float16)v.z; o.w = (_Float16)v.w;
  ((f16x4*)(xh + (size_t)r * 1024))[c4] = o;
}

// ---------------- state init (+ barrier reset) ----------------
__global__ __launch_bounds__(256) void k_init(const float* __restrict__ h0, const float* __restrict__ c0,
                                              float* __restrict__ c,
                                              _Float16* __restrict__ h0B, _Float16* __restrict__ h1B,
                                              int* __restrict__ bar) {
  int i = blockIdx.x * 256 + threadIdx.x;  // 65536
  float hv = h0[i];
  c[i] = c0[i];
  if (i < 32768) h0B[i] = (_Float16)hv;
  else           h1B[i - 32768] = (_Float16)hv;
  if (i < 576) bar[i] = 0;
}

// ---------------- tiled MFMA GEMM: C[M,N] = A[M,1024] * B[N,1024]^T ----------------
// blockIdx.x = B col-tile (fast), blockIdx.y = A row-tile (R2 orientation).
template <int MODE>
__global__ __launch_bounds__(256) void k_gemm(const _Float16* __restrict__ A,
                                              const _Float16* __restrict__ Bm,
                                              const float* __restrict__ bias0,
                                              const float* __restrict__ bias1,
                                              float* __restrict__ C) {
  __shared__ _Float16 As[4 * 128 * 8];
  __shared__ _Float16 Bs[4 * 128 * 8];
  const int tid = threadIdx.x;
  const int lane = tid & 63;
  const int w = tid >> 6;
  const int wm = w >> 1, wn = w & 1;
  const _Float16* Ab = A + (size_t)blockIdx.y * 128 * 1024;
  const _Float16* Bb = Bm + (size_t)blockIdx.x * 128 * 1024;
  f32x4 acc[4][4] = {};
  for (int kc = 0; kc < 32; ++kc) {
#pragma unroll
    for (int ii = 0; ii < 2; ++ii) {
      int idx = tid + ii * 256;
      int kb = idx >> 7, row = idx & 127;
      int gofs = row * 1024 + kc * 32 + kb * 8;
      int sofs = kb * 1024 + row * 8;
      *(f16x8*)(As + sofs) = *(const f16x8*)(Ab + gofs);
      *(f16x8*)(Bs + sofs) = *(const f16x8*)(Bb + gofs);
    }
    __syncthreads();
    const int kb = lane >> 4;
    f16x8 af[4], bfv[4];
#pragma unroll
    for (int mf = 0; mf < 4; ++mf) {
      int row = wm * 64 + mf * 16 + (lane & 15);
      af[mf] = *(const f16x8*)(As + kb * 1024 + row * 8);
    }
#pragma unroll
    for (int nf = 0; nf < 4; ++nf) {
      int row = wn * 64 + nf * 16 + (lane & 15);
      bfv[nf] = *(const f16x8*)(Bs + kb * 1024 + row * 8);
    }
#pragma unroll
    for (int mf = 0; mf < 4; ++mf)
#pragma unroll
      for (int nf = 0; nf < 4; ++nf)
        acc[mf][nf] = __builtin_amdgcn_mfma_f32_16x16x32_f16(af[mf], bfv[nf], acc[mf][nf], 0, 0, 0);
    __syncthreads();
  }
  const int rl = (lane >> 4) * 4;
#pragma unroll
  for (int mf = 0; mf < 4; ++mf) {
#pragma unroll
    for (int nf = 0; nf < 4; ++nf) {
#pragma unroll
      for (int j = 0; j < 4; ++j) {
        int m = wm * 64 + mf * 16 + rl + j;
        int n = wn * 64 + nf * 16 + (lane & 15);
        int rg = blockIdx.y * 128 + m;
        int ng = blockIdx.x * 128 + n;
        float v = acc[mf][nf][j];
        if constexpr (MODE == 0) {
          C[(size_t)rg * 8192 + ng] = v + bias0[ng] + bias1[ng];
        } else {
          int tt = rg >> 5, b = rg & 31;
          C[(size_t)(b * 64 + tt) * 32000 + ng] = v + bias0[ng];
        }
      }
    }
  }
}

// ---------------- two-level tree barrier (RELAXED-only, no cache maintenance) ----------------
// bar[grp*32] = per-group counters (16 groups of 8 blocks), bar[512] = root, bar[544] = gen.
__device__ __forceinline__ void gbar(int* bar) {
  __syncthreads();
  if (threadIdx.x == 0) {
    int* gen = bar + 544;
    int g = ALOAD(gen);
    int grp = blockIdx.x >> 3;
    int a = __hip_atomic_fetch_add(bar + grp * 32, 1, __ATOMIC_RELAXED, __HIP_MEMORY_SCOPE_AGENT);
    if (a == 7) {
      ASTORE(bar + grp * 32, 0);
      int r = __hip_atomic_fetch_add(bar + 512, 1, __ATOMIC_RELAXED, __HIP_MEMORY_SCOPE_AGENT);
      if (r == 15) {
        ASTORE(bar + 512, 0);
        ASTORE(gen, g + 1);
      }
    }
    while (ALOAD(gen) == g) __builtin_amdgcn_s_sleep(2);
  }
  __syncthreads();
}

// ---------------- persistent pipelined LSTM ----------------
// 128 blocks x 512 threads (8 waves). Phase p: blocks 0..63 = layer0 of t=p;
// blocks 64..127 = layer1 of t=p-1. Wave kh = K-slice (K/8); each wave computes
// all 4 gates for the block's 16 units over its K-slice (8 indep MFMA chains).
// Partials reduced via LDS (4 copies, overlaid on the A buffer after MFMA).
template <int ROLE>
__device__ __forceinline__ void run_phases(
    int jb, const _Float16* __restrict__ Pk,
    const float* __restrict__ gx, const float* __restrict__ x_f,
    float* __restrict__ c_f,
    _Float16* __restrict__ h0A, _Float16* __restrict__ h0B,
    _Float16* __restrict__ h1A, _Float16* __restrict__ h1B,
    float* __restrict__ ipfA, float* __restrict__ ipfB,
    float* __restrict__ outs_f, _Float16* __restrict__ outs_h,
    float* __restrict__ outHT, float* __restrict__ outCT,
    int* bar, _Float16* As) {
  constexpr int S = ROLE ? 8 : 4;        // steps per wave (32 k each)
  constexpr int NF = ROLE ? 16 : 8;      // 16B fragments staged per thread
  constexpr int RSH = ROLE ? 8 : 7;      // log2(frags per row)
  constexpr int K8M = ROLE ? 255 : 127;
  const int u0 = jb * 16;
  const int tid = threadIdx.x;
  const int lane = tid & 63;
  const int kh = tid >> 6;               // wave = K-slice
  const int col = lane & 15;
  const int kslot = lane >> 4;

  float* cst = c_f + ROLE * 32768;
  const float* gxbase = gx + (ROLE ? 4096 : 0);
  const int cb = tid >> 4, cul = tid & 15, cu = u0 + cul;

  const _Float16* pkbase = Pk + ((size_t)(jb * 8 + kh) * S) * 4 * 512 + lane * 8;
  const int a0off = col * 2056 + kh * S * 32 + kslot * 8;
  const int a1off = a0off + 16 * 2056;

  for (int p = 0; p <= 64; ++p) {
    const bool active = (ROLE == 0) ? (p < 64) : (p > 0);
    if (active) {
      const int t = (ROLE == 0) ? p : p - 1;
      const _Float16 *h0r, *h1r;
      _Float16 *h0w, *h1w;
      const float* ipfr; float* ipfw;
      if (p & 1) { h0r = h0A; h0w = h0B; ipfr = ipfA; ipfw = ipfB; h1r = h1B; h1w = h1A; }
      else       { h0r = h0B; h0w = h0A; ipfr = ipfB; ipfw = ipfA; h1r = h1A; h1w = h1B; }

      // ---- prefetch all A-state fragments (sc1 agent loads, coalesced) ----
      u64 sreg[NF * 2];
#pragma unroll
      for (int i = 0; i < NF; ++i) {
        int fr = i * 512 + tid;
        int row = fr >> RSH, k8 = fr & K8M;
        const _Float16* s;
        if (ROLE == 0) s = h0r + row * 1024 + k8 * 8;
        else           s = (k8 < 128) ? (h0r + row * 1024 + k8 * 8)
                                      : (h1r + row * 1024 + (k8 - 128) * 8);
        const u64* qq = (const u64*)s;
        sreg[2 * i]     = ALOAD(qq);
        sreg[2 * i + 1] = ALOAD(qq + 1);
      }
      // ---- prefetch cell inputs ----
      const float* gxr = gxbase + (size_t)(t * 32 + cb) * 8192;
      float pg0 = gxr[cu], pg1 = gxr[1024 + cu], pg2 = gxr[2048 + cu], pg3 = gxr[3072 + cu];
      float pc = cst[cb * 1024 + cu];
      float px = 0.f, pip = 0.f;
      if (ROLE == 0) px = x_f[(size_t)(t * 32 + cb) * 1024 + cu];
      else           pip = ALOAD(ipfr + cb * 1024 + cu);

      // ---- stage A to LDS (row-major, stride 2056 f16) ----
#pragma unroll
      for (int i = 0; i < NF; ++i) {
        int fr = i * 512 + tid;
        int row = fr >> RSH, k8 = fr & K8M;
        u64* d = (u64*)(As + row * 2056 + k8 * 8);
        d[0] = sreg[2 * i];
        d[1] = sreg[2 * i + 1];
      }
      __syncthreads();

      // ---- MFMA: per step, 2 A-frags (LDS) x 4 gate B-frags (packed global) ----
      f32x4 acc[2][4] = {};
#pragma unroll
      for (int s2 = 0; s2 < S; ++s2) {
        f16x8 b0 = *(const f16x8*)(pkbase + (s2 * 4 + 0) * 512);
        f16x8 b1 = *(const f16x8*)(pkbase + (s2 * 4 + 1) * 512);
        f16x8 b2 = *(const f16x8*)(pkbase + (s2 * 4 + 2) * 512);
        f16x8 b3 = *(const f16x8*)(pkbase + (s2 * 4 + 3) * 512);
        f16x8 a0 = *(const f16x8*)(As + a0off + s2 * 32);
        f16x8 a1 = *(const f16x8*)(As + a1off + s2 * 32);
        acc[0][0] = __builtin_amdgcn_mfma_f32_16x16x32_f16(a0, b0, acc[0][0], 0, 0, 0);
        acc[1][0] = __builtin_amdgcn_mfma_f32_16x16x32_f16(a1, b0, acc[1][0], 0, 0, 0);
        acc[0][1] = __builtin_amdgcn_mfma_f32_16x16x32_f16(a0, b1, acc[0][1], 0, 0, 0);
        acc[1][1] = __builtin_amdgcn_mfma_f32_16x16x32_f16(a1, b1, acc[1][1], 0, 0, 0);
        acc[0][2] = __builtin_amdgcn_mfma_f32_16x16x32_f16(a0, b2, acc[0][2], 0, 0, 0);
        acc[1][2] = __builtin_amdgcn_mfma_f32_16x16x32_f16(a1, b2, acc[1][2], 0, 0, 0);
        acc[0][3] = __builtin_amdgcn_mfma_f32_16x16x32_f16(a0, b3, acc[0][3], 0, 0, 0);
        acc[1][3] = __builtin_amdgcn_mfma_f32_16x16x32_f16(a1, b3, acc[1][3], 0, 0, 0);
      }
      __syncthreads();

      // ---- reduce 8 wave-partials via 4 LDS copies (overlay on As) ----
      float (*gs)[32][68] = (float (*)[32][68])(void*)As;
      const int rl = kslot * 4;
      if (kh < 4) {
#pragma unroll
        for (int m = 0; m < 2; ++m)
#pragma unroll
          for (int g = 0; g < 4; ++g)
#pragma unroll
            for (int j = 0; j < 4; ++j)
              gs[kh][m * 16 + rl + j][g * 16 + col] = acc[m][g][j];
      }
      __syncthreads();
      if (kh >= 4) {
#pragma unroll
        for (int m = 0; m < 2; ++m)
#pragma unroll
          for (int g = 0; g < 4; ++g)
#pragma unroll
            for (int j = 0; j < 4; ++j)
              gs[kh - 4][m * 16 + rl + j][g * 16 + col] += acc[m][g][j];
      }
      __syncthreads();

      // ---- fused cell: one thread per (batch cb, unit cul) ----
      {
        float ig = pg0, fg = pg1, gg = pg2, og = pg3;
#pragma unroll
        for (int cc = 0; cc < 4; ++cc) {
          ig += gs[cc][cb][cul];
          fg += gs[cc][cb][16 + cul];
          gg += gs[cc][cb][32 + cul];
          og += gs[cc][cb][48 + cul];
        }
        float si = 1.f / (1.f + expf(-ig));
        float sf = 1.f / (1.f + expf(-fg));
        float so = 1.f / (1.f + expf(-og));
        float ci = sf * pc + si * tanhf(gg);
        float hi = so * tanhf(ci);
        cst[cb * 1024 + cu] = ci;
        if (t == 63) {
          outHT[ROLE * 32768 + cb * 1024 + cu] = hi;
          outCT[ROLE * 32768 + cb * 1024 + cu] = ci;
        }
        if (ROLE == 0) {
          float hn = __shfl_down(hi, 1);
          float ipv = hi + px;
          float ipn = __shfl_down(ipv, 1);
          if ((cul & 1) == 0) {
            union { _Float16 h[2]; u32 v; } ph;
            ph.h[0] = (_Float16)hi; ph.h[1] = (_Float16)hn;
            ASTORE((u32*)(h0w + cb * 1024 + cu), ph.v);
            union { float f[2]; u64 v; } pi;
            pi.f[0] = ipv; pi.f[1] = ipn;
            ASTORE((u64*)(ipfw + cb * 1024 + cu), pi.v);
          }
        } else {
          float hn = __shfl_down(hi, 1);
          if ((cul & 1) == 0) {
            union { _Float16 h[2]; u32 v; } ph;
            ph.h[0] = (_Float16)hi; ph.h[1] = (_Float16)hn;
            ASTORE((u32*)(h1w + cb * 1024 + cu), ph.v);
          }
          float ro = hi + pip;
          outs_f[(size_t)(t * 32 + cb) * 1024 + cu] = ro;
          outs_h[(size_t)(t * 32 + cb) * 1024 + cu] = (_Float16)ro;
        }
      }
    }
    if (p < 64) gbar(bar);
  }
}

__global__ __launch_bounds__(512, 1) void k_lstm_persist(
    const _Float16* __restrict__ Pk0, const _Float16* __restrict__ Pk1,
    const float* __restrict__ gx, const float* __restrict__ x_f,
    float* __restrict__ c_f,
    _Float16* __restrict__ h0A, _Float16* __restrict__ h0B,
    _Float16* __restrict__ h1A, _Float16* __restrict__ h1B,
    float* __restrict__ ipfA, float* __restrict__ ipfB,
    float* __restrict__ outs_f, _Float16* __restrict__ outs_h,
    float* __restrict__ outHT, float* __restrict__ outCT,
    int* bar) {
  __shared__ _Float16 As[32 * 2056];  // 131,584 B; gs overlaid after MFMA phase
  const int jb = blockIdx.x & 63;
  if (blockIdx.x < 64)
    run_phases<0>(jb, Pk0, gx, x_f, c_f, h0A, h0B, h1A, h1B,
                  ipfA, ipfB, outs_f, outs_h, outHT, outCT, bar, As);
  else
    run_phases<1>(jb, Pk1, gx, x_f, c_f, h0A, h0B, h1A, h1B,
                  ipfA, ipfB, outs_f, outs_h, outHT, outCT, bar, As);
}

// ---------------- batched dot-attention + softmax ----------------
__global__ __launch_bounds__(256) void k_attn(const float* __restrict__ outs,
                                              const float* __restrict__ enc,
                                              float* __restrict__ att) {
  __shared__ float o_s[8][1024];
  __shared__ float sc[8][128];
  const int tid = threadIdx.x;
  const int lane = tid & 63;
  const int w = tid >> 6;
  const int b = blockIdx.x >> 3;
  const int t0 = (blockIdx.x & 7) * 8;
#pragma unroll
  for (int ii = 0; ii < 8; ++ii) {
    int idx = tid + ii * 256;
    int tt = idx >> 8, c4 = idx & 255;
    ((float4*)&o_s[tt][0])[c4] =
        *(const float4*)(outs + (size_t)((t0 + tt) * 32 + b) * 1024 + (size_t)c4 * 4);
  }
  __syncthreads();
  for (int si = 0; si < 32; ++si) {
    int s = w * 32 + si;
    float av[8] = {0, 0, 0, 0, 0, 0, 0, 0};
    const float* er = enc + (size_t)(b * 128 + s) * 1024;
#pragma unroll
    for (int i = 0; i < 4; ++i) {
      int k = i * 256 + lane * 4;
      float4 e = *(const float4*)(er + k);
#pragma unroll
      for (int tt = 0; tt < 8; ++tt) {
        float4 o = *(const float4*)&o_s[tt][k];
        av[tt] += e.x * o.x + e.y * o.y + e.z * o.z + e.w * o.w;
      }
    }
#pragma unroll
    for (int tt = 0; tt < 8; ++tt) {
      float v = av[tt];
#pragma unroll
      for (int off = 32; off > 0; off >>= 1) v += __shfl_down(v, off);
      if (lane == 0) sc[tt][s] = v;
    }
  }
  __syncthreads();
#pragma unroll
  for (int pp = 0; pp < 2; ++pp) {
    int tt = w + pp * 4;
    float a = sc[tt][lane], b2 = sc[tt][64 + lane];
    float m = fmaxf(a, b2);
#pragma unroll
    for (int off = 32; off > 0; off >>= 1) m = fmaxf(m, __shfl_xor(m, off));
    float e0 = expf(a - m), e1 = expf(b2 - m);
    float ss = e0 + e1;
#pragma unroll
    for (int off = 32; off > 0; off >>= 1) ss += __shfl_xor(ss, off);
    float r = 1.f / ss;
    att[(size_t)b * 8192 + (size_t)lane * 64 + t0 + tt] = e0 * r;
    att[(size_t)b * 8192 + (size_t)(64 + lane) * 64 + t0 + tt] = e1 * r;
  }
}

extern "C" void kernel_launch(void* const* d_in, const int* in_sizes, int n_in,
                              void* d_out, int out_size, void* d_ws, size_t ws_size,
                              hipStream_t stream) {
  const int*   dec   = (const int*)d_in[0];
  const float* h0    = (const float*)d_in[1];
  const float* c0    = (const float*)d_in[2];
  const float* enc   = (const float*)d_in[3];
  const float* emb   = (const float*)d_in[4];
  const float* W_ih  = (const float*)d_in[5];
  const float* W_hh  = (const float*)d_in[6];
  const float* b_ih  = (const float*)d_in[7];
  const float* b_hh  = (const float*)d_in[8];
  const float* cls_W = (const float*)d_in[9];
  const float* cls_b = (const float*)d_in[10];
  float* out = (float*)d_out;
  char* ws = (char*)d_ws;

  float*    x_f    = (float*)(ws + 0);                // [2048][1024] f32
  _Float16* x_h    = (_Float16*)(ws + 8388608);       // [2048][1024] f16 (dead after gx gemm)
  _Float16* Pk0    = (_Float16*)(ws + 8388608);       // 8MB packed Whh0 (written AFTER gx gemm)
  _Float16* Wih_h  = (_Float16*)(ws + 12582912);      // [8192][1024] f16 (dead after gx gemm)
  _Float16* Pk1    = (_Float16*)(ws + 29360128);      // 16MB packed [Wih1|Whh1]
  _Float16* clsW_h = (_Float16*)(ws + 46137344);      // [32000][1024] f16
  float*    gx     = (float*)(ws + 111673344);        // [2048][8192] f32
  float*    outs_f = (float*)(ws + 178782208);        // [2048][1024] f32
  _Float16* outs_h = (_Float16*)(ws + 187170816);     // [2048][1024] f16
  float*    c_f    = (float*)(ws + 191627264);        // [2][32][1024] f32
  _Float16* h0A    = (_Float16*)(ws + 191889408);     // [32][1024] f16
  _Float16* h0B    = (_Float16*)(ws + 191954944);
  _Float16* h1A    = (_Float16*)(ws + 192020480);
  _Float16* h1B    = (_Float16*)(ws + 192086016);
  int*      bar    = (int*)(ws + 192151552);          // 576 ints (tree barrier)
  float*    ipfA   = (float*)(ws + 192155648);        // [32][1024] f32
  float*    ipfB   = (float*)(ws + 192286720);        // end 192417792

  k_f32_to_f16<<<2048, 256, 0, stream>>>(W_ih, Wih_h, 2097152);
  k_f32_to_f16<<<4096, 256, 0, stream>>>(cls_W, clsW_h, 8192000);
  k_embed<<<2048, 256, 0, stream>>>(dec, emb, x_f, x_h);
  k_init<<<256, 256, 0, stream>>>(h0, c0, c_f, h0B, h1B, bar);
  k_pack1<<<4096, 256, 0, stream>>>(W_ih + (size_t)4096 * 1024, W_hh + (size_t)4096 * 1024, Pk1);
  // gx[r][0:4096] = x@Wih0^T + b_ih0 + b_hh0 ; gx[r][4096:8192] = x@Wih1^T + b_ih1 + b_hh1
  k_gemm<0><<<dim3(64, 16), 256, 0, stream>>>(x_h, Wih_h, b_ih, b_hh, gx);
  k_pack0<<<2048, 256, 0, stream>>>(W_hh, Pk0);  // after gemm<0>: overwrites x_h/Wih_h region

  k_lstm_persist<<<128, 512, 0, stream>>>(Pk0, Pk1, gx, x_f, c_f,
                                          h0A, h0B, h1A, h1B, ipfA, ipfB,
                                          outs_f, outs_h,
                                          out + (size_t)65536000, out + (size_t)65601536,
                                          bar);

  k_attn<<<256, 256, 0, stream>>>(outs_f, enc, out + (size_t)65667072);
  k_gemm<1><<<dim3(250, 16), 256, 0, stream>>>(outs_h, clsW_h, cls_b, (const float*)nullptr, out);
}

// Round 6
// 993.694 us; speedup vs baseline: 1.8332x; 1.1904x over previous
//
#include <hip/hip_runtime.h>
#include <math.h>

typedef _Float16 f16x8 __attribute__((ext_vector_type(8)));
typedef _Float16 f16x4 __attribute__((ext_vector_type(4)));
typedef float    f32x4 __attribute__((ext_vector_type(4)));
typedef unsigned long long u64;
typedef unsigned int u32;

#define ALOAD(p)    __hip_atomic_load((p), __ATOMIC_RELAXED, __HIP_MEMORY_SCOPE_AGENT)
#define ASTORE(p,v) __hip_atomic_store((p), (v), __ATOMIC_RELAXED, __HIP_MEMORY_SCOPE_AGENT)

// ---------------- conversion f32 -> f16 ----------------
__global__ __launch_bounds__(256) void k_f32_to_f16(const float* __restrict__ src,
                                                    _Float16* __restrict__ dst, int n4) {
  int i = blockIdx.x * 256 + threadIdx.x;
  int stride = gridDim.x * 256;
  for (; i < n4; i += stride) {
    float4 v = ((const float4*)src)[i];
    f16x4 o;
    o.x = (_Float16)v.x; o.y = (_Float16)v.y; o.z = (_Float16)v.z; o.w = (_Float16)v.w;
    ((f16x4*)dst)[i] = o;
  }
}

// ---------------- weight packing into per-wave fragment-stream order ----------------
// frag idx = (((jb*8+kh)*S + s)*4 + g)*64 + kslot*16 + col ; source row = g*1024+jb*16+col,
// k = kh*(S*32) + s*32 + kslot*8.  ROLE0: S=4 (Whh0). ROLE1: S=8 (kh 0..3 Wih1, 4..7 Whh1).
__global__ __launch_bounds__(256) void k_pack0(const float* __restrict__ Whh0,
                                               _Float16* __restrict__ P) {
  int li = blockIdx.x * 256 + threadIdx.x;  // 524288
  int row = li >> 7, k8 = li & 127;
  const float* s = Whh0 + (size_t)row * 1024 + k8 * 8;
  int g = row >> 10, u = row & 1023, jb = u >> 4, col = u & 15;
  int kh = k8 >> 4, rem = k8 & 15, st = rem >> 2, kslot = rem & 3;
  size_t idx = ((size_t)(((jb * 8 + kh) * 4 + st) * 4 + g)) * 64 + kslot * 16 + col;
  f16x8 o;
#pragma unroll
  for (int j = 0; j < 8; ++j) o[j] = (_Float16)s[j];
  *(f16x8*)(P + idx * 8) = o;
}

__global__ __launch_bounds__(256) void k_pack1(const float* __restrict__ Wih1,
                                               const float* __restrict__ Whh1,
                                               _Float16* __restrict__ P) {
  int li = blockIdx.x * 256 + threadIdx.x;  // 1048576
  int mat = li >> 19;
  int li2 = li & 524287;
  int row = li2 >> 7, k8l = li2 & 127;
  const float* s = (mat ? Whh1 : Wih1) + (size_t)row * 1024 + k8l * 8;
  int g = row >> 10, u = row & 1023, jb = u >> 4, col = u & 15;
  int k8g = mat * 128 + k8l;
  int kh = k8g >> 5, rem = k8g & 31, st = rem >> 2, kslot = rem & 3;
  size_t idx = ((size_t)(((jb * 8 + kh) * 8 + st) * 4 + g)) * 64 + kslot * 16 + col;
  f16x8 o;
#pragma unroll
  for (int j = 0; j < 8; ++j) o[j] = (_Float16)s[j];
  *(f16x8*)(P + idx * 8) = o;
}

// ---------------- embedding + relu ----------------
__global__ __launch_bounds__(256) void k_embed(const int* __restrict__ dec,
                                               const float* __restrict__ emb,
                                               float* __restrict__ xf,
                                               _Float16* __restrict__ xh) {
  int i = blockIdx.x * 256 + threadIdx.x;  // 524288 float4 units
  int r = i >> 8;
  int c4 = i & 255;
  int b = r & 31, t = r >> 5;
  int tok = dec[b * 64 + t];
  float4 v = ((const float4*)(emb + (size_t)tok * 1024))[c4];
  v.x = fmaxf(v.x, 0.f); v.y = fmaxf(v.y, 0.f); v.z = fmaxf(v.z, 0.f); v.w = fmaxf(v.w, 0.f);
  ((float4*)(xf + (size_t)r * 1024))[c4] = v;
  f16x4 o;
  o.x = (_Float16)v.x; o.y = (_Float16)v.y; o.z = (_Float16)v.z; o.w = (_Float16)v.w;
  ((f16x4*)(xh + (size_t)r * 1024))[c4] = o;
}

// ---------------- state init (+ barrier reset) ----------------
__global__ __launch_bounds__(256) void k_init(const float* __restrict__ h0, const float* __restrict__ c0,
                                              float* __restrict__ c,
                                              _Float16* __restrict__ h0B, _Float16* __restrict__ h1B,
                                              int* __restrict__ bar) {
  int i = blockIdx.x * 256 + threadIdx.x;  // 65536
  float hv = h0[i];
  c[i] = c0[i];
  if (i < 32768) h0B[i] = (_Float16)hv;
  else           h1B[i - 32768] = (_Float16)hv;
  if (i < 576) bar[i] = 0;
}

// ---------------- tiled MFMA GEMM: C[M,N] = A[M,1024] * B[N,1024]^T ----------------
template <int MODE>
__global__ __launch_bounds__(256) void k_gemm(const _Float16* __restrict__ A,
                                              const _Float16* __restrict__ Bm,
                                              const float* __restrict__ bias0,
                                              const float* __restrict__ bias1,
                                              float* __restrict__ C) {
  __shared__ _Float16 As[4 * 128 * 8];
  __shared__ _Float16 Bs[4 * 128 * 8];
  const int tid = threadIdx.x;
  const int lane = tid & 63;
  const int w = tid >> 6;
  const int wm = w >> 1, wn = w & 1;
  const _Float16* Ab = A + (size_t)blockIdx.y * 128 * 1024;
  const _Float16* Bb = Bm + (size_t)blockIdx.x * 128 * 1024;
  f32x4 acc[4][4] = {};
  for (int kc = 0; kc < 32; ++kc) {
#pragma unroll
    for (int ii = 0; ii < 2; ++ii) {
      int idx = tid + ii * 256;
      int kb = idx >> 7, row = idx & 127;
      int gofs = row * 1024 + kc * 32 + kb * 8;
      int sofs = kb * 1024 + row * 8;
      *(f16x8*)(As + sofs) = *(const f16x8*)(Ab + gofs);
      *(f16x8*)(Bs + sofs) = *(const f16x8*)(Bb + gofs);
    }
    __syncthreads();
    const int kb = lane >> 4;
    f16x8 af[4], bfv[4];
#pragma unroll
    for (int mf = 0; mf < 4; ++mf) {
      int row = wm * 64 + mf * 16 + (lane & 15);
      af[mf] = *(const f16x8*)(As + kb * 1024 + row * 8);
    }
#pragma unroll
    for (int nf = 0; nf < 4; ++nf) {
      int row = wn * 64 + nf * 16 + (lane & 15);
      bfv[nf] = *(const f16x8*)(Bs + kb * 1024 + row * 8);
    }
#pragma unroll
    for (int mf = 0; mf < 4; ++mf)
#pragma unroll
      for (int nf = 0; nf < 4; ++nf)
        acc[mf][nf] = __builtin_amdgcn_mfma_f32_16x16x32_f16(af[mf], bfv[nf], acc[mf][nf], 0, 0, 0);
    __syncthreads();
  }
  const int rl = (lane >> 4) * 4;
#pragma unroll
  for (int mf = 0; mf < 4; ++mf) {
#pragma unroll
    for (int nf = 0; nf < 4; ++nf) {
#pragma unroll
      for (int j = 0; j < 4; ++j) {
        int m = wm * 64 + mf * 16 + rl + j;
        int n = wn * 64 + nf * 16 + (lane & 15);
        int rg = blockIdx.y * 128 + m;
        int ng = blockIdx.x * 128 + n;
        float v = acc[mf][nf][j];
        if constexpr (MODE == 0) {
          C[(size_t)rg * 8192 + ng] = v + bias0[ng] + bias1[ng];
        } else {
          int tt = rg >> 5, b = rg & 31;
          C[(size_t)(b * 64 + tt) * 32000 + ng] = v + bias0[ng];
        }
      }
    }
  }
}

// ---------------- two-level tree barrier (RELAXED-only, no cache maintenance) ----------------
__device__ __forceinline__ void gbar(int* bar) {
  __syncthreads();
  if (threadIdx.x == 0) {
    int* gen = bar + 544;
    int g = ALOAD(gen);
    int grp = blockIdx.x >> 3;
    int a = __hip_atomic_fetch_add(bar + grp * 32, 1, __ATOMIC_RELAXED, __HIP_MEMORY_SCOPE_AGENT);
    if (a == 7) {
      ASTORE(bar + grp * 32, 0);
      int r = __hip_atomic_fetch_add(bar + 512, 1, __ATOMIC_RELAXED, __HIP_MEMORY_SCOPE_AGENT);
      if (r == 15) {
        ASTORE(bar + 512, 0);
        ASTORE(gen, g + 1);
      }
    }
    while (ALOAD(gen) == g) __builtin_amdgcn_s_sleep(2);
  }
  __syncthreads();
}

// ---------------- persistent pipelined LSTM (weights pinned in registers) ----------------
// 128 blocks x 512 threads (8 waves). Phase p: blocks 0..63 = layer0 of t=p;
// blocks 64..127 = layer1 of t=p-1. Wave kh = K-slice; all 4 gates per wave.
// Packed weights are loaded ONCE into VGPRs (role0: 16 frags=64 VGPR, role1: 32=128)
// -> zero per-phase weight memory traffic. State exchange via sc1 agent atomics.
template <int ROLE>
__device__ __forceinline__ void run_phases(
    int jb, const _Float16* __restrict__ Pk,
    const float* __restrict__ gx, const float* __restrict__ x_f,
    float* __restrict__ c_f,
    _Float16* __restrict__ h0A, _Float16* __restrict__ h0B,
    _Float16* __restrict__ h1A, _Float16* __restrict__ h1B,
    float* __restrict__ ipfA, float* __restrict__ ipfB,
    float* __restrict__ outs_f, _Float16* __restrict__ outs_h,
    float* __restrict__ outHT, float* __restrict__ outCT,
    int* bar, _Float16* As) {
  constexpr int S = ROLE ? 8 : 4;        // steps per wave (32 k each)
  constexpr int NHALF = ROLE ? 2 : 1;    // state staged in halves of 8 fragments
  constexpr int RSH = ROLE ? 8 : 7;      // log2(frag-cols per row)
  constexpr int K8M = ROLE ? 255 : 127;
  const int u0 = jb * 16;
  const int tid = threadIdx.x;
  const int lane = tid & 63;
  const int kh = tid >> 6;               // wave = K-slice
  const int col = lane & 15;
  const int kslot = lane >> 4;

  float* cst = c_f + ROLE * 32768;
  const float* gxbase = gx + (ROLE ? 4096 : 0);
  const int cb = tid >> 4, cul = tid & 15, cu = u0 + cul;

  const _Float16* pkbase = Pk + ((size_t)(jb * 8 + kh) * S) * 4 * 512 + lane * 8;
  const int a0off = col * 2056 + kh * S * 32 + kslot * 8;
  const int a1off = a0off + 16 * 2056;

  // ---- preload ALL weight fragments for this wave into registers (once) ----
  f16x8 wreg[S * 4];
#pragma unroll
  for (int i = 0; i < S * 4; ++i) wreg[i] = *(const f16x8*)(pkbase + i * 512);

  for (int p = 0; p <= 64; ++p) {
    const bool active = (ROLE == 0) ? (p < 64) : (p > 0);
    if (active) {
      const int t = (ROLE == 0) ? p : p - 1;
      const _Float16 *h0r, *h1r;
      _Float16 *h0w, *h1w;
      const float* ipfr; float* ipfw;
      if (p & 1) { h0r = h0A; h0w = h0B; ipfr = ipfA; ipfw = ipfB; h1r = h1B; h1w = h1A; }
      else       { h0r = h0B; h0w = h0A; ipfr = ipfB; ipfw = ipfA; h1r = h1A; h1w = h1B; }

      // ---- prefetch cell inputs ----
      const float* gxr = gxbase + (size_t)(t * 32 + cb) * 8192;
      float pg0 = gxr[cu], pg1 = gxr[1024 + cu], pg2 = gxr[2048 + cu], pg3 = gxr[3072 + cu];
      float pc = cst[cb * 1024 + cu];
      float px = 0.f, pip = 0.f;
      if (ROLE == 0) px = x_f[(size_t)(t * 32 + cb) * 1024 + cu];
      else           pip = ALOAD(ipfr + cb * 1024 + cu);

      // ---- state -> LDS in halves of 8 fragments (sc1 loads, bounded reg pressure) ----
#pragma unroll
      for (int hf = 0; hf < NHALF; ++hf) {
        u64 sreg[16];
#pragma unroll
        for (int i = 0; i < 8; ++i) {
          int fr = (hf * 8 + i) * 512 + tid;
          int row = fr >> RSH, k8 = fr & K8M;
          const _Float16* s;
          if (ROLE == 0) s = h0r + row * 1024 + k8 * 8;
          else           s = (k8 < 128) ? (h0r + row * 1024 + k8 * 8)
                                        : (h1r + row * 1024 + (k8 - 128) * 8);
          const u64* qq = (const u64*)s;
          sreg[2 * i]     = ALOAD(qq);
          sreg[2 * i + 1] = ALOAD(qq + 1);
        }
#pragma unroll
        for (int i = 0; i < 8; ++i) {
          int fr = (hf * 8 + i) * 512 + tid;
          int row = fr >> RSH, k8 = fr & K8M;
          u64* d = (u64*)(As + row * 2056 + k8 * 8);
          d[0] = sreg[2 * i];
          d[1] = sreg[2 * i + 1];
        }
      }
      __syncthreads();

      // ---- MFMA: pure registers for B, LDS for A ----
      f32x4 acc[2][4] = {};
#pragma unroll
      for (int s2 = 0; s2 < S; ++s2) {
        f16x8 a0 = *(const f16x8*)(As + a0off + s2 * 32);
        f16x8 a1 = *(const f16x8*)(As + a1off + s2 * 32);
        acc[0][0] = __builtin_amdgcn_mfma_f32_16x16x32_f16(a0, wreg[s2 * 4 + 0], acc[0][0], 0, 0, 0);
        acc[1][0] = __builtin_amdgcn_mfma_f32_16x16x32_f16(a1, wreg[s2 * 4 + 0], acc[1][0], 0, 0, 0);
        acc[0][1] = __builtin_amdgcn_mfma_f32_16x16x32_f16(a0, wreg[s2 * 4 + 1], acc[0][1], 0, 0, 0);
        acc[1][1] = __builtin_amdgcn_mfma_f32_16x16x32_f16(a1, wreg[s2 * 4 + 1], acc[1][1], 0, 0, 0);
        acc[0][2] = __builtin_amdgcn_mfma_f32_16x16x32_f16(a0, wreg[s2 * 4 + 2], acc[0][2], 0, 0, 0);
        acc[1][2] = __builtin_amdgcn_mfma_f32_16x16x32_f16(a1, wreg[s2 * 4 + 2], acc[1][2], 0, 0, 0);
        acc[0][3] = __builtin_amdgcn_mfma_f32_16x16x32_f16(a0, wreg[s2 * 4 + 3], acc[0][3], 0, 0, 0);
        acc[1][3] = __builtin_amdgcn_mfma_f32_16x16x32_f16(a1, wreg[s2 * 4 + 3], acc[1][3], 0, 0, 0);
      }
      __syncthreads();

      // ---- reduce 8 wave-partials via 4 LDS copies (overlay on As) ----
      float (*gs)[32][68] = (float (*)[32][68])(void*)As;
      const int rl = kslot * 4;
      if (kh < 4) {
#pragma unroll
        for (int m = 0; m < 2; ++m)
#pragma unroll
          for (int g = 0; g < 4; ++g)
#pragma unroll
            for (int j = 0; j < 4; ++j)
              gs[kh][m * 16 + rl + j][g * 16 + col] = acc[m][g][j];
      }
      __syncthreads();
      if (kh >= 4) {
#pragma unroll
        for (int m = 0; m < 2; ++m)
#pragma unroll
          for (int g = 0; g < 4; ++g)
#pragma unroll
            for (int j = 0; j < 4; ++j)
              gs[kh - 4][m * 16 + rl + j][g * 16 + col] += acc[m][g][j];
      }
      __syncthreads();

      // ---- fused cell: one thread per (batch cb, unit cul) ----
      {
        float ig = pg0, fg = pg1, gg = pg2, og = pg3;
#pragma unroll
        for (int cc = 0; cc < 4; ++cc) {
          ig += gs[cc][cb][cul];
          fg += gs[cc][cb][16 + cul];
          gg += gs[cc][cb][32 + cul];
          og += gs[cc][cb][48 + cul];
        }
        float si = 1.f / (1.f + expf(-ig));
        float sf = 1.f / (1.f + expf(-fg));
        float so = 1.f / (1.f + expf(-og));
        float ci = sf * pc + si * tanhf(gg);
        float hi = so * tanhf(ci);
        cst[cb * 1024 + cu] = ci;
        if (t == 63) {
          outHT[ROLE * 32768 + cb * 1024 + cu] = hi;
          outCT[ROLE * 32768 + cb * 1024 + cu] = ci;
        }
        if (ROLE == 0) {
          float hn = __shfl_down(hi, 1);
          float ipv = hi + px;
          float ipn = __shfl_down(ipv, 1);
          if ((cul & 1) == 0) {
            union { _Float16 h[2]; u32 v; } ph;
            ph.h[0] = (_Float16)hi; ph.h[1] = (_Float16)hn;
            ASTORE((u32*)(h0w + cb * 1024 + cu), ph.v);
            union { float f[2]; u64 v; } pi;
            pi.f[0] = ipv; pi.f[1] = ipn;
            ASTORE((u64*)(ipfw + cb * 1024 + cu), pi.v);
          }
        } else {
          float hn = __shfl_down(hi, 1);
          if ((cul & 1) == 0) {
            union { _Float16 h[2]; u32 v; } ph;
            ph.h[0] = (_Float16)hi; ph.h[1] = (_Float16)hn;
            ASTORE((u32*)(h1w + cb * 1024 + cu), ph.v);
          }
          float ro = hi + pip;
          outs_f[(size_t)(t * 32 + cb) * 1024 + cu] = ro;
          outs_h[(size_t)(t * 32 + cb) * 1024 + cu] = (_Float16)ro;
        }
      }
    }
    if (p < 64) gbar(bar);
  }
}

__global__ __launch_bounds__(512, 1) void k_lstm_persist(
    const _Float16* __restrict__ Pk0, const _Float16* __restrict__ Pk1,
    const float* __restrict__ gx, const float* __restrict__ x_f,
    float* __restrict__ c_f,
    _Float16* __restrict__ h0A, _Float16* __restrict__ h0B,
    _Float16* __restrict__ h1A, _Float16* __restrict__ h1B,
    float* __restrict__ ipfA, float* __restrict__ ipfB,
    float* __restrict__ outs_f, _Float16* __restrict__ outs_h,
    float* __restrict__ outHT, float* __restrict__ outCT,
    int* bar) {
  __shared__ _Float16 As[32 * 2056];  // 131,584 B; gs overlaid after MFMA phase
  const int jb = blockIdx.x & 63;
  if (blockIdx.x < 64)
    run_phases<0>(jb, Pk0, gx, x_f, c_f, h0A, h0B, h1A, h1B,
                  ipfA, ipfB, outs_f, outs_h, outHT, outCT, bar, As);
  else
    run_phases<1>(jb, Pk1, gx, x_f, c_f, h0A, h0B, h1A, h1B,
                  ipfA, ipfB, outs_f, outs_h, outHT, outCT, bar, As);
}

// ---------------- batched dot-attention + softmax ----------------
__global__ __launch_bounds__(256) void k_attn(const float* __restrict__ outs,
                                              const float* __restrict__ enc,
                                              float* __restrict__ att) {
  __shared__ float o_s[8][1024];
  __shared__ float sc[8][128];
  const int tid = threadIdx.x;
  const int lane = tid & 63;
  const int w = tid >> 6;
  const int b = blockIdx.x >> 3;
  const int t0 = (blockIdx.x & 7) * 8;
#pragma unroll
  for (int ii = 0; ii < 8; ++ii) {
    int idx = tid + ii * 256;
    int tt = idx >> 8, c4 = idx & 255;
    ((float4*)&o_s[tt][0])[c4] =
        *(const float4*)(outs + (size_t)((t0 + tt) * 32 + b) * 1024 + (size_t)c4 * 4);
  }
  __syncthreads();
  for (int si = 0; si < 32; ++si) {
    int s = w * 32 + si;
    float av[8] = {0, 0, 0, 0, 0, 0, 0, 0};
    const float* er = enc + (size_t)(b * 128 + s) * 1024;
#pragma unroll
    for (int i = 0; i < 4; ++i) {
      int k = i * 256 + lane * 4;
      float4 e = *(const float4*)(er + k);
#pragma unroll
      for (int tt = 0; tt < 8; ++tt) {
        float4 o = *(const float4*)&o_s[tt][k];
        av[tt] += e.x * o.x + e.y * o.y + e.z * o.z + e.w * o.w;
      }
    }
#pragma unroll
    for (int tt = 0; tt < 8; ++tt) {
      float v = av[tt];
#pragma unroll
      for (int off = 32; off > 0; off >>= 1) v += __shfl_down(v, off);
      if (lane == 0) sc[tt][s] = v;
    }
  }
  __syncthreads();
#pragma unroll
  for (int pp = 0; pp < 2; ++pp) {
    int tt = w + pp * 4;
    float a = sc[tt][lane], b2 = sc[tt][64 + lane];
    float m = fmaxf(a, b2);
#pragma unroll
    for (int off = 32; off > 0; off >>= 1) m = fmaxf(m, __shfl_xor(m, off));
    float e0 = expf(a - m), e1 = expf(b2 - m);
    float ss = e0 + e1;
#pragma unroll
    for (int off = 32; off > 0; off >>= 1) ss += __shfl_xor(ss, off);
    float r = 1.f / ss;
    att[(size_t)b * 8192 + (size_t)lane * 64 + t0 + tt] = e0 * r;
    att[(size_t)b * 8192 + (size_t)(64 + lane) * 64 + t0 + tt] = e1 * r;
  }
}

extern "C" void kernel_launch(void* const* d_in, const int* in_sizes, int n_in,
                              void* d_out, int out_size, void* d_ws, size_t ws_size,
                              hipStream_t stream) {
  const int*   dec   = (const int*)d_in[0];
  const float* h0    = (const float*)d_in[1];
  const float* c0    = (const float*)d_in[2];
  const float* enc   = (const float*)d_in[3];
  const float* emb   = (const float*)d_in[4];
  const float* W_ih  = (const float*)d_in[5];
  const float* W_hh  = (const float*)d_in[6];
  const float* b_ih  = (const float*)d_in[7];
  const float* b_hh  = (const float*)d_in[8];
  const float* cls_W = (const float*)d_in[9];
  const float* cls_b = (const float*)d_in[10];
  float* out = (float*)d_out;
  char* ws = (char*)d_ws;

  float*    x_f    = (float*)(ws + 0);                // [2048][1024] f32
  _Float16* x_h    = (_Float16*)(ws + 8388608);       // [2048][1024] f16 (dead after gx gemm)
  _Float16* Pk0    = (_Float16*)(ws + 8388608);       // 8MB packed Whh0 (written AFTER gx gemm)
  _Float16* Wih_h  = (_Float16*)(ws + 12582912);      // [8192][1024] f16 (dead after gx gemm)
  _Float16* Pk1    = (_Float16*)(ws + 29360128);      // 16MB packed [Wih1|Whh1]
  _Float16* clsW_h = (_Float16*)(ws + 46137344);      // [32000][1024] f16
  float*    gx     = (float*)(ws + 111673344);        // [2048][8192] f32
  float*    outs_f = (float*)(ws + 178782208);        // [2048][1024] f32
  _Float16* outs_h = (_Float16*)(ws + 187170816);     // [2048][1024] f16
  float*    c_f    = (float*)(ws + 191627264);        // [2][32][1024] f32
  _Float16* h0A    = (_Float16*)(ws + 191889408);     // [32][1024] f16
  _Float16* h0B    = (_Float16*)(ws + 191954944);
  _Float16* h1A    = (_Float16*)(ws + 192020480);
  _Float16* h1B    = (_Float16*)(ws + 192086016);
  int*      bar    = (int*)(ws + 192151552);          // 576 ints (tree barrier)
  float*    ipfA   = (float*)(ws + 192155648);        // [32][1024] f32
  float*    ipfB   = (float*)(ws + 192286720);        // end 192417792

  k_f32_to_f16<<<2048, 256, 0, stream>>>(W_ih, Wih_h, 2097152);
  k_f32_to_f16<<<4096, 256, 0, stream>>>(cls_W, clsW_h, 8192000);
  k_embed<<<2048, 256, 0, stream>>>(dec, emb, x_f, x_h);
  k_init<<<256, 256, 0, stream>>>(h0, c0, c_f, h0B, h1B, bar);
  k_pack1<<<4096, 256, 0, stream>>>(W_ih + (size_t)4096 * 1024, W_hh + (size_t)4096 * 1024, Pk1);
  // gx[r][0:4096] = x@Wih0^T + b_ih0 + b_hh0 ; gx[r][4096:8192] = x@Wih1^T + b_ih1 + b_hh1
  k_gemm<0><<<dim3(64, 16), 256, 0, stream>>>(x_h, Wih_h, b_ih, b_hh, gx);
  k_pack0<<<2048, 256, 0, stream>>>(W_hh, Pk0);  // after gemm<0>: overwrites x_h/Wih_h region

  k_lstm_persist<<<128, 512, 0, stream>>>(Pk0, Pk1, gx, x_f, c_f,
                                          h0A, h0B, h1A, h1B, ipfA, ipfB,
                                          outs_f, outs_h,
                                          out + (size_t)65536000, out + (size_t)65601536,
                                          bar);

  k_attn<<<256, 256, 0, stream>>>(outs_f, enc, out + (size_t)65667072);
  k_gemm<1><<<dim3(250, 16), 256, 0, stream>>>(outs_h, clsW_h, cls_b, (const float*)nullptr, out);
}

// Round 7
// 894.130 us; speedup vs baseline: 2.0373x; 1.1114x over previous
//
#include <hip/hip_runtime.h>
#include <math.h>

typedef _Float16 f16x8 __attribute__((ext_vector_type(8)));
typedef _Float16 f16x4 __attribute__((ext_vector_type(4)));
typedef float    f32x4 __attribute__((ext_vector_type(4)));
typedef unsigned long long u64;
typedef unsigned int u32;

#define ALOAD(p)    __hip_atomic_load((p), __ATOMIC_RELAXED, __HIP_MEMORY_SCOPE_AGENT)
#define ASTORE(p,v) __hip_atomic_store((p), (v), __ATOMIC_RELAXED, __HIP_MEMORY_SCOPE_AGENT)

// ---------------- conversion f32 -> f16 ----------------
__global__ __launch_bounds__(256) void k_f32_to_f16(const float* __restrict__ src,
                                                    _Float16* __restrict__ dst, int n4) {
  int i = blockIdx.x * 256 + threadIdx.x;
  int stride = gridDim.x * 256;
  for (; i < n4; i += stride) {
    float4 v = ((const float4*)src)[i];
    f16x4 o;
    o.x = (_Float16)v.x; o.y = (_Float16)v.y; o.z = (_Float16)v.z; o.w = (_Float16)v.w;
    ((f16x4*)dst)[i] = o;
  }
}

// ---------------- weight packing into per-wave fragment-stream order ----------------
__global__ __launch_bounds__(256) void k_pack0(const float* __restrict__ Whh0,
                                               _Float16* __restrict__ P) {
  int li = blockIdx.x * 256 + threadIdx.x;  // 524288
  int row = li >> 7, k8 = li & 127;
  const float* s = Whh0 + (size_t)row * 1024 + k8 * 8;
  int g = row >> 10, u = row & 1023, jb = u >> 4, col = u & 15;
  int kh = k8 >> 4, rem = k8 & 15, st = rem >> 2, kslot = rem & 3;
  size_t idx = ((size_t)(((jb * 8 + kh) * 4 + st) * 4 + g)) * 64 + kslot * 16 + col;
  f16x8 o;
#pragma unroll
  for (int j = 0; j < 8; ++j) o[j] = (_Float16)s[j];
  *(f16x8*)(P + idx * 8) = o;
}

__global__ __launch_bounds__(256) void k_pack1(const float* __restrict__ Wih1,
                                               const float* __restrict__ Whh1,
                                               _Float16* __restrict__ P) {
  int li = blockIdx.x * 256 + threadIdx.x;  // 1048576
  int mat = li >> 19;
  int li2 = li & 524287;
  int row = li2 >> 7, k8l = li2 & 127;
  const float* s = (mat ? Whh1 : Wih1) + (size_t)row * 1024 + k8l * 8;
  int g = row >> 10, u = row & 1023, jb = u >> 4, col = u & 15;
  int k8g = mat * 128 + k8l;
  int kh = k8g >> 5, rem = k8g & 31, st = rem >> 2, kslot = rem & 3;
  size_t idx = ((size_t)(((jb * 8 + kh) * 8 + st) * 4 + g)) * 64 + kslot * 16 + col;
  f16x8 o;
#pragma unroll
  for (int j = 0; j < 8; ++j) o[j] = (_Float16)s[j];
  *(f16x8*)(P + idx * 8) = o;
}

// ---------------- embedding + relu ----------------
__global__ __launch_bounds__(256) void k_embed(const int* __restrict__ dec,
                                               const float* __restrict__ emb,
                                               float* __restrict__ xf,
                                               _Float16* __restrict__ xh) {
  int i = blockIdx.x * 256 + threadIdx.x;  // 524288 float4 units
  int r = i >> 8;
  int c4 = i & 255;
  int b = r & 31, t = r >> 5;
  int tok = dec[b * 64 + t];
  float4 v = ((const float4*)(emb + (size_t)tok * 1024))[c4];
  v.x = fmaxf(v.x, 0.f); v.y = fmaxf(v.y, 0.f); v.z = fmaxf(v.z, 0.f); v.w = fmaxf(v.w, 0.f);
  ((float4*)(xf + (size_t)r * 1024))[c4] = v;
  f16x4 o;
  o.x = (_Float16)v.x; o.y = (_Float16)v.y; o.z = (_Float16)v.z; o.w = (_Float16)v.w;
  ((f16x4*)(xh + (size_t)r * 1024))[c4] = o;
}

// ---------------- state init (+ barrier reset) ----------------
__global__ __launch_bounds__(256) void k_init(const float* __restrict__ h0, const float* __restrict__ c0,
                                              float* __restrict__ c,
                                              _Float16* __restrict__ h0B, _Float16* __restrict__ h1B,
                                              int* __restrict__ bar) {
  int i = blockIdx.x * 256 + threadIdx.x;  // 65536
  float hv = h0[i];
  c[i] = c0[i];
  if (i < 32768) h0B[i] = (_Float16)hv;
  else           h1B[i - 32768] = (_Float16)hv;
  if (i < 576) bar[i] = 0;
}

// ---------------- tiled MFMA GEMM (gx precompute): C = A*B^T + biases ----------------
__global__ __launch_bounds__(256) void k_gemm0(const _Float16* __restrict__ A,
                                               const _Float16* __restrict__ Bm,
                                               const float* __restrict__ bias0,
                                               const float* __restrict__ bias1,
                                               float* __restrict__ C) {
  __shared__ _Float16 As[4 * 128 * 8];
  __shared__ _Float16 Bs[4 * 128 * 8];
  const int tid = threadIdx.x;
  const int lane = tid & 63;
  const int w = tid >> 6;
  const int wm = w >> 1, wn = w & 1;
  const _Float16* Ab = A + (size_t)blockIdx.y * 128 * 1024;
  const _Float16* Bb = Bm + (size_t)blockIdx.x * 128 * 1024;
  f32x4 acc[4][4] = {};
  for (int kc = 0; kc < 32; ++kc) {
#pragma unroll
    for (int ii = 0; ii < 2; ++ii) {
      int idx = tid + ii * 256;
      int kb = idx >> 7, row = idx & 127;
      int gofs = row * 1024 + kc * 32 + kb * 8;
      int sofs = kb * 1024 + row * 8;
      *(f16x8*)(As + sofs) = *(const f16x8*)(Ab + gofs);
      *(f16x8*)(Bs + sofs) = *(const f16x8*)(Bb + gofs);
    }
    __syncthreads();
    const int kb = lane >> 4;
    f16x8 af[4], bfv[4];
#pragma unroll
    for (int mf = 0; mf < 4; ++mf) {
      int row = wm * 64 + mf * 16 + (lane & 15);
      af[mf] = *(const f16x8*)(As + kb * 1024 + row * 8);
    }
#pragma unroll
    for (int nf = 0; nf < 4; ++nf) {
      int row = wn * 64 + nf * 16 + (lane & 15);
      bfv[nf] = *(const f16x8*)(Bs + kb * 1024 + row * 8);
    }
#pragma unroll
    for (int mf = 0; mf < 4; ++mf)
#pragma unroll
      for (int nf = 0; nf < 4; ++nf)
        acc[mf][nf] = __builtin_amdgcn_mfma_f32_16x16x32_f16(af[mf], bfv[nf], acc[mf][nf], 0, 0, 0);
    __syncthreads();
  }
  const int rl = (lane >> 4) * 4;
#pragma unroll
  for (int mf = 0; mf < 4; ++mf) {
#pragma unroll
    for (int nf = 0; nf < 4; ++nf) {
#pragma unroll
      for (int j = 0; j < 4; ++j) {
        int m = wm * 64 + mf * 16 + rl + j;
        int n = wn * 64 + nf * 16 + (lane & 15);
        int rg = blockIdx.y * 128 + m;
        int ng = blockIdx.x * 128 + n;
        C[(size_t)rg * 8192 + ng] = acc[mf][nf][j] + bias0[ng] + bias1[ng];
      }
    }
  }
}

// ---------------- two-level tree barrier (RELAXED-only) ----------------
__device__ __forceinline__ void gbar(int* bar) {
  __syncthreads();
  if (threadIdx.x == 0) {
    int* gen = bar + 544;
    int g = ALOAD(gen);
    int grp = blockIdx.x >> 3;
    int a = __hip_atomic_fetch_add(bar + grp * 32, 1, __ATOMIC_RELAXED, __HIP_MEMORY_SCOPE_AGENT);
    if (a == 7) {
      ASTORE(bar + grp * 32, 0);
      int r = __hip_atomic_fetch_add(bar + 512, 1, __ATOMIC_RELAXED, __HIP_MEMORY_SCOPE_AGENT);
      if (r == 15) {
        ASTORE(bar + 512, 0);
        ASTORE(gen, g + 1);
      }
    }
    while (ALOAD(gen) == g) __builtin_amdgcn_s_sleep(2);
  }
  __syncthreads();
}

// ---------------- persistent LSTM phases (blocks 0..127) ----------------
template <int ROLE>
__device__ __forceinline__ void run_phases(
    int jb, const _Float16* __restrict__ Pk,
    const float* __restrict__ gx, const float* __restrict__ x_f,
    float* __restrict__ c_f,
    _Float16* __restrict__ h0A, _Float16* __restrict__ h0B,
    _Float16* __restrict__ h1A, _Float16* __restrict__ h1B,
    float* __restrict__ ipfA, float* __restrict__ ipfB,
    float* __restrict__ outs_f, _Float16* __restrict__ outs_h,
    float* __restrict__ outHT, float* __restrict__ outCT,
    int* bar, _Float16* As) {
  constexpr int S = ROLE ? 8 : 4;
  constexpr int NHALF = ROLE ? 2 : 1;
  constexpr int RSH = ROLE ? 8 : 7;
  constexpr int K8M = ROLE ? 255 : 127;
  const int u0 = jb * 16;
  const int tid = threadIdx.x;
  const int lane = tid & 63;
  const int kh = tid >> 6;
  const int col = lane & 15;
  const int kslot = lane >> 4;

  float* cst = c_f + ROLE * 32768;
  const float* gxbase = gx + (ROLE ? 4096 : 0);
  const int cb = tid >> 4, cul = tid & 15, cu = u0 + cul;

  const _Float16* pkbase = Pk + ((size_t)(jb * 8 + kh) * S) * 4 * 512 + lane * 8;
  const int a0off = col * 2056 + kh * S * 32 + kslot * 8;
  const int a1off = a0off + 16 * 2056;

  // weights pinned in registers for the whole recurrence
  f16x8 wreg[S * 4];
#pragma unroll
  for (int i = 0; i < S * 4; ++i) wreg[i] = *(const f16x8*)(pkbase + i * 512);

  for (int p = 0; p <= 64; ++p) {
    const bool active = (ROLE == 0) ? (p < 64) : (p > 0);
    if (active) {
      const int t = (ROLE == 0) ? p : p - 1;
      const _Float16 *h0r, *h1r;
      _Float16 *h0w, *h1w;
      const float* ipfr; float* ipfw;
      if (p & 1) { h0r = h0A; h0w = h0B; ipfr = ipfA; ipfw = ipfB; h1r = h1B; h1w = h1A; }
      else       { h0r = h0B; h0w = h0A; ipfr = ipfB; ipfw = ipfA; h1r = h1A; h1w = h1B; }

      const float* gxr = gxbase + (size_t)(t * 32 + cb) * 8192;
      float pg0 = gxr[cu], pg1 = gxr[1024 + cu], pg2 = gxr[2048 + cu], pg3 = gxr[3072 + cu];
      float pc = cst[cb * 1024 + cu];
      float px = 0.f, pip = 0.f;
      if (ROLE == 0) px = x_f[(size_t)(t * 32 + cb) * 1024 + cu];
      else           pip = ALOAD(ipfr + cb * 1024 + cu);

#pragma unroll
      for (int hf = 0; hf < NHALF; ++hf) {
        u64 sreg[16];
#pragma unroll
        for (int i = 0; i < 8; ++i) {
          int fr = (hf * 8 + i) * 512 + tid;
          int row = fr >> RSH, k8 = fr & K8M;
          const _Float16* s;
          if (ROLE == 0) s = h0r + row * 1024 + k8 * 8;
          else           s = (k8 < 128) ? (h0r + row * 1024 + k8 * 8)
                                        : (h1r + row * 1024 + (k8 - 128) * 8);
          const u64* qq = (const u64*)s;
          sreg[2 * i]     = ALOAD(qq);
          sreg[2 * i + 1] = ALOAD(qq + 1);
        }
#pragma unroll
        for (int i = 0; i < 8; ++i) {
          int fr = (hf * 8 + i) * 512 + tid;
          int row = fr >> RSH, k8 = fr & K8M;
          u64* d = (u64*)(As + row * 2056 + k8 * 8);
          d[0] = sreg[2 * i];
          d[1] = sreg[2 * i + 1];
        }
      }
      __syncthreads();

      f32x4 acc[2][4] = {};
#pragma unroll
      for (int s2 = 0; s2 < S; ++s2) {
        f16x8 a0 = *(const f16x8*)(As + a0off + s2 * 32);
        f16x8 a1 = *(const f16x8*)(As + a1off + s2 * 32);
        acc[0][0] = __builtin_amdgcn_mfma_f32_16x16x32_f16(a0, wreg[s2 * 4 + 0], acc[0][0], 0, 0, 0);
        acc[1][0] = __builtin_amdgcn_mfma_f32_16x16x32_f16(a1, wreg[s2 * 4 + 0], acc[1][0], 0, 0, 0);
        acc[0][1] = __builtin_amdgcn_mfma_f32_16x16x32_f16(a0, wreg[s2 * 4 + 1], acc[0][1], 0, 0, 0);
        acc[1][1] = __builtin_amdgcn_mfma_f32_16x16x32_f16(a1, wreg[s2 * 4 + 1], acc[1][1], 0, 0, 0);
        acc[0][2] = __builtin_amdgcn_mfma_f32_16x16x32_f16(a0, wreg[s2 * 4 + 2], acc[0][2], 0, 0, 0);
        acc[1][2] = __builtin_amdgcn_mfma_f32_16x16x32_f16(a1, wreg[s2 * 4 + 2], acc[1][2], 0, 0, 0);
        acc[0][3] = __builtin_amdgcn_mfma_f32_16x16x32_f16(a0, wreg[s2 * 4 + 3], acc[0][3], 0, 0, 0);
        acc[1][3] = __builtin_amdgcn_mfma_f32_16x16x32_f16(a1, wreg[s2 * 4 + 3], acc[1][3], 0, 0, 0);
      }
      __syncthreads();

      float (*gs)[32][68] = (float (*)[32][68])(void*)As;
      const int rl = kslot * 4;
      if (kh < 4) {
#pragma unroll
        for (int m = 0; m < 2; ++m)
#pragma unroll
          for (int g = 0; g < 4; ++g)
#pragma unroll
            for (int j = 0; j < 4; ++j)
              gs[kh][m * 16 + rl + j][g * 16 + col] = acc[m][g][j];
      }
      __syncthreads();
      if (kh >= 4) {
#pragma unroll
        for (int m = 0; m < 2; ++m)
#pragma unroll
          for (int g = 0; g < 4; ++g)
#pragma unroll
            for (int j = 0; j < 4; ++j)
              gs[kh - 4][m * 16 + rl + j][g * 16 + col] += acc[m][g][j];
      }
      __syncthreads();

      {
        float ig = pg0, fg = pg1, gg = pg2, og = pg3;
#pragma unroll
        for (int cc = 0; cc < 4; ++cc) {
          ig += gs[cc][cb][cul];
          fg += gs[cc][cb][16 + cul];
          gg += gs[cc][cb][32 + cul];
          og += gs[cc][cb][48 + cul];
        }
        float si = 1.f / (1.f + expf(-ig));
        float sf = 1.f / (1.f + expf(-fg));
        float so = 1.f / (1.f + expf(-og));
        float ci = sf * pc + si * tanhf(gg);
        float hi = so * tanhf(ci);
        cst[cb * 1024 + cu] = ci;
        if (t == 63) {
          outHT[ROLE * 32768 + cb * 1024 + cu] = hi;
          outCT[ROLE * 32768 + cb * 1024 + cu] = ci;
        }
        if (ROLE == 0) {
          float hn = __shfl_down(hi, 1);
          float ipv = hi + px;
          float ipn = __shfl_down(ipv, 1);
          if ((cul & 1) == 0) {
            union { _Float16 h[2]; u32 v; } ph;
            ph.h[0] = (_Float16)hi; ph.h[1] = (_Float16)hn;
            ASTORE((u32*)(h0w + cb * 1024 + cu), ph.v);
            union { float f[2]; u64 v; } pi;
            pi.f[0] = ipv; pi.f[1] = ipn;
            ASTORE((u64*)(ipfw + cb * 1024 + cu), pi.v);
          }
        } else {
          float hn = __shfl_down(hi, 1);
          float ro = hi + pip;
          float rn = __shfl_down(ro, 1);
          if ((cul & 1) == 0) {
            union { _Float16 h[2]; u32 v; } ph;
            ph.h[0] = (_Float16)hi; ph.h[1] = (_Float16)hn;
            ASTORE((u32*)(h1w + cb * 1024 + cu), ph.v);
            union { _Float16 h[2]; u32 v; } po;
            po.h[0] = (_Float16)ro; po.h[1] = (_Float16)rn;
            // sc1 write-through: consumers (logits GEMM blocks) read after gen bump
            ASTORE((u32*)(outs_h + (size_t)(t * 32 + cb) * 1024 + cu), po.v);
          }
          outs_f[(size_t)(t * 32 + cb) * 1024 + cu] = ro;
        }
      }
    }
    gbar(bar);  // every phase, incl. last -> gen ends at 65
  }
}

// ---------------- in-kernel logits GEMM consumers (blocks 128..255) ----------------
// Tile 128x256 (m-tile = 4 consecutive t's, ready when gen >= 4m+5). 2000 tiles.
__device__ __forceinline__ void run_consumer(
    int cb, const _Float16* __restrict__ outs_h, const _Float16* __restrict__ clsW_h,
    const float* __restrict__ cls_b, float* __restrict__ out, int* bar, _Float16* lds) {
  _Float16* As2 = lds;          // [4][128][8] = 4096 f16
  _Float16* Bs2 = lds + 4096;   // [4][256][8] = 8192 f16
  const int tid = threadIdx.x;
  const int lane = tid & 63;
  const int w = tid >> 6;
  const int wm = w >> 2, wn = w & 3;
  int* gen = bar + 544;
  const int akb = tid >> 7, arow = tid & 127;

  for (int tau = cb; tau < 2000; tau += 128) {
    int m = tau / 125, nt = tau - m * 125;
    if (tid == 0) {
      int need = 4 * m + 5;
      while (ALOAD(gen) < need) __builtin_amdgcn_s_sleep(8);
    }
    __syncthreads();
    const _Float16* Ab = outs_h + (size_t)m * 128 * 1024;
    const _Float16* Bb = clsW_h + (size_t)nt * 256 * 1024;
    f32x4 acc[4][4] = {};
    f16x8 pa, pb0, pb1;
    pa  = *(const f16x8*)(Ab + arow * 1024 + akb * 8);
    pb0 = *(const f16x8*)(Bb + (tid & 255) * 1024 + (tid >> 8) * 8);
    pb1 = *(const f16x8*)(Bb + (tid & 255) * 1024 + ((tid + 512) >> 8) * 8);
    for (int kc = 0; kc < 32; ++kc) {
      *(f16x8*)(As2 + akb * 1024 + arow * 8) = pa;
      *(f16x8*)(Bs2 + (tid >> 8) * 2048 + (tid & 255) * 8) = pb0;
      *(f16x8*)(Bs2 + ((tid + 512) >> 8) * 2048 + (tid & 255) * 8) = pb1;
      __syncthreads();
      if (kc + 1 < 32) {
        int ko = (kc + 1) * 32;
        pa  = *(const f16x8*)(Ab + arow * 1024 + ko + akb * 8);
        pb0 = *(const f16x8*)(Bb + (tid & 255) * 1024 + ko + (tid >> 8) * 8);
        pb1 = *(const f16x8*)(Bb + (tid & 255) * 1024 + ko + ((tid + 512) >> 8) * 8);
      }
      const int kb = lane >> 4;
      f16x8 af[4], bf[4];
#pragma unroll
      for (int mf = 0; mf < 4; ++mf) {
        int row = wm * 64 + mf * 16 + (lane & 15);
        af[mf] = *(const f16x8*)(As2 + kb * 1024 + row * 8);
      }
#pragma unroll
      for (int nf = 0; nf < 4; ++nf) {
        int row = wn * 64 + nf * 16 + (lane & 15);
        bf[nf] = *(const f16x8*)(Bs2 + kb * 2048 + row * 8);
      }
#pragma unroll
      for (int mf = 0; mf < 4; ++mf)
#pragma unroll
        for (int nf = 0; nf < 4; ++nf)
          acc[mf][nf] = __builtin_amdgcn_mfma_f32_16x16x32_f16(af[mf], bf[nf], acc[mf][nf], 0, 0, 0);
      __syncthreads();
    }
    const int rl = (lane >> 4) * 4;
#pragma unroll
    for (int mf = 0; mf < 4; ++mf) {
#pragma unroll
      for (int nf = 0; nf < 4; ++nf) {
#pragma unroll
        for (int j = 0; j < 4; ++j) {
          int rg = m * 128 + wm * 64 + mf * 16 + rl + j;
          int tt = rg >> 5, b = rg & 31;
          int ng = nt * 256 + wn * 64 + nf * 16 + (lane & 15);
          out[(size_t)(b * 64 + tt) * 32000 + ng] = acc[mf][nf][j] + cls_b[ng];
        }
      }
    }
  }
}

__global__ __launch_bounds__(512, 1) void k_lstm_fused(
    const _Float16* __restrict__ Pk0, const _Float16* __restrict__ Pk1,
    const float* __restrict__ gx, const float* __restrict__ x_f,
    float* __restrict__ c_f,
    _Float16* __restrict__ h0A, _Float16* __restrict__ h0B,
    _Float16* __restrict__ h1A, _Float16* __restrict__ h1B,
    float* __restrict__ ipfA, float* __restrict__ ipfB,
    float* __restrict__ outs_f, _Float16* __restrict__ outs_h,
    const _Float16* __restrict__ clsW_h, const float* __restrict__ cls_b,
    float* __restrict__ out_logits,
    float* __restrict__ outHT, float* __restrict__ outCT,
    int* bar) {
  __shared__ _Float16 As[32 * 2056];  // 131,584 B (forces 1 block/CU -> 256 blocks co-resident)
  const int bid = blockIdx.x;
  if (bid < 64)
    run_phases<0>(bid & 63, Pk0, gx, x_f, c_f, h0A, h0B, h1A, h1B,
                  ipfA, ipfB, outs_f, outs_h, outHT, outCT, bar, As);
  else if (bid < 128)
    run_phases<1>(bid & 63, Pk1, gx, x_f, c_f, h0A, h0B, h1A, h1B,
                  ipfA, ipfB, outs_f, outs_h, outHT, outCT, bar, As);
  else
    run_consumer(bid - 128, outs_h, clsW_h, cls_b, out_logits, bar, As);
}

// ---------------- batched dot-attention + softmax ----------------
__global__ __launch_bounds__(256) void k_attn(const float* __restrict__ outs,
                                              const float* __restrict__ enc,
                                              float* __restrict__ att) {
  __shared__ float o_s[8][1024];
  __shared__ float sc[8][128];
  const int tid = threadIdx.x;
  const int lane = tid & 63;
  const int w = tid >> 6;
  const int b = blockIdx.x >> 3;
  const int t0 = (blockIdx.x & 7) * 8;
#pragma unroll
  for (int ii = 0; ii < 8; ++ii) {
    int idx = tid + ii * 256;
    int tt = idx >> 8, c4 = idx & 255;
    ((float4*)&o_s[tt][0])[c4] =
        *(const float4*)(outs + (size_t)((t0 + tt) * 32 + b) * 1024 + (size_t)c4 * 4);
  }
  __syncthreads();
  for (int si = 0; si < 32; ++si) {
    int s = w * 32 + si;
    float av[8] = {0, 0, 0, 0, 0, 0, 0, 0};
    const float* er = enc + (size_t)(b * 128 + s) * 1024;
#pragma unroll
    for (int i = 0; i < 4; ++i) {
      int k = i * 256 + lane * 4;
      float4 e = *(const float4*)(er + k);
#pragma unroll
      for (int tt = 0; tt < 8; ++tt) {
        float4 o = *(const float4*)&o_s[tt][k];
        av[tt] += e.x * o.x + e.y * o.y + e.z * o.z + e.w * o.w;
      }
    }
#pragma unroll
    for (int tt = 0; tt < 8; ++tt) {
      float v = av[tt];
#pragma unroll
      for (int off = 32; off > 0; off >>= 1) v += __shfl_down(v, off);
      if (lane == 0) sc[tt][s] = v;
    }
  }
  __syncthreads();
#pragma unroll
  for (int pp = 0; pp < 2; ++pp) {
    int tt = w + pp * 4;
    float a = sc[tt][lane], b2 = sc[tt][64 + lane];
    float m = fmaxf(a, b2);
#pragma unroll
    for (int off = 32; off > 0; off >>= 1) m = fmaxf(m, __shfl_xor(m, off));
    float e0 = expf(a - m), e1 = expf(b2 - m);
    float ss = e0 + e1;
#pragma unroll
    for (int off = 32; off > 0; off >>= 1) ss += __shfl_xor(ss, off);
    float r = 1.f / ss;
    att[(size_t)b * 8192 + (size_t)lane * 64 + t0 + tt] = e0 * r;
    att[(size_t)b * 8192 + (size_t)(64 + lane) * 64 + t0 + tt] = e1 * r;
  }
}

extern "C" void kernel_launch(void* const* d_in, const int* in_sizes, int n_in,
                              void* d_out, int out_size, void* d_ws, size_t ws_size,
                              hipStream_t stream) {
  const int*   dec   = (const int*)d_in[0];
  const float* h0    = (const float*)d_in[1];
  const float* c0    = (const float*)d_in[2];
  const float* enc   = (const float*)d_in[3];
  const float* emb   = (const float*)d_in[4];
  const float* W_ih  = (const float*)d_in[5];
  const float* W_hh  = (const float*)d_in[6];
  const float* b_ih  = (const float*)d_in[7];
  const float* b_hh  = (const float*)d_in[8];
  const float* cls_W = (const float*)d_in[9];
  const float* cls_b = (const float*)d_in[10];
  float* out = (float*)d_out;
  char* ws = (char*)d_ws;

  float*    x_f    = (float*)(ws + 0);                // [2048][1024] f32
  _Float16* x_h    = (_Float16*)(ws + 8388608);       // [2048][1024] f16 (dead after gx gemm)
  _Float16* Pk0    = (_Float16*)(ws + 8388608);       // 8MB packed Whh0 (written AFTER gx gemm)
  _Float16* Wih_h  = (_Float16*)(ws + 12582912);      // [8192][1024] f16 (dead after gx gemm)
  _Float16* Pk1    = (_Float16*)(ws + 29360128);      // 16MB packed [Wih1|Whh1]
  _Float16* clsW_h = (_Float16*)(ws + 46137344);      // [32000][1024] f16
  float*    gx     = (float*)(ws + 111673344);        // [2048][8192] f32
  float*    outs_f = (float*)(ws + 178782208);        // [2048][1024] f32
  _Float16* outs_h = (_Float16*)(ws + 187170816);     // [2048][1024] f16
  float*    c_f    = (float*)(ws + 191627264);        // [2][32][1024] f32
  _Float16* h0A    = (_Float16*)(ws + 191889408);     // [32][1024] f16
  _Float16* h0B    = (_Float16*)(ws + 191954944);
  _Float16* h1A    = (_Float16*)(ws + 192020480);
  _Float16* h1B    = (_Float16*)(ws + 192086016);
  int*      bar    = (int*)(ws + 192151552);          // 576 ints (tree barrier + gen)
  float*    ipfA   = (float*)(ws + 192155648);        // [32][1024] f32
  float*    ipfB   = (float*)(ws + 192286720);        // end 192417792

  k_f32_to_f16<<<2048, 256, 0, stream>>>(W_ih, Wih_h, 2097152);
  k_f32_to_f16<<<4096, 256, 0, stream>>>(cls_W, clsW_h, 8192000);
  k_embed<<<2048, 256, 0, stream>>>(dec, emb, x_f, x_h);
  k_init<<<256, 256, 0, stream>>>(h0, c0, c_f, h0B, h1B, bar);
  k_pack1<<<4096, 256, 0, stream>>>(W_ih + (size_t)4096 * 1024, W_hh + (size_t)4096 * 1024, Pk1);
  // gx[r][0:4096] = x@Wih0^T + b_ih0 + b_hh0 ; gx[r][4096:8192] = x@Wih1^T + b_ih1 + b_hh1
  k_gemm0<<<dim3(64, 16), 256, 0, stream>>>(x_h, Wih_h, b_ih, b_hh, gx);
  k_pack0<<<2048, 256, 0, stream>>>(W_hh, Pk0);  // after gemm0: overwrites x_h/Wih_h region

  k_lstm_fused<<<256, 512, 0, stream>>>(Pk0, Pk1, gx, x_f, c_f,
                                        h0A, h0B, h1A, h1B, ipfA, ipfB,
                                        outs_f, outs_h, clsW_h, cls_b, out,
                                        out + (size_t)65536000, out + (size_t)65601536,
                                        bar);

  k_attn<<<256, 256, 0, stream>>>(outs_f, enc, out + (size_t)65667072);
}

// Round 8
// 851.635 us; speedup vs baseline: 2.1389x; 1.0499x over previous
//
#include <hip/hip_runtime.h>
#include <math.h>

typedef _Float16 f16x8 __attribute__((ext_vector_type(8)));
typedef _Float16 f16x4 __attribute__((ext_vector_type(4)));
typedef float    f32x4 __attribute__((ext_vector_type(4)));
typedef unsigned long long u64;
typedef unsigned int u32;

#define ALOAD(p)    __hip_atomic_load((p), __ATOMIC_RELAXED, __HIP_MEMORY_SCOPE_AGENT)
#define ASTORE(p,v) __hip_atomic_store((p), (v), __ATOMIC_RELAXED, __HIP_MEMORY_SCOPE_AGENT)

// ---------------- conversion f32 -> f16 ----------------
__global__ __launch_bounds__(256) void k_f32_to_f16(const float* __restrict__ src,
                                                    _Float16* __restrict__ dst, int n4) {
  int i = blockIdx.x * 256 + threadIdx.x;
  int stride = gridDim.x * 256;
  for (; i < n4; i += stride) {
    float4 v = ((const float4*)src)[i];
    f16x4 o;
    o.x = (_Float16)v.x; o.y = (_Float16)v.y; o.z = (_Float16)v.z; o.w = (_Float16)v.w;
    ((f16x4*)dst)[i] = o;
  }
}

// ---------------- weight packing into per-wave fragment-stream order ----------------
__global__ __launch_bounds__(256) void k_pack0(const float* __restrict__ Whh0,
                                               _Float16* __restrict__ P) {
  int li = blockIdx.x * 256 + threadIdx.x;  // 524288
  int row = li >> 7, k8 = li & 127;
  const float* s = Whh0 + (size_t)row * 1024 + k8 * 8;
  int g = row >> 10, u = row & 1023, jb = u >> 4, col = u & 15;
  int kh = k8 >> 4, rem = k8 & 15, st = rem >> 2, kslot = rem & 3;
  size_t idx = ((size_t)(((jb * 8 + kh) * 4 + st) * 4 + g)) * 64 + kslot * 16 + col;
  f16x8 o;
#pragma unroll
  for (int j = 0; j < 8; ++j) o[j] = (_Float16)s[j];
  *(f16x8*)(P + idx * 8) = o;
}

__global__ __launch_bounds__(256) void k_pack1(const float* __restrict__ Wih1,
                                               const float* __restrict__ Whh1,
                                               _Float16* __restrict__ P) {
  int li = blockIdx.x * 256 + threadIdx.x;  // 1048576
  int mat = li >> 19;
  int li2 = li & 524287;
  int row = li2 >> 7, k8l = li2 & 127;
  const float* s = (mat ? Whh1 : Wih1) + (size_t)row * 1024 + k8l * 8;
  int g = row >> 10, u = row & 1023, jb = u >> 4, col = u & 15;
  int k8g = mat * 128 + k8l;
  int kh = k8g >> 5, rem = k8g & 31, st = rem >> 2, kslot = rem & 3;
  size_t idx = ((size_t)(((jb * 8 + kh) * 8 + st) * 4 + g)) * 64 + kslot * 16 + col;
  f16x8 o;
#pragma unroll
  for (int j = 0; j < 8; ++j) o[j] = (_Float16)s[j];
  *(f16x8*)(P + idx * 8) = o;
}

// ---------------- embedding + relu ----------------
__global__ __launch_bounds__(256) void k_embed(const int* __restrict__ dec,
                                               const float* __restrict__ emb,
                                               float* __restrict__ xf,
                                               _Float16* __restrict__ xh) {
  int i = blockIdx.x * 256 + threadIdx.x;  // 524288 float4 units
  int r = i >> 8;
  int c4 = i & 255;
  int b = r & 31, t = r >> 5;
  int tok = dec[b * 64 + t];
  float4 v = ((const float4*)(emb + (size_t)tok * 1024))[c4];
  v.x = fmaxf(v.x, 0.f); v.y = fmaxf(v.y, 0.f); v.z = fmaxf(v.z, 0.f); v.w = fmaxf(v.w, 0.f);
  ((float4*)(xf + (size_t)r * 1024))[c4] = v;
  f16x4 o;
  o.x = (_Float16)v.x; o.y = (_Float16)v.y; o.z = (_Float16)v.z; o.w = (_Float16)v.w;
  ((f16x4*)(xh + (size_t)r * 1024))[c4] = o;
}

// ---------------- state init (+ barrier/work-counter reset) ----------------
__global__ __launch_bounds__(256) void k_init(const float* __restrict__ h0, const float* __restrict__ c0,
                                              float* __restrict__ c,
                                              _Float16* __restrict__ h0B, _Float16* __restrict__ h1B,
                                              int* __restrict__ bar) {
  int i = blockIdx.x * 256 + threadIdx.x;  // 65536
  float hv = h0[i];
  c[i] = c0[i];
  if (i < 32768) h0B[i] = (_Float16)hv;
  else           h1B[i - 32768] = (_Float16)hv;
  if (i < 640) bar[i] = 0;
}

// ---------------- tiled MFMA GEMM (gx precompute): C = A*B^T + biases ----------------
__global__ __launch_bounds__(256) void k_gemm0(const _Float16* __restrict__ A,
                                               const _Float16* __restrict__ Bm,
                                               const float* __restrict__ bias0,
                                               const float* __restrict__ bias1,
                                               float* __restrict__ C) {
  __shared__ _Float16 As[4 * 128 * 8];
  __shared__ _Float16 Bs[4 * 128 * 8];
  const int tid = threadIdx.x;
  const int lane = tid & 63;
  const int w = tid >> 6;
  const int wm = w >> 1, wn = w & 1;
  const _Float16* Ab = A + (size_t)blockIdx.y * 128 * 1024;
  const _Float16* Bb = Bm + (size_t)blockIdx.x * 128 * 1024;
  f32x4 acc[4][4] = {};
  for (int kc = 0; kc < 32; ++kc) {
#pragma unroll
    for (int ii = 0; ii < 2; ++ii) {
      int idx = tid + ii * 256;
      int kb = idx >> 7, row = idx & 127;
      int gofs = row * 1024 + kc * 32 + kb * 8;
      int sofs = kb * 1024 + row * 8;
      *(f16x8*)(As + sofs) = *(const f16x8*)(Ab + gofs);
      *(f16x8*)(Bs + sofs) = *(const f16x8*)(Bb + gofs);
    }
    __syncthreads();
    const int kb = lane >> 4;
    f16x8 af[4], bfv[4];
#pragma unroll
    for (int mf = 0; mf < 4; ++mf) {
      int row = wm * 64 + mf * 16 + (lane & 15);
      af[mf] = *(const f16x8*)(As + kb * 1024 + row * 8);
    }
#pragma unroll
    for (int nf = 0; nf < 4; ++nf) {
      int row = wn * 64 + nf * 16 + (lane & 15);
      bfv[nf] = *(const f16x8*)(Bs + kb * 1024 + row * 8);
    }
#pragma unroll
    for (int mf = 0; mf < 4; ++mf)
#pragma unroll
      for (int nf = 0; nf < 4; ++nf)
        acc[mf][nf] = __builtin_amdgcn_mfma_f32_16x16x32_f16(af[mf], bfv[nf], acc[mf][nf], 0, 0, 0);
    __syncthreads();
  }
  const int rl = (lane >> 4) * 4;
#pragma unroll
  for (int mf = 0; mf < 4; ++mf) {
#pragma unroll
    for (int nf = 0; nf < 4; ++nf) {
#pragma unroll
      for (int j = 0; j < 4; ++j) {
        int m = wm * 64 + mf * 16 + rl + j;
        int n = wn * 64 + nf * 16 + (lane & 15);
        int rg = blockIdx.y * 128 + m;
        int ng = blockIdx.x * 128 + n;
        C[(size_t)rg * 8192 + ng] = acc[mf][nf][j] + bias0[ng] + bias1[ng];
      }
    }
  }
}

// ---------------- two-level tree barrier (RELAXED-only) ----------------
__device__ __forceinline__ void gbar(int* bar) {
  __syncthreads();
  if (threadIdx.x == 0) {
    int* gen = bar + 544;
    int g = ALOAD(gen);
    int grp = blockIdx.x >> 3;
    int a = __hip_atomic_fetch_add(bar + grp * 32, 1, __ATOMIC_RELAXED, __HIP_MEMORY_SCOPE_AGENT);
    if (a == 7) {
      ASTORE(bar + grp * 32, 0);
      int r = __hip_atomic_fetch_add(bar + 512, 1, __ATOMIC_RELAXED, __HIP_MEMORY_SCOPE_AGENT);
      if (r == 15) {
        ASTORE(bar + 512, 0);
        ASTORE(gen, g + 1);
      }
    }
    while (ALOAD(gen) == g) __builtin_amdgcn_s_sleep(2);
  }
  __syncthreads();
}

// ---------------- persistent LSTM phases (blocks 0..127) ----------------
template <int ROLE>
__device__ __forceinline__ void run_phases(
    int jb, const _Float16* __restrict__ Pk,
    const float* __restrict__ gx, const float* __restrict__ x_f,
    float* __restrict__ c_f,
    _Float16* __restrict__ h0A, _Float16* __restrict__ h0B,
    _Float16* __restrict__ h1A, _Float16* __restrict__ h1B,
    float* __restrict__ ipfA, float* __restrict__ ipfB,
    float* __restrict__ outs_f, _Float16* __restrict__ outs_h,
    float* __restrict__ outHT, float* __restrict__ outCT,
    int* bar, _Float16* As) {
  constexpr int S = ROLE ? 8 : 4;
  constexpr int NHALF = ROLE ? 2 : 1;
  constexpr int RSH = ROLE ? 8 : 7;
  constexpr int K8M = ROLE ? 255 : 127;
  const int u0 = jb * 16;
  const int tid = threadIdx.x;
  const int lane = tid & 63;
  const int kh = tid >> 6;
  const int col = lane & 15;
  const int kslot = lane >> 4;

  float* cst = c_f + ROLE * 32768;
  const float* gxbase = gx + (ROLE ? 4096 : 0);
  const int cb = tid >> 4, cul = tid & 15, cu = u0 + cul;

  const _Float16* pkbase = Pk + ((size_t)(jb * 8 + kh) * S) * 4 * 512 + lane * 8;
  const int a0off = col * 2056 + kh * S * 32 + kslot * 8;
  const int a1off = a0off + 16 * 2056;

  // weights pinned in registers for the whole recurrence
  f16x8 wreg[S * 4];
#pragma unroll
  for (int i = 0; i < S * 4; ++i) wreg[i] = *(const f16x8*)(pkbase + i * 512);

  for (int p = 0; p <= 64; ++p) {
    const bool active = (ROLE == 0) ? (p < 64) : (p > 0);
    if (active) {
      const int t = (ROLE == 0) ? p : p - 1;
      const _Float16 *h0r, *h1r;
      _Float16 *h0w, *h1w;
      const float* ipfr; float* ipfw;
      if (p & 1) { h0r = h0A; h0w = h0B; ipfr = ipfA; ipfw = ipfB; h1r = h1B; h1w = h1A; }
      else       { h0r = h0B; h0w = h0A; ipfr = ipfB; ipfw = ipfA; h1r = h1A; h1w = h1B; }

      const float* gxr = gxbase + (size_t)(t * 32 + cb) * 8192;
      float pg0 = gxr[cu], pg1 = gxr[1024 + cu], pg2 = gxr[2048 + cu], pg3 = gxr[3072 + cu];
      float pc = cst[cb * 1024 + cu];
      float px = 0.f, pip = 0.f;
      if (ROLE == 0) px = x_f[(size_t)(t * 32 + cb) * 1024 + cu];
      else           pip = ALOAD(ipfr + cb * 1024 + cu);

#pragma unroll
      for (int hf = 0; hf < NHALF; ++hf) {
        u64 sreg[16];
#pragma unroll
        for (int i = 0; i < 8; ++i) {
          int fr = (hf * 8 + i) * 512 + tid;
          int row = fr >> RSH, k8 = fr & K8M;
          const _Float16* s;
          if (ROLE == 0) s = h0r + row * 1024 + k8 * 8;
          else           s = (k8 < 128) ? (h0r + row * 1024 + k8 * 8)
                                        : (h1r + row * 1024 + (k8 - 128) * 8);
          const u64* qq = (const u64*)s;
          sreg[2 * i]     = ALOAD(qq);
          sreg[2 * i + 1] = ALOAD(qq + 1);
        }
#pragma unroll
        for (int i = 0; i < 8; ++i) {
          int fr = (hf * 8 + i) * 512 + tid;
          int row = fr >> RSH, k8 = fr & K8M;
          u64* d = (u64*)(As + row * 2056 + k8 * 8);
          d[0] = sreg[2 * i];
          d[1] = sreg[2 * i + 1];
        }
      }
      __syncthreads();

      f32x4 acc[2][4] = {};
#pragma unroll
      for (int s2 = 0; s2 < S; ++s2) {
        f16x8 a0 = *(const f16x8*)(As + a0off + s2 * 32);
        f16x8 a1 = *(const f16x8*)(As + a1off + s2 * 32);
        acc[0][0] = __builtin_amdgcn_mfma_f32_16x16x32_f16(a0, wreg[s2 * 4 + 0], acc[0][0], 0, 0, 0);
        acc[1][0] = __builtin_amdgcn_mfma_f32_16x16x32_f16(a1, wreg[s2 * 4 + 0], acc[1][0], 0, 0, 0);
        acc[0][1] = __builtin_amdgcn_mfma_f32_16x16x32_f16(a0, wreg[s2 * 4 + 1], acc[0][1], 0, 0, 0);
        acc[1][1] = __builtin_amdgcn_mfma_f32_16x16x32_f16(a1, wreg[s2 * 4 + 1], acc[1][1], 0, 0, 0);
        acc[0][2] = __builtin_amdgcn_mfma_f32_16x16x32_f16(a0, wreg[s2 * 4 + 2], acc[0][2], 0, 0, 0);
        acc[1][2] = __builtin_amdgcn_mfma_f32_16x16x32_f16(a1, wreg[s2 * 4 + 2], acc[1][2], 0, 0, 0);
        acc[0][3] = __builtin_amdgcn_mfma_f32_16x16x32_f16(a0, wreg[s2 * 4 + 3], acc[0][3], 0, 0, 0);
        acc[1][3] = __builtin_amdgcn_mfma_f32_16x16x32_f16(a1, wreg[s2 * 4 + 3], acc[1][3], 0, 0, 0);
      }
      __syncthreads();

      float (*gs)[32][68] = (float (*)[32][68])(void*)As;
      const int rl = kslot * 4;
      if (kh < 4) {
#pragma unroll
        for (int m = 0; m < 2; ++m)
#pragma unroll
          for (int g = 0; g < 4; ++g)
#pragma unroll
            for (int j = 0; j < 4; ++j)
              gs[kh][m * 16 + rl + j][g * 16 + col] = acc[m][g][j];
      }
      __syncthreads();
      if (kh >= 4) {
#pragma unroll
        for (int m = 0; m < 2; ++m)
#pragma unroll
          for (int g = 0; g < 4; ++g)
#pragma unroll
            for (int j = 0; j < 4; ++j)
              gs[kh - 4][m * 16 + rl + j][g * 16 + col] += acc[m][g][j];
      }
      __syncthreads();

      {
        float ig = pg0, fg = pg1, gg = pg2, og = pg3;
#pragma unroll
        for (int cc = 0; cc < 4; ++cc) {
          ig += gs[cc][cb][cul];
          fg += gs[cc][cb][16 + cul];
          gg += gs[cc][cb][32 + cul];
          og += gs[cc][cb][48 + cul];
        }
        float si = 1.f / (1.f + expf(-ig));
        float sf = 1.f / (1.f + expf(-fg));
        float so = 1.f / (1.f + expf(-og));
        float ci = sf * pc + si * tanhf(gg);
        float hi = so * tanhf(ci);
        cst[cb * 1024 + cu] = ci;
        if (t == 63) {
          outHT[ROLE * 32768 + cb * 1024 + cu] = hi;
          outCT[ROLE * 32768 + cb * 1024 + cu] = ci;
        }
        if (ROLE == 0) {
          float hn = __shfl_down(hi, 1);
          float ipv = hi + px;
          float ipn = __shfl_down(ipv, 1);
          if ((cul & 1) == 0) {
            union { _Float16 h[2]; u32 v; } ph;
            ph.h[0] = (_Float16)hi; ph.h[1] = (_Float16)hn;
            ASTORE((u32*)(h0w + cb * 1024 + cu), ph.v);
            union { float f[2]; u64 v; } pi;
            pi.f[0] = ipv; pi.f[1] = ipn;
            ASTORE((u64*)(ipfw + cb * 1024 + cu), pi.v);
          }
        } else {
          float hn = __shfl_down(hi, 1);
          float ro = hi + pip;
          float rn = __shfl_down(ro, 1);
          if ((cul & 1) == 0) {
            union { _Float16 h[2]; u32 v; } ph;
            ph.h[0] = (_Float16)hi; ph.h[1] = (_Float16)hn;
            ASTORE((u32*)(h1w + cb * 1024 + cu), ph.v);
            union { _Float16 h[2]; u32 v; } po;
            po.h[0] = (_Float16)ro; po.h[1] = (_Float16)rn;
            // sc1 write-through: consumers read after the gen bump
            ASTORE((u32*)(outs_h + (size_t)(t * 32 + cb) * 1024 + cu), po.v);
          }
          outs_f[(size_t)(t * 32 + cb) * 1024 + cu] = ro;
        }
      }
    }
    gbar(bar);  // every phase, incl. last -> gen ends at 65
  }
}

// ---------------- logits GEMM consumer: 256x256 tiles, dynamic work-steal ----------------
// 1000 tiles (m 0..7 x nt 0..124), handed out m-major via atomic counter bar[576].
// m-tile m covers t in [8m, 8m+7]; outs[t] visible once gen >= t+2 -> need gen >= 8m+9.
// Double-buffered LDS, ONE __syncthreads per kc. Cross-tile buffer hazards are
// separated by the tau broadcast + readiness barriers.
__device__ __forceinline__ void run_consumer(
    const _Float16* __restrict__ outs_h, const _Float16* __restrict__ clsW_h,
    const float* __restrict__ cls_b, float* __restrict__ out, int* bar, _Float16* lds) {
  __shared__ int tau_s;
  const int tid = threadIdx.x;
  const int lane = tid & 63;
  const int w = tid >> 6;
  const int wm = w >> 2, wn = w & 3;      // 2x4 wave grid; wave tile 128x64
  int* gen = bar + 544;
  int* wcnt = bar + 576;
  const int r0 = tid & 255, kb0 = tid >> 8;  // staging: 2 frags A + 2 frags B per thread

  for (;;) {
    if (tid == 0) tau_s = __hip_atomic_fetch_add(wcnt, 1, __ATOMIC_RELAXED, __HIP_MEMORY_SCOPE_AGENT);
    __syncthreads();
    int tau = tau_s;
    if (tau >= 1000) break;
    int m = tau / 125, nt = tau - m * 125;
    if (tid == 0) {
      int need = 8 * m + 9; if (need > 65) need = 65;
      while (ALOAD(gen) < need) __builtin_amdgcn_s_sleep(8);
    }
    __syncthreads();   // also guards tau_s reuse and LDS buffer reuse across tiles

    const _Float16* Ab = outs_h + (size_t)m * 256 * 1024;
    const _Float16* Bb = clsW_h + (size_t)nt * 256 * 1024;
    // LDS: A buffers at 0 / 8192 f16; B buffers at 16384 / 24576 f16 (64 KB total)
    f16x8 pa0, pa1, pb0, pb1;
    pa0 = *(const f16x8*)(Ab + r0 * 1024 + kb0 * 8);
    pa1 = *(const f16x8*)(Ab + r0 * 1024 + (kb0 + 2) * 8);
    pb0 = *(const f16x8*)(Bb + r0 * 1024 + kb0 * 8);
    pb1 = *(const f16x8*)(Bb + r0 * 1024 + (kb0 + 2) * 8);
    f32x4 acc[8][4] = {};
    for (int kc = 0; kc < 32; ++kc) {
      _Float16* Ac = lds + (kc & 1) * 8192;
      _Float16* Bc = lds + 16384 + (kc & 1) * 8192;
      *(f16x8*)(Ac + kb0 * 2048 + r0 * 8) = pa0;
      *(f16x8*)(Ac + (kb0 + 2) * 2048 + r0 * 8) = pa1;
      *(f16x8*)(Bc + kb0 * 2048 + r0 * 8) = pb0;
      *(f16x8*)(Bc + (kb0 + 2) * 2048 + r0 * 8) = pb1;
      if (kc + 1 < 32) {
        int ko = (kc + 1) * 32;
        pa0 = *(const f16x8*)(Ab + r0 * 1024 + ko + kb0 * 8);
        pa1 = *(const f16x8*)(Ab + r0 * 1024 + ko + (kb0 + 2) * 8);
        pb0 = *(const f16x8*)(Bb + r0 * 1024 + ko + kb0 * 8);
        pb1 = *(const f16x8*)(Bb + r0 * 1024 + ko + (kb0 + 2) * 8);
      }
      __syncthreads();
      const int kb = lane >> 4;
      f16x8 af[8], bf[4];
#pragma unroll
      for (int mf = 0; mf < 8; ++mf) {
        int row = wm * 128 + mf * 16 + (lane & 15);
        af[mf] = *(const f16x8*)(Ac + kb * 2048 + row * 8);
      }
#pragma unroll
      for (int nf = 0; nf < 4; ++nf) {
        int row = wn * 64 + nf * 16 + (lane & 15);
        bf[nf] = *(const f16x8*)(Bc + kb * 2048 + row * 8);
      }
#pragma unroll
      for (int mf = 0; mf < 8; ++mf)
#pragma unroll
        for (int nf = 0; nf < 4; ++nf)
          acc[mf][nf] = __builtin_amdgcn_mfma_f32_16x16x32_f16(af[mf], bf[nf], acc[mf][nf], 0, 0, 0);
      // no second sync: double-buffered
    }
    const int rl = (lane >> 4) * 4;
#pragma unroll
    for (int mf = 0; mf < 8; ++mf) {
#pragma unroll
      for (int nf = 0; nf < 4; ++nf) {
#pragma unroll
        for (int j = 0; j < 4; ++j) {
          int rg = m * 256 + wm * 128 + mf * 16 + rl + j;
          int tt = rg >> 5, b = rg & 31;
          int ng = nt * 256 + wn * 64 + nf * 16 + (lane & 15);
          out[(size_t)(b * 64 + tt) * 32000 + ng] = acc[mf][nf][j] + cls_b[ng];
        }
      }
    }
  }
}

__global__ __launch_bounds__(512, 1) void k_lstm_fused(
    const _Float16* __restrict__ Pk0, const _Float16* __restrict__ Pk1,
    const float* __restrict__ gx, const float* __restrict__ x_f,
    float* __restrict__ c_f,
    _Float16* __restrict__ h0A, _Float16* __restrict__ h0B,
    _Float16* __restrict__ h1A, _Float16* __restrict__ h1B,
    float* __restrict__ ipfA, float* __restrict__ ipfB,
    float* __restrict__ outs_f, _Float16* __restrict__ outs_h,
    const _Float16* __restrict__ clsW_h, const float* __restrict__ cls_b,
    float* __restrict__ out_logits,
    float* __restrict__ outHT, float* __restrict__ outCT,
    int* bar) {
  __shared__ _Float16 As[32 * 2056];  // 131,584 B (1 block/CU -> 256 blocks co-resident)
  const int bid = blockIdx.x;
  if (bid < 64)
    run_phases<0>(bid & 63, Pk0, gx, x_f, c_f, h0A, h0B, h1A, h1B,
                  ipfA, ipfB, outs_f, outs_h, outHT, outCT, bar, As);
  else if (bid < 128)
    run_phases<1>(bid & 63, Pk1, gx, x_f, c_f, h0A, h0B, h1A, h1B,
                  ipfA, ipfB, outs_f, outs_h, outHT, outCT, bar, As);
  // all 256 blocks join the tile pool (producers arrive after their last gbar)
  run_consumer(outs_h, clsW_h, cls_b, out_logits, bar, As);
}

// ---------------- batched dot-attention + softmax ----------------
__global__ __launch_bounds__(256) void k_attn(const float* __restrict__ outs,
                                              const float* __restrict__ enc,
                                              float* __restrict__ att) {
  __shared__ float o_s[8][1024];
  __shared__ float sc[8][128];
  const int tid = threadIdx.x;
  const int lane = tid & 63;
  const int w = tid >> 6;
  const int b = blockIdx.x >> 3;
  const int t0 = (blockIdx.x & 7) * 8;
#pragma unroll
  for (int ii = 0; ii < 8; ++ii) {
    int idx = tid + ii * 256;
    int tt = idx >> 8, c4 = idx & 255;
    ((float4*)&o_s[tt][0])[c4] =
        *(const float4*)(outs + (size_t)((t0 + tt) * 32 + b) * 1024 + (size_t)c4 * 4);
  }
  __syncthreads();
  for (int si = 0; si < 32; ++si) {
    int s = w * 32 + si;
    float av[8] = {0, 0, 0, 0, 0, 0, 0, 0};
    const float* er = enc + (size_t)(b * 128 + s) * 1024;
#pragma unroll
    for (int i = 0; i < 4; ++i) {
      int k = i * 256 + lane * 4;
      float4 e = *(const float4*)(er + k);
#pragma unroll
      for (int tt = 0; tt < 8; ++tt) {
        float4 o = *(const float4*)&o_s[tt][k];
        av[tt] += e.x * o.x + e.y * o.y + e.z * o.z + e.w * o.w;
      }
    }
#pragma unroll
    for (int tt = 0; tt < 8; ++tt) {
      float v = av[tt];
#pragma unroll
      for (int off = 32; off > 0; off >>= 1) v += __shfl_down(v, off);
      if (lane == 0) sc[tt][s] = v;
    }
  }
  __syncthreads();
#pragma unroll
  for (int pp = 0; pp < 2; ++pp) {
    int tt = w + pp * 4;
    float a = sc[tt][lane], b2 = sc[tt][64 + lane];
    float m = fmaxf(a, b2);
#pragma unroll
    for (int off = 32; off > 0; off >>= 1) m = fmaxf(m, __shfl_xor(m, off));
    float e0 = expf(a - m), e1 = expf(b2 - m);
    float ss = e0 + e1;
#pragma unroll
    for (int off = 32; off > 0; off >>= 1) ss += __shfl_xor(ss, off);
    float r = 1.f / ss;
    att[(size_t)b * 8192 + (size_t)lane * 64 + t0 + tt] = e0 * r;
    att[(size_t)b * 8192 + (size_t)(64 + lane) * 64 + t0 + tt] = e1 * r;
  }
}

extern "C" void kernel_launch(void* const* d_in, const int* in_sizes, int n_in,
                              void* d_out, int out_size, void* d_ws, size_t ws_size,
                              hipStream_t stream) {
  const int*   dec   = (const int*)d_in[0];
  const float* h0    = (const float*)d_in[1];
  const float* c0    = (const float*)d_in[2];
  const float* enc   = (const float*)d_in[3];
  const float* emb   = (const float*)d_in[4];
  const float* W_ih  = (const float*)d_in[5];
  const float* W_hh  = (const float*)d_in[6];
  const float* b_ih  = (const float*)d_in[7];
  const float* b_hh  = (const float*)d_in[8];
  const float* cls_W = (const float*)d_in[9];
  const float* cls_b = (const float*)d_in[10];
  float* out = (float*)d_out;
  char* ws = (char*)d_ws;

  float*    x_f    = (float*)(ws + 0);                // [2048][1024] f32
  _Float16* x_h    = (_Float16*)(ws + 8388608);       // [2048][1024] f16 (dead after gx gemm)
  _Float16* Pk0    = (_Float16*)(ws + 8388608);       // 8MB packed Whh0 (written AFTER gx gemm)
  _Float16* Wih_h  = (_Float16*)(ws + 12582912);      // [8192][1024] f16 (dead after gx gemm)
  _Float16* Pk1    = (_Float16*)(ws + 29360128);      // 16MB packed [Wih1|Whh1]
  _Float16* clsW_h = (_Float16*)(ws + 46137344);      // [32000][1024] f16
  float*    gx     = (float*)(ws + 111673344);        // [2048][8192] f32
  float*    outs_f = (float*)(ws + 178782208);        // [2048][1024] f32
  _Float16* outs_h = (_Float16*)(ws + 187170816);     // [2048][1024] f16
  float*    c_f    = (float*)(ws + 191627264);        // [2][32][1024] f32
  _Float16* h0A    = (_Float16*)(ws + 191889408);     // [32][1024] f16
  _Float16* h0B    = (_Float16*)(ws + 191954944);
  _Float16* h1A    = (_Float16*)(ws + 192020480);
  _Float16* h1B    = (_Float16*)(ws + 192086016);
  int*      bar    = (int*)(ws + 192151552);          // 640 ints (tree barrier + gen + work cnt)
  float*    ipfA   = (float*)(ws + 192155648);        // [32][1024] f32
  float*    ipfB   = (float*)(ws + 192286720);        // end 192417792

  k_f32_to_f16<<<2048, 256, 0, stream>>>(W_ih, Wih_h, 2097152);
  k_f32_to_f16<<<4096, 256, 0, stream>>>(cls_W, clsW_h, 8192000);
  k_embed<<<2048, 256, 0, stream>>>(dec, emb, x_f, x_h);
  k_init<<<256, 256, 0, stream>>>(h0, c0, c_f, h0B, h1B, bar);
  k_pack1<<<4096, 256, 0, stream>>>(W_ih + (size_t)4096 * 1024, W_hh + (size_t)4096 * 1024, Pk1);
  // gx[r][0:4096] = x@Wih0^T + b_ih0 + b_hh0 ; gx[r][4096:8192] = x@Wih1^T + b_ih1 + b_hh1
  k_gemm0<<<dim3(64, 16), 256, 0, stream>>>(x_h, Wih_h, b_ih, b_hh, gx);
  k_pack0<<<2048, 256, 0, stream>>>(W_hh, Pk0);  // after gemm0: overwrites x_h/Wih_h region

  k_lstm_fused<<<256, 512, 0, stream>>>(Pk0, Pk1, gx, x_f, c_f,
                                        h0A, h0B, h1A, h1B, ipfA, ipfB,
                                        outs_f, outs_h, clsW_h, cls_b, out,
                                        out + (size_t)65536000, out + (size_t)65601536,
                                        bar);

  k_attn<<<256, 256, 0, stream>>>(outs_f, enc, out + (size_t)65667072);
}

// Round 9
// 823.620 us; speedup vs baseline: 2.2117x; 1.0340x over previous
//
#include <hip/hip_runtime.h>
#include <math.h>

typedef _Float16 f16x8 __attribute__((ext_vector_type(8)));
typedef _Float16 f16x4 __attribute__((ext_vector_type(4)));
typedef float    f32x4 __attribute__((ext_vector_type(4)));
typedef unsigned long long u64;
typedef unsigned int u32;

#define ALOAD(p)    __hip_atomic_load((p), __ATOMIC_RELAXED, __HIP_MEMORY_SCOPE_AGENT)
#define ASTORE(p,v) __hip_atomic_store((p), (v), __ATOMIC_RELAXED, __HIP_MEMORY_SCOPE_AGENT)

// ---------------- conversion f32 -> f16 ----------------
__global__ __launch_bounds__(256) void k_f32_to_f16(const float* __restrict__ src,
                                                    _Float16* __restrict__ dst, int n4) {
  int i = blockIdx.x * 256 + threadIdx.x;
  int stride = gridDim.x * 256;
  for (; i < n4; i += stride) {
    float4 v = ((const float4*)src)[i];
    f16x4 o;
    o.x = (_Float16)v.x; o.y = (_Float16)v.y; o.z = (_Float16)v.z; o.w = (_Float16)v.w;
    ((f16x4*)dst)[i] = o;
  }
}

// ---------------- weight packing into per-wave fragment-stream order ----------------
__global__ __launch_bounds__(256) void k_pack0(const float* __restrict__ Whh0,
                                               _Float16* __restrict__ P) {
  int li = blockIdx.x * 256 + threadIdx.x;  // 524288
  int row = li >> 7, k8 = li & 127;
  const float* s = Whh0 + (size_t)row * 1024 + k8 * 8;
  int g = row >> 10, u = row & 1023, jb = u >> 4, col = u & 15;
  int kh = k8 >> 4, rem = k8 & 15, st = rem >> 2, kslot = rem & 3;
  size_t idx = ((size_t)(((jb * 8 + kh) * 4 + st) * 4 + g)) * 64 + kslot * 16 + col;
  f16x8 o;
#pragma unroll
  for (int j = 0; j < 8; ++j) o[j] = (_Float16)s[j];
  *(f16x8*)(P + idx * 8) = o;
}

__global__ __launch_bounds__(256) void k_pack1(const float* __restrict__ Wih1,
                                               const float* __restrict__ Whh1,
                                               _Float16* __restrict__ P) {
  int li = blockIdx.x * 256 + threadIdx.x;  // 1048576
  int mat = li >> 19;
  int li2 = li & 524287;
  int row = li2 >> 7, k8l = li2 & 127;
  const float* s = (mat ? Whh1 : Wih1) + (size_t)row * 1024 + k8l * 8;
  int g = row >> 10, u = row & 1023, jb = u >> 4, col = u & 15;
  int k8g = mat * 128 + k8l;
  int kh = k8g >> 5, rem = k8g & 31, st = rem >> 2, kslot = rem & 3;
  size_t idx = ((size_t)(((jb * 8 + kh) * 8 + st) * 4 + g)) * 64 + kslot * 16 + col;
  f16x8 o;
#pragma unroll
  for (int j = 0; j < 8; ++j) o[j] = (_Float16)s[j];
  *(f16x8*)(P + idx * 8) = o;
}

// ---------------- embedding + relu ----------------
__global__ __launch_bounds__(256) void k_embed(const int* __restrict__ dec,
                                               const float* __restrict__ emb,
                                               float* __restrict__ xf,
                                               _Float16* __restrict__ xh) {
  int i = blockIdx.x * 256 + threadIdx.x;  // 524288 float4 units
  int r = i >> 8;
  int c4 = i & 255;
  int b = r & 31, t = r >> 5;
  int tok = dec[b * 64 + t];
  float4 v = ((const float4*)(emb + (size_t)tok * 1024))[c4];
  v.x = fmaxf(v.x, 0.f); v.y = fmaxf(v.y, 0.f); v.z = fmaxf(v.z, 0.f); v.w = fmaxf(v.w, 0.f);
  ((float4*)(xf + (size_t)r * 1024))[c4] = v;
  f16x4 o;
  o.x = (_Float16)v.x; o.y = (_Float16)v.y; o.z = (_Float16)v.z; o.w = (_Float16)v.w;
  ((f16x4*)(xh + (size_t)r * 1024))[c4] = o;
}

// ---------------- state init (+ barrier/work-counter reset) ----------------
__global__ __launch_bounds__(256) void k_init(const float* __restrict__ h0, const float* __restrict__ c0,
                                              float* __restrict__ c,
                                              _Float16* __restrict__ h0B, _Float16* __restrict__ h1B,
                                              int* __restrict__ bar) {
  int i = blockIdx.x * 256 + threadIdx.x;  // 65536
  float hv = h0[i];
  c[i] = c0[i];
  if (i < 32768) h0B[i] = (_Float16)hv;
  else           h1B[i - 32768] = (_Float16)hv;
  if (i < 640) bar[i] = 0;
}

// ---------------- tiled MFMA GEMM (gx precompute): C = A*B^T + biases ----------------
__global__ __launch_bounds__(256) void k_gemm0(const _Float16* __restrict__ A,
                                               const _Float16* __restrict__ Bm,
                                               const float* __restrict__ bias0,
                                               const float* __restrict__ bias1,
                                               float* __restrict__ C) {
  __shared__ _Float16 As[4 * 128 * 8];
  __shared__ _Float16 Bs[4 * 128 * 8];
  const int tid = threadIdx.x;
  const int lane = tid & 63;
  const int w = tid >> 6;
  const int wm = w >> 1, wn = w & 1;
  const _Float16* Ab = A + (size_t)blockIdx.y * 128 * 1024;
  const _Float16* Bb = Bm + (size_t)blockIdx.x * 128 * 1024;
  f32x4 acc[4][4] = {};
  for (int kc = 0; kc < 32; ++kc) {
#pragma unroll
    for (int ii = 0; ii < 2; ++ii) {
      int idx = tid + ii * 256;
      int kb = idx >> 7, row = idx & 127;
      int gofs = row * 1024 + kc * 32 + kb * 8;
      int sofs = kb * 1024 + row * 8;
      *(f16x8*)(As + sofs) = *(const f16x8*)(Ab + gofs);
      *(f16x8*)(Bs + sofs) = *(const f16x8*)(Bb + gofs);
    }
    __syncthreads();
    const int kb = lane >> 4;
    f16x8 af[4], bfv[4];
#pragma unroll
    for (int mf = 0; mf < 4; ++mf) {
      int row = wm * 64 + mf * 16 + (lane & 15);
      af[mf] = *(const f16x8*)(As + kb * 1024 + row * 8);
    }
#pragma unroll
    for (int nf = 0; nf < 4; ++nf) {
      int row = wn * 64 + nf * 16 + (lane & 15);
      bfv[nf] = *(const f16x8*)(Bs + kb * 1024 + row * 8);
    }
#pragma unroll
    for (int mf = 0; mf < 4; ++mf)
#pragma unroll
      for (int nf = 0; nf < 4; ++nf)
        acc[mf][nf] = __builtin_amdgcn_mfma_f32_16x16x32_f16(af[mf], bfv[nf], acc[mf][nf], 0, 0, 0);
    __syncthreads();
  }
  const int rl = (lane >> 4) * 4;
#pragma unroll
  for (int mf = 0; mf < 4; ++mf) {
#pragma unroll
    for (int nf = 0; nf < 4; ++nf) {
#pragma unroll
      for (int j = 0; j < 4; ++j) {
        int m = wm * 64 + mf * 16 + rl + j;
        int n = wn * 64 + nf * 16 + (lane & 15);
        int rg = blockIdx.y * 128 + m;
        int ng = blockIdx.x * 128 + n;
        C[(size_t)rg * 8192 + ng] = acc[mf][nf][j] + bias0[ng] + bias1[ng];
      }
    }
  }
}

// ---------------- two-level tree barrier (RELAXED-only) ----------------
__device__ __forceinline__ void gbar(int* bar) {
  __syncthreads();
  if (threadIdx.x == 0) {
    int* gen = bar + 544;
    int g = ALOAD(gen);
    int grp = blockIdx.x >> 3;
    int a = __hip_atomic_fetch_add(bar + grp * 32, 1, __ATOMIC_RELAXED, __HIP_MEMORY_SCOPE_AGENT);
    if (a == 7) {
      ASTORE(bar + grp * 32, 0);
      int r = __hip_atomic_fetch_add(bar + 512, 1, __ATOMIC_RELAXED, __HIP_MEMORY_SCOPE_AGENT);
      if (r == 15) {
        ASTORE(bar + 512, 0);
        ASTORE(gen, g + 1);
      }
    }
    while (ALOAD(gen) == g) __builtin_amdgcn_s_sleep(1);
  }
  __syncthreads();
}

// ---------------- persistent LSTM phases (blocks 0..127) ----------------
template <int ROLE>
__device__ __forceinline__ void run_phases(
    int jb, const _Float16* __restrict__ Pk,
    const float* __restrict__ gx, const float* __restrict__ x_f,
    float* __restrict__ c_f,
    _Float16* __restrict__ h0A, _Float16* __restrict__ h0B,
    _Float16* __restrict__ h1A, _Float16* __restrict__ h1B,
    float* __restrict__ ipfA, float* __restrict__ ipfB,
    float* __restrict__ outs_f, _Float16* __restrict__ outs_h,
    float* __restrict__ outHT, float* __restrict__ outCT,
    int* bar, _Float16* As) {
  constexpr int S = ROLE ? 8 : 4;
  constexpr int NHALF = ROLE ? 2 : 1;
  constexpr int RSH = ROLE ? 8 : 7;
  constexpr int K8M = ROLE ? 255 : 127;
  const int u0 = jb * 16;
  const int tid = threadIdx.x;
  const int lane = tid & 63;
  const int kh = tid >> 6;
  const int col = lane & 15;
  const int kslot = lane >> 4;

  float* cst = c_f + ROLE * 32768;
  const float* gxbase = gx + (ROLE ? 4096 : 0);
  const int cb = tid >> 4, cul = tid & 15, cu = u0 + cul;

  const _Float16* pkbase = Pk + ((size_t)(jb * 8 + kh) * S) * 4 * 512 + lane * 8;
  const int a0off = col * 2056 + kh * S * 32 + kslot * 8;
  const int a1off = a0off + 16 * 2056;

  // weights pinned in registers for the whole recurrence
  f16x8 wreg[S * 4];
#pragma unroll
  for (int i = 0; i < S * 4; ++i) wreg[i] = *(const f16x8*)(pkbase + i * 512);

  for (int p = 0; p <= 64; ++p) {
    const bool active = (ROLE == 0) ? (p < 64) : (p > 0);
    if (active) {
      const int t = (ROLE == 0) ? p : p - 1;
      const _Float16 *h0r, *h1r;
      _Float16 *h0w, *h1w;
      const float* ipfr; float* ipfw;
      if (p & 1) { h0r = h0A; h0w = h0B; ipfr = ipfA; ipfw = ipfB; h1r = h1B; h1w = h1A; }
      else       { h0r = h0B; h0w = h0A; ipfr = ipfB; ipfw = ipfA; h1r = h1A; h1w = h1B; }

      const float* gxr = gxbase + (size_t)(t * 32 + cb) * 8192;
      float pg0 = gxr[cu], pg1 = gxr[1024 + cu], pg2 = gxr[2048 + cu], pg3 = gxr[3072 + cu];
      float pc = cst[cb * 1024 + cu];
      float px = 0.f, pip = 0.f;
      if (ROLE == 0) px = x_f[(size_t)(t * 32 + cb) * 1024 + cu];
      else           pip = ALOAD(ipfr + cb * 1024 + cu);

#pragma unroll
      for (int hf = 0; hf < NHALF; ++hf) {
        u64 sreg[16];
#pragma unroll
        for (int i = 0; i < 8; ++i) {
          int fr = (hf * 8 + i) * 512 + tid;
          int row = fr >> RSH, k8 = fr & K8M;
          const _Float16* s;
          if (ROLE == 0) s = h0r + row * 1024 + k8 * 8;
          else           s = (k8 < 128) ? (h0r + row * 1024 + k8 * 8)
                                        : (h1r + row * 1024 + (k8 - 128) * 8);
          const u64* qq = (const u64*)s;
          sreg[2 * i]     = ALOAD(qq);
          sreg[2 * i + 1] = ALOAD(qq + 1);
        }
#pragma unroll
        for (int i = 0; i < 8; ++i) {
          int fr = (hf * 8 + i) * 512 + tid;
          int row = fr >> RSH, k8 = fr & K8M;
          u64* d = (u64*)(As + row * 2056 + k8 * 8);
          d[0] = sreg[2 * i];
          d[1] = sreg[2 * i + 1];
        }
      }
      __syncthreads();

      f32x4 acc[2][4] = {};
#pragma unroll
      for (int s2 = 0; s2 < S; ++s2) {
        f16x8 a0 = *(const f16x8*)(As + a0off + s2 * 32);
        f16x8 a1 = *(const f16x8*)(As + a1off + s2 * 32);
        acc[0][0] = __builtin_amdgcn_mfma_f32_16x16x32_f16(a0, wreg[s2 * 4 + 0], acc[0][0], 0, 0, 0);
        acc[1][0] = __builtin_amdgcn_mfma_f32_16x16x32_f16(a1, wreg[s2 * 4 + 0], acc[1][0], 0, 0, 0);
        acc[0][1] = __builtin_amdgcn_mfma_f32_16x16x32_f16(a0, wreg[s2 * 4 + 1], acc[0][1], 0, 0, 0);
        acc[1][1] = __builtin_amdgcn_mfma_f32_16x16x32_f16(a1, wreg[s2 * 4 + 1], acc[1][1], 0, 0, 0);
        acc[0][2] = __builtin_amdgcn_mfma_f32_16x16x32_f16(a0, wreg[s2 * 4 + 2], acc[0][2], 0, 0, 0);
        acc[1][2] = __builtin_amdgcn_mfma_f32_16x16x32_f16(a1, wreg[s2 * 4 + 2], acc[1][2], 0, 0, 0);
        acc[0][3] = __builtin_amdgcn_mfma_f32_16x16x32_f16(a0, wreg[s2 * 4 + 3], acc[0][3], 0, 0, 0);
        acc[1][3] = __builtin_amdgcn_mfma_f32_16x16x32_f16(a1, wreg[s2 * 4 + 3], acc[1][3], 0, 0, 0);
      }
      __syncthreads();

      float (*gs)[32][68] = (float (*)[32][68])(void*)As;
      const int rl = kslot * 4;
      if (kh < 4) {
#pragma unroll
        for (int m = 0; m < 2; ++m)
#pragma unroll
          for (int g = 0; g < 4; ++g)
#pragma unroll
            for (int j = 0; j < 4; ++j)
              gs[kh][m * 16 + rl + j][g * 16 + col] = acc[m][g][j];
      }
      __syncthreads();
      if (kh >= 4) {
#pragma unroll
        for (int m = 0; m < 2; ++m)
#pragma unroll
          for (int g = 0; g < 4; ++g)
#pragma unroll
            for (int j = 0; j < 4; ++j)
              gs[kh - 4][m * 16 + rl + j][g * 16 + col] += acc[m][g][j];
      }
      __syncthreads();

      {
        float ig = pg0, fg = pg1, gg = pg2, og = pg3;
#pragma unroll
        for (int cc = 0; cc < 4; ++cc) {
          ig += gs[cc][cb][cul];
          fg += gs[cc][cb][16 + cul];
          gg += gs[cc][cb][32 + cul];
          og += gs[cc][cb][48 + cul];
        }
        float si = 1.f / (1.f + expf(-ig));
        float sf = 1.f / (1.f + expf(-fg));
        float so = 1.f / (1.f + expf(-og));
        float ci = sf * pc + si * tanhf(gg);
        float hi = so * tanhf(ci);
        cst[cb * 1024 + cu] = ci;
        if (t == 63) {
          outHT[ROLE * 32768 + cb * 1024 + cu] = hi;
          outCT[ROLE * 32768 + cb * 1024 + cu] = ci;
        }
        if (ROLE == 0) {
          float hn = __shfl_down(hi, 1);
          float ipv = hi + px;
          float ipn = __shfl_down(ipv, 1);
          if ((cul & 1) == 0) {
            union { _Float16 h[2]; u32 v; } ph;
            ph.h[0] = (_Float16)hi; ph.h[1] = (_Float16)hn;
            ASTORE((u32*)(h0w + cb * 1024 + cu), ph.v);
            union { float f[2]; u64 v; } pi;
            pi.f[0] = ipv; pi.f[1] = ipn;
            ASTORE((u64*)(ipfw + cb * 1024 + cu), pi.v);
          }
        } else {
          float hn = __shfl_down(hi, 1);
          float ro = hi + pip;
          float rn = __shfl_down(ro, 1);
          if ((cul & 1) == 0) {
            union { _Float16 h[2]; u32 v; } ph;
            ph.h[0] = (_Float16)hi; ph.h[1] = (_Float16)hn;
            ASTORE((u32*)(h1w + cb * 1024 + cu), ph.v);
            union { _Float16 h[2]; u32 v; } po;
            po.h[0] = (_Float16)ro; po.h[1] = (_Float16)rn;
            // sc1 write-through: consumers read after the gen bump
            ASTORE((u32*)(outs_h + (size_t)(t * 32 + cb) * 1024 + cu), po.v);
          }
          outs_f[(size_t)(t * 32 + cb) * 1024 + cu] = ro;
        }
      }
    }
    gbar(bar);  // every phase, incl. last -> gen ends at 65
  }
}

// ---------------- clsW f32->f16 conversion by consumer blocks (sc1 write-through) ----------------
__device__ __forceinline__ void conv_clsW(const float* __restrict__ src,
                                          _Float16* __restrict__ dst, int cb) {
  // 32000*1024 f16 = 4,096,000 f16x8 units; 128 blocks x 512 threads
  for (int i = cb * 512 + threadIdx.x; i < 4096000; i += 65536) {
    const float4* s = (const float4*)(src + (size_t)i * 8);
    float4 v0 = s[0], v1 = s[1];
    union { _Float16 h[8]; u64 q[2]; } o;
    o.h[0] = (_Float16)v0.x; o.h[1] = (_Float16)v0.y;
    o.h[2] = (_Float16)v0.z; o.h[3] = (_Float16)v0.w;
    o.h[4] = (_Float16)v1.x; o.h[5] = (_Float16)v1.y;
    o.h[6] = (_Float16)v1.z; o.h[7] = (_Float16)v1.w;
    u64* d = (u64*)(dst + (size_t)i * 8);
    ASTORE(d, o.q[0]);
    ASTORE(d + 1, o.q[1]);
  }
}

// ---------------- logits GEMM consumer: 256x256 tiles, dynamic work-steal ----------------
// 1000 tiles (m 0..7 x nt 0..124), m-major via atomic counter bar[576].
// m-tile m needs gen >= min(8m+9, 65). Conversion gate: bar[608] == 128.
__device__ __forceinline__ void run_consumer(
    const _Float16* __restrict__ outs_h, const _Float16* __restrict__ clsW_h,
    const float* __restrict__ cls_b, float* __restrict__ out, int* bar, _Float16* lds) {
  __shared__ int tau_s;
  const int tid = threadIdx.x;
  const int lane = tid & 63;
  const int w = tid >> 6;
  const int wm = w >> 2, wn = w & 3;      // 2x4 wave grid; wave tile 128x64
  int* gen = bar + 544;
  int* wcnt = bar + 576;
  const int r0 = tid & 255, kb0 = tid >> 8;

  // wait until clsW_h fully converted (consumer blocks bump bar[608] after conv)
  if (tid == 0) {
    while (ALOAD(bar + 608) < 128) __builtin_amdgcn_s_sleep(16);
  }
  __syncthreads();

  for (;;) {
    if (tid == 0) tau_s = __hip_atomic_fetch_add(wcnt, 1, __ATOMIC_RELAXED, __HIP_MEMORY_SCOPE_AGENT);
    __syncthreads();
    int tau = tau_s;
    if (tau >= 1000) break;
    int m = tau / 125, nt = tau - m * 125;
    if (tid == 0) {
      int need = 8 * m + 9; if (need > 65) need = 65;
      while (ALOAD(gen) < need) __builtin_amdgcn_s_sleep(64);  // coarse poll: readiness is ~55us grain
    }
    __syncthreads();   // also guards tau_s reuse and LDS buffer reuse across tiles

    const _Float16* Ab = outs_h + (size_t)m * 256 * 1024;
    const _Float16* Bb = clsW_h + (size_t)nt * 256 * 1024;
    f16x8 pa0, pa1, pb0, pb1;
    pa0 = *(const f16x8*)(Ab + r0 * 1024 + kb0 * 8);
    pa1 = *(const f16x8*)(Ab + r0 * 1024 + (kb0 + 2) * 8);
    pb0 = *(const f16x8*)(Bb + r0 * 1024 + kb0 * 8);
    pb1 = *(const f16x8*)(Bb + r0 * 1024 + (kb0 + 2) * 8);
    f32x4 acc[8][4] = {};
    for (int kc = 0; kc < 32; ++kc) {
      _Float16* Ac = lds + (kc & 1) * 8192;
      _Float16* Bc = lds + 16384 + (kc & 1) * 8192;
      *(f16x8*)(Ac + kb0 * 2048 + r0 * 8) = pa0;
      *(f16x8*)(Ac + (kb0 + 2) * 2048 + r0 * 8) = pa1;
      *(f16x8*)(Bc + kb0 * 2048 + r0 * 8) = pb0;
      *(f16x8*)(Bc + (kb0 + 2) * 2048 + r0 * 8) = pb1;
      if (kc + 1 < 32) {
        int ko = (kc + 1) * 32;
        pa0 = *(const f16x8*)(Ab + r0 * 1024 + ko + kb0 * 8);
        pa1 = *(const f16x8*)(Ab + r0 * 1024 + ko + (kb0 + 2) * 8);
        pb0 = *(const f16x8*)(Bb + r0 * 1024 + ko + kb0 * 8);
        pb1 = *(const f16x8*)(Bb + r0 * 1024 + ko + (kb0 + 2) * 8);
      }
      __syncthreads();
      const int kb = lane >> 4;
      f16x8 af[8], bf[4];
#pragma unroll
      for (int mf = 0; mf < 8; ++mf) {
        int row = wm * 128 + mf * 16 + (lane & 15);
        af[mf] = *(const f16x8*)(Ac + kb * 2048 + row * 8);
      }
#pragma unroll
      for (int nf = 0; nf < 4; ++nf) {
        int row = wn * 64 + nf * 16 + (lane & 15);
        bf[nf] = *(const f16x8*)(Bc + kb * 2048 + row * 8);
      }
#pragma unroll
      for (int mf = 0; mf < 8; ++mf)
#pragma unroll
        for (int nf = 0; nf < 4; ++nf)
          acc[mf][nf] = __builtin_amdgcn_mfma_f32_16x16x32_f16(af[mf], bf[nf], acc[mf][nf], 0, 0, 0);
      // no second sync: double-buffered
    }
    const int rl = (lane >> 4) * 4;
#pragma unroll
    for (int mf = 0; mf < 8; ++mf) {
#pragma unroll
      for (int nf = 0; nf < 4; ++nf) {
#pragma unroll
        for (int j = 0; j < 4; ++j) {
          int rg = m * 256 + wm * 128 + mf * 16 + rl + j;
          int tt = rg >> 5, b = rg & 31;
          int ng = nt * 256 + wn * 64 + nf * 16 + (lane & 15);
          out[(size_t)(b * 64 + tt) * 32000 + ng] = acc[mf][nf][j] + cls_b[ng];
        }
      }
    }
  }
}

__global__ __launch_bounds__(512, 1) void k_lstm_fused(
    const _Float16* __restrict__ Pk0, const _Float16* __restrict__ Pk1,
    const float* __restrict__ gx, const float* __restrict__ x_f,
    float* __restrict__ c_f,
    _Float16* __restrict__ h0A, _Float16* __restrict__ h0B,
    _Float16* __restrict__ h1A, _Float16* __restrict__ h1B,
    float* __restrict__ ipfA, float* __restrict__ ipfB,
    float* __restrict__ outs_f, _Float16* __restrict__ outs_h,
    const float* __restrict__ cls_W, _Float16* __restrict__ clsW_h,
    const float* __restrict__ cls_b,
    float* __restrict__ out_logits,
    float* __restrict__ outHT, float* __restrict__ outCT,
    int* bar) {
  __shared__ _Float16 As[32 * 2056];  // 131,584 B (1 block/CU -> 256 blocks co-resident)
  const int bid = blockIdx.x;
  if (bid < 64) {
    run_phases<0>(bid & 63, Pk0, gx, x_f, c_f, h0A, h0B, h1A, h1B,
                  ipfA, ipfB, outs_f, outs_h, outHT, outCT, bar, As);
  } else if (bid < 128) {
    run_phases<1>(bid & 63, Pk1, gx, x_f, c_f, h0A, h0B, h1A, h1B,
                  ipfA, ipfB, outs_f, outs_h, outHT, outCT, bar, As);
  } else {
    // consumer blocks: convert clsW during the producers' early phases
    conv_clsW(cls_W, clsW_h, bid - 128);
    __syncthreads();
    if (threadIdx.x == 0)
      __hip_atomic_fetch_add(bar + 608, 1, __ATOMIC_RELAXED, __HIP_MEMORY_SCOPE_AGENT);
  }
  // all 256 blocks join the tile pool (producers arrive after their last gbar)
  run_consumer(outs_h, clsW_h, cls_b, out_logits, bar, As);
}

// ---------------- batched dot-attention + softmax ----------------
__global__ __launch_bounds__(256) void k_attn(const float* __restrict__ outs,
                                              const float* __restrict__ enc,
                                              float* __restrict__ att) {
  __shared__ float o_s[8][1024];
  __shared__ float sc[8][128];
  const int tid = threadIdx.x;
  const int lane = tid & 63;
  const int w = tid >> 6;
  const int b = blockIdx.x >> 3;
  const int t0 = (blockIdx.x & 7) * 8;
#pragma unroll
  for (int ii = 0; ii < 8; ++ii) {
    int idx = tid + ii * 256;
    int tt = idx >> 8, c4 = idx & 255;
    ((float4*)&o_s[tt][0])[c4] =
        *(const float4*)(outs + (size_t)((t0 + tt) * 32 + b) * 1024 + (size_t)c4 * 4);
  }
  __syncthreads();
  for (int si = 0; si < 32; ++si) {
    int s = w * 32 + si;
    float av[8] = {0, 0, 0, 0, 0, 0, 0, 0};
    const float* er = enc + (size_t)(b * 128 + s) * 1024;
#pragma unroll
    for (int i = 0; i < 4; ++i) {
      int k = i * 256 + lane * 4;
      float4 e = *(const float4*)(er + k);
#pragma unroll
      for (int tt = 0; tt < 8; ++tt) {
        float4 o = *(const float4*)&o_s[tt][k];
        av[tt] += e.x * o.x + e.y * o.y + e.z * o.z + e.w * o.w;
      }
    }
#pragma unroll
    for (int tt = 0; tt < 8; ++tt) {
      float v = av[tt];
#pragma unroll
      for (int off = 32; off > 0; off >>= 1) v += __shfl_down(v, off);
      if (lane == 0) sc[tt][s] = v;
    }
  }
  __syncthreads();
#pragma unroll
  for (int pp = 0; pp < 2; ++pp) {
    int tt = w + pp * 4;
    float a = sc[tt][lane], b2 = sc[tt][64 + lane];
    float m = fmaxf(a, b2);
#pragma unroll
    for (int off = 32; off > 0; off >>= 1) m = fmaxf(m, __shfl_xor(m, off));
    float e0 = expf(a - m), e1 = expf(b2 - m);
    float ss = e0 + e1;
#pragma unroll
    for (int off = 32; off > 0; off >>= 1) ss += __shfl_xor(ss, off);
    float r = 1.f / ss;
    att[(size_t)b * 8192 + (size_t)lane * 64 + t0 + tt] = e0 * r;
    att[(size_t)b * 8192 + (size_t)(64 + lane) * 64 + t0 + tt] = e1 * r;
  }
}

extern "C" void kernel_launch(void* const* d_in, const int* in_sizes, int n_in,
                              void* d_out, int out_size, void* d_ws, size_t ws_size,
                              hipStream_t stream) {
  const int*   dec   = (const int*)d_in[0];
  const float* h0    = (const float*)d_in[1];
  const float* c0    = (const float*)d_in[2];
  const float* enc   = (const float*)d_in[3];
  const float* emb   = (const float*)d_in[4];
  const float* W_ih  = (const float*)d_in[5];
  const float* W_hh  = (const float*)d_in[6];
  const float* b_ih  = (const float*)d_in[7];
  const float* b_hh  = (const float*)d_in[8];
  const float* cls_W = (const float*)d_in[9];
  const float* cls_b = (const float*)d_in[10];
  float* out = (float*)d_out;
  char* ws = (char*)d_ws;

  float*    x_f    = (float*)(ws + 0);                // [2048][1024] f32
  _Float16* x_h    = (_Float16*)(ws + 8388608);       // [2048][1024] f16 (dead after gx gemm)
  _Float16* Pk0    = (_Float16*)(ws + 8388608);       // 8MB packed Whh0 (written AFTER gx gemm)
  _Float16* Wih_h  = (_Float16*)(ws + 12582912);      // [8192][1024] f16 (dead after gx gemm)
  _Float16* Pk1    = (_Float16*)(ws + 29360128);      // 16MB packed [Wih1|Whh1]
  _Float16* clsW_h = (_Float16*)(ws + 46137344);      // [32000][1024] f16 (filled in-kernel)
  float*    gx     = (float*)(ws + 111673344);        // [2048][8192] f32
  float*    outs_f = (float*)(ws + 178782208);        // [2048][1024] f32
  _Float16* outs_h = (_Float16*)(ws + 187170816);     // [2048][1024] f16
  float*    c_f    = (float*)(ws + 191627264);        // [2][32][1024] f32
  _Float16* h0A    = (_Float16*)(ws + 191889408);     // [32][1024] f16
  _Float16* h0B    = (_Float16*)(ws + 191954944);
  _Float16* h1A    = (_Float16*)(ws + 192020480);
  _Float16* h1B    = (_Float16*)(ws + 192086016);
  int*      bar    = (int*)(ws + 192151552);          // 640 ints (tree barrier + gen + wcnt + conv)
  float*    ipfA   = (float*)(ws + 192155648);        // [32][1024] f32
  float*    ipfB   = (float*)(ws + 192286720);        // end 192417792

  k_f32_to_f16<<<2048, 256, 0, stream>>>(W_ih, Wih_h, 2097152);
  k_embed<<<2048, 256, 0, stream>>>(dec, emb, x_f, x_h);
  k_init<<<256, 256, 0, stream>>>(h0, c0, c_f, h0B, h1B, bar);
  k_pack1<<<4096, 256, 0, stream>>>(W_ih + (size_t)4096 * 1024, W_hh + (size_t)4096 * 1024, Pk1);
  // gx[r][0:4096] = x@Wih0^T + b_ih0 + b_hh0 ; gx[r][4096:8192] = x@Wih1^T + b_ih1 + b_hh1
  k_gemm0<<<dim3(64, 16), 256, 0, stream>>>(x_h, Wih_h, b_ih, b_hh, gx);
  k_pack0<<<2048, 256, 0, stream>>>(W_hh, Pk0);  // after gemm0: overwrites x_h/Wih_h region

  k_lstm_fused<<<256, 512, 0, stream>>>(Pk0, Pk1, gx, x_f, c_f,
                                        h0A, h0B, h1A, h1B, ipfA, ipfB,
                                        outs_f, outs_h, cls_W, clsW_h, cls_b, out,
                                        out + (size_t)65536000, out + (size_t)65601536,
                                        bar);

  k_attn<<<256, 256, 0, stream>>>(outs_f, enc, out + (size_t)65667072);
}

// Round 11
// 699.469 us; speedup vs baseline: 2.6043x; 1.1775x over previous
//
#include <hip/hip_runtime.h>
#include <math.h>

typedef _Float16 f16x8 __attribute__((ext_vector_type(8)));
typedef _Float16 f16x4 __attribute__((ext_vector_type(4)));
typedef float    f32x4 __attribute__((ext_vector_type(4)));
typedef unsigned long long u64;
typedef unsigned int u32;

#define ALOAD(p)    __hip_atomic_load((p), __ATOMIC_RELAXED, __HIP_MEMORY_SCOPE_AGENT)
#define ASTORE(p,v) __hip_atomic_store((p), (v), __ATOMIC_RELAXED, __HIP_MEMORY_SCOPE_AGENT)

// ---------------- conversion f32 -> f16 ----------------
__global__ __launch_bounds__(256) void k_f32_to_f16(const float* __restrict__ src,
                                                    _Float16* __restrict__ dst, int n4) {
  int i = blockIdx.x * 256 + threadIdx.x;
  int stride = gridDim.x * 256;
  for (; i < n4; i += stride) {
    float4 v = ((const float4*)src)[i];
    f16x4 o;
    o.x = (_Float16)v.x; o.y = (_Float16)v.y; o.z = (_Float16)v.z; o.w = (_Float16)v.w;
    ((f16x4*)dst)[i] = o;
  }
}

// ---------------- weight packing into per-wave fragment-stream order ----------------
__global__ __launch_bounds__(256) void k_pack0(const float* __restrict__ Whh0,
                                               _Float16* __restrict__ P) {
  int li = blockIdx.x * 256 + threadIdx.x;  // 524288
  int row = li >> 7, k8 = li & 127;
  const float* s = Whh0 + (size_t)row * 1024 + k8 * 8;
  int g = row >> 10, u = row & 1023, jb = u >> 4, col = u & 15;
  int kh = k8 >> 4, rem = k8 & 15, st = rem >> 2, kslot = rem & 3;
  size_t idx = ((size_t)(((jb * 8 + kh) * 4 + st) * 4 + g)) * 64 + kslot * 16 + col;
  f16x8 o;
#pragma unroll
  for (int j = 0; j < 8; ++j) o[j] = (_Float16)s[j];
  *(f16x8*)(P + idx * 8) = o;
}

__global__ __launch_bounds__(256) void k_pack1(const float* __restrict__ Wih1,
                                               const float* __restrict__ Whh1,
                                               _Float16* __restrict__ P) {
  int li = blockIdx.x * 256 + threadIdx.x;  // 1048576
  int mat = li >> 19;
  int li2 = li & 524287;
  int row = li2 >> 7, k8l = li2 & 127;
  const float* s = (mat ? Whh1 : Wih1) + (size_t)row * 1024 + k8l * 8;
  int g = row >> 10, u = row & 1023, jb = u >> 4, col = u & 15;
  int k8g = mat * 128 + k8l;
  int kh = k8g >> 5, rem = k8g & 31, st = rem >> 2, kslot = rem & 3;
  size_t idx = ((size_t)(((jb * 8 + kh) * 8 + st) * 4 + g)) * 64 + kslot * 16 + col;
  f16x8 o;
#pragma unroll
  for (int j = 0; j < 8; ++j) o[j] = (_Float16)s[j];
  *(f16x8*)(P + idx * 8) = o;
}

// ---------------- embedding + relu ----------------
__global__ __launch_bounds__(256) void k_embed(const int* __restrict__ dec,
                                               const float* __restrict__ emb,
                                               float* __restrict__ xf,
                                               _Float16* __restrict__ xh) {
  int i = blockIdx.x * 256 + threadIdx.x;  // 524288 float4 units
  int r = i >> 8;
  int c4 = i & 255;
  int b = r & 31, t = r >> 5;
  int tok = dec[b * 64 + t];
  float4 v = ((const float4*)(emb + (size_t)tok * 1024))[c4];
  v.x = fmaxf(v.x, 0.f); v.y = fmaxf(v.y, 0.f); v.z = fmaxf(v.z, 0.f); v.w = fmaxf(v.w, 0.f);
  ((float4*)(xf + (size_t)r * 1024))[c4] = v;
  f16x4 o;
  o.x = (_Float16)v.x; o.y = (_Float16)v.y; o.z = (_Float16)v.z; o.w = (_Float16)v.w;
  ((f16x4*)(xh + (size_t)r * 1024))[c4] = o;
}

// ---------------- state init (slot 0 of rotating buffers + barrier reset) ----------------
// NOTE: launched AFTER k_gemm0 (h0S/h1S reuse the dead Wih_h region).
__global__ __launch_bounds__(256) void k_init(const float* __restrict__ h0, const float* __restrict__ c0,
                                              float* __restrict__ c,
                                              _Float16* __restrict__ h0S, _Float16* __restrict__ h1S,
                                              int* __restrict__ bar) {
  int i = blockIdx.x * 256 + threadIdx.x;  // 65536
  float hv = h0[i];
  c[i] = c0[i];
  if (i < 32768) h0S[i] = (_Float16)hv;
  else           h1S[i - 32768] = (_Float16)hv;
  if (i < 640) bar[i] = 0;
}

// ---------------- tiled MFMA GEMM (gx precompute): C = A*B^T + biases ----------------
__global__ __launch_bounds__(256) void k_gemm0(const _Float16* __restrict__ A,
                                               const _Float16* __restrict__ Bm,
                                               const float* __restrict__ bias0,
                                               const float* __restrict__ bias1,
                                               float* __restrict__ C) {
  __shared__ _Float16 As[4 * 128 * 8];
  __shared__ _Float16 Bs[4 * 128 * 8];
  const int tid = threadIdx.x;
  const int lane = tid & 63;
  const int w = tid >> 6;
  const int wm = w >> 1, wn = w & 1;
  const _Float16* Ab = A + (size_t)blockIdx.y * 128 * 1024;
  const _Float16* Bb = Bm + (size_t)blockIdx.x * 128 * 1024;
  f32x4 acc[4][4] = {};
  for (int kc = 0; kc < 32; ++kc) {
#pragma unroll
    for (int ii = 0; ii < 2; ++ii) {
      int idx = tid + ii * 256;
      int kb = idx >> 7, row = idx & 127;
      int gofs = row * 1024 + kc * 32 + kb * 8;
      int sofs = kb * 1024 + row * 8;
      *(f16x8*)(As + sofs) = *(const f16x8*)(Ab + gofs);
      *(f16x8*)(Bs + sofs) = *(const f16x8*)(Bb + gofs);
    }
    __syncthreads();
    const int kb = lane >> 4;
    f16x8 af[4], bfv[4];
#pragma unroll
    for (int mf = 0; mf < 4; ++mf) {
      int row = wm * 64 + mf * 16 + (lane & 15);
      af[mf] = *(const f16x8*)(As + kb * 1024 + row * 8);
    }
#pragma unroll
    for (int nf = 0; nf < 4; ++nf) {
      int row = wn * 64 + nf * 16 + (lane & 15);
      bfv[nf] = *(const f16x8*)(Bs + kb * 1024 + row * 8);
    }
#pragma unroll
    for (int mf = 0; mf < 4; ++mf)
#pragma unroll
      for (int nf = 0; nf < 4; ++nf)
        acc[mf][nf] = __builtin_amdgcn_mfma_f32_16x16x32_f16(af[mf], bfv[nf], acc[mf][nf], 0, 0, 0);
    __syncthreads();
  }
  const int rl = (lane >> 4) * 4;
#pragma unroll
  for (int mf = 0; mf < 4; ++mf) {
#pragma unroll
    for (int nf = 0; nf < 4; ++nf) {
#pragma unroll
      for (int j = 0; j < 4; ++j) {
        int m = wm * 64 + mf * 16 + rl + j;
        int n = wn * 64 + nf * 16 + (lane & 15);
        int rg = blockIdx.y * 128 + m;
        int ng = blockIdx.x * 128 + n;
        C[(size_t)rg * 8192 + ng] = acc[mf][nf][j] + bias0[ng] + bias1[ng];
      }
    }
  }
}

// ---------------- two-level tree barrier (RELAXED-only) ----------------
__device__ __forceinline__ void gbar(int* bar) {
  __syncthreads();
  if (threadIdx.x == 0) {
    int* gen = bar + 544;
    int g = ALOAD(gen);
    int grp = blockIdx.x >> 3;
    int a = __hip_atomic_fetch_add(bar + grp * 32, 1, __ATOMIC_RELAXED, __HIP_MEMORY_SCOPE_AGENT);
    if (a == 7) {
      ASTORE(bar + grp * 32, 0);
      int r = __hip_atomic_fetch_add(bar + 512, 1, __ATOMIC_RELAXED, __HIP_MEMORY_SCOPE_AGENT);
      if (r == 15) {
        ASTORE(bar + 512, 0);
        ASTORE(gen, g + 1);
      }
    }
    while (ALOAD(gen) == g) __builtin_amdgcn_s_sleep(1);
  }
  __syncthreads();
}

// ---------------- persistent LSTM phases (blocks 0..127) ----------------
// State exchange: WRITE-ONCE rotating slots. Writers use sc1 (write-through to the
// coherence point); readers use PLAIN CACHED loads — safe because every slot address
// is read only after its unique write (never cached stale; deterministic across graph
// replays, so even a prior-replay line holds identical values). Blocks sharing an XCD
// L2-hit on the broadcast state -> ~8x less fabric traffic than sc1 reads.
template <int ROLE>
__device__ __forceinline__ void run_phases(
    int jb, const _Float16* __restrict__ Pk,
    const float* __restrict__ gx, const float* __restrict__ x_f,
    float* __restrict__ c_f,
    _Float16* __restrict__ h0S, _Float16* __restrict__ h1S,
    float* __restrict__ ipfA, float* __restrict__ ipfB,
    float* __restrict__ outs_f, _Float16* __restrict__ outs_h,
    float* __restrict__ outHT, float* __restrict__ outCT,
    int* bar, _Float16* As) {
  constexpr int S = ROLE ? 8 : 4;
  constexpr int NHALF = ROLE ? 2 : 1;
  constexpr int RSH = ROLE ? 8 : 7;
  constexpr int K8M = ROLE ? 255 : 127;
  const int u0 = jb * 16;
  const int tid = threadIdx.x;
  const int lane = tid & 63;
  const int kh = tid >> 6;
  const int col = lane & 15;
  const int kslot = lane >> 4;

  float* cst = c_f + ROLE * 32768;
  const float* gxbase = gx + (ROLE ? 4096 : 0);
  const int cb = tid >> 4, cul = tid & 15, cu = u0 + cul;

  const _Float16* pkbase = Pk + ((size_t)(jb * 8 + kh) * S) * 4 * 512 + lane * 8;
  const int a0off = col * 2056 + kh * S * 32 + kslot * 8;
  const int a1off = a0off + 16 * 2056;

  // weights pinned in registers for the whole recurrence
  f16x8 wreg[S * 4];
#pragma unroll
  for (int i = 0; i < S * 4; ++i) wreg[i] = *(const f16x8*)(pkbase + i * 512);

  for (int p = 0; p <= 64; ++p) {
    const bool active = (ROLE == 0) ? (p < 64) : (p > 0);
    if (active) {
      const int t = (ROLE == 0) ? p : p - 1;
      // rotating slots: H0[s] = h0 after step s-1; role0 phase p: read H0[p], write H0[p+1].
      // role1 phase p: read H0[p] + H1[p-1], write H1[p].
      const _Float16* h0r = h0S + (size_t)p * 32768;
      _Float16* h0w = h0S + (size_t)(p + 1) * 32768;
      const _Float16* h1r = h1S + (size_t)(p - 1) * 32768;
      _Float16* h1w = h1S + (size_t)p * 32768;
      const float* ipfr; float* ipfw;
      if (p & 1) { ipfr = ipfA; ipfw = ipfB; }
      else       { ipfr = ipfB; ipfw = ipfA; }

      const float* gxr = gxbase + (size_t)(t * 32 + cb) * 8192;
      float pg0 = gxr[cu], pg1 = gxr[1024 + cu], pg2 = gxr[2048 + cu], pg3 = gxr[3072 + cu];
      float pc = cst[cb * 1024 + cu];
      float px = 0.f, pip = 0.f;
      if (ROLE == 0) px = x_f[(size_t)(t * 32 + cb) * 1024 + cu];
      else           pip = ALOAD(ipfr + cb * 1024 + cu);

      // ---- state -> LDS (plain cached loads; addresses are write-once-fresh) ----
#pragma unroll
      for (int hf = 0; hf < NHALF; ++hf) {
        f16x8 sreg[8];
#pragma unroll
        for (int i = 0; i < 8; ++i) {
          int fr = (hf * 8 + i) * 512 + tid;
          int row = fr >> RSH, k8 = fr & K8M;
          const _Float16* s;
          if (ROLE == 0) s = h0r + row * 1024 + k8 * 8;
          else           s = (k8 < 128) ? (h0r + row * 1024 + k8 * 8)
                                        : (h1r + row * 1024 + (k8 - 128) * 8);
          sreg[i] = *(const f16x8*)s;
        }
#pragma unroll
        for (int i = 0; i < 8; ++i) {
          int fr = (hf * 8 + i) * 512 + tid;
          int row = fr >> RSH, k8 = fr & K8M;
          *(f16x8*)(As + row * 2056 + k8 * 8) = sreg[i];
        }
      }
      __syncthreads();

      f32x4 acc[2][4] = {};
#pragma unroll
      for (int s2 = 0; s2 < S; ++s2) {
        f16x8 a0 = *(const f16x8*)(As + a0off + s2 * 32);
        f16x8 a1 = *(const f16x8*)(As + a1off + s2 * 32);
        acc[0][0] = __builtin_amdgcn_mfma_f32_16x16x32_f16(a0, wreg[s2 * 4 + 0], acc[0][0], 0, 0, 0);
        acc[1][0] = __builtin_amdgcn_mfma_f32_16x16x32_f16(a1, wreg[s2 * 4 + 0], acc[1][0], 0, 0, 0);
        acc[0][1] = __builtin_amdgcn_mfma_f32_16x16x32_f16(a0, wreg[s2 * 4 + 1], acc[0][1], 0, 0, 0);
        acc[1][1] = __builtin_amdgcn_mfma_f32_16x16x32_f16(a1, wreg[s2 * 4 + 1], acc[1][1], 0, 0, 0);
        acc[0][2] = __builtin_amdgcn_mfma_f32_16x16x32_f16(a0, wreg[s2 * 4 + 2], acc[0][2], 0, 0, 0);
        acc[1][2] = __builtin_amdgcn_mfma_f32_16x16x32_f16(a1, wreg[s2 * 4 + 2], acc[1][2], 0, 0, 0);
        acc[0][3] = __builtin_amdgcn_mfma_f32_16x16x32_f16(a0, wreg[s2 * 4 + 3], acc[0][3], 0, 0, 0);
        acc[1][3] = __builtin_amdgcn_mfma_f32_16x16x32_f16(a1, wreg[s2 * 4 + 3], acc[1][3], 0, 0, 0);
      }
      __syncthreads();

      float (*gs)[32][68] = (float (*)[32][68])(void*)As;
      const int rl = kslot * 4;
      if (kh < 4) {
#pragma unroll
        for (int m = 0; m < 2; ++m)
#pragma unroll
          for (int g = 0; g < 4; ++g)
#pragma unroll
            for (int j = 0; j < 4; ++j)
              gs[kh][m * 16 + rl + j][g * 16 + col] = acc[m][g][j];
      }
      __syncthreads();
      if (kh >= 4) {
#pragma unroll
        for (int m = 0; m < 2; ++m)
#pragma unroll
          for (int g = 0; g < 4; ++g)
#pragma unroll
            for (int j = 0; j < 4; ++j)
              gs[kh - 4][m * 16 + rl + j][g * 16 + col] += acc[m][g][j];
      }
      __syncthreads();

      {
        float ig = pg0, fg = pg1, gg = pg2, og = pg3;
#pragma unroll
        for (int cc = 0; cc < 4; ++cc) {
          ig += gs[cc][cb][cul];
          fg += gs[cc][cb][16 + cul];
          gg += gs[cc][cb][32 + cul];
          og += gs[cc][cb][48 + cul];
        }
        float si = 1.f / (1.f + expf(-ig));
        float sf = 1.f / (1.f + expf(-fg));
        float so = 1.f / (1.f + expf(-og));
        float ci = sf * pc + si * tanhf(gg);
        float hi = so * tanhf(ci);
        cst[cb * 1024 + cu] = ci;
        if (t == 63) {
          outHT[ROLE * 32768 + cb * 1024 + cu] = hi;
          outCT[ROLE * 32768 + cb * 1024 + cu] = ci;
        }
        if (ROLE == 0) {
          float hn = __shfl_down(hi, 1);
          float ipv = hi + px;
          float ipn = __shfl_down(ipv, 1);
          if ((cul & 1) == 0) {
            union { _Float16 h[2]; u32 v; } ph;
            ph.h[0] = (_Float16)hi; ph.h[1] = (_Float16)hn;
            ASTORE((u32*)(h0w + cb * 1024 + cu), ph.v);
            union { float f[2]; u64 v; } pi;
            pi.f[0] = ipv; pi.f[1] = ipn;
            ASTORE((u64*)(ipfw + cb * 1024 + cu), pi.v);
          }
        } else {
          float hn = __shfl_down(hi, 1);
          float ro = hi + pip;
          float rn = __shfl_down(ro, 1);
          if ((cul & 1) == 0) {
            union { _Float16 h[2]; u32 v; } ph;
            ph.h[0] = (_Float16)hi; ph.h[1] = (_Float16)hn;
            ASTORE((u32*)(h1w + cb * 1024 + cu), ph.v);
            union { _Float16 h[2]; u32 v; } po;
            po.h[0] = (_Float16)ro; po.h[1] = (_Float16)rn;
            ASTORE((u32*)(outs_h + (size_t)(t * 32 + cb) * 1024 + cu), po.v);
          }
          outs_f[(size_t)(t * 32 + cb) * 1024 + cu] = ro;
        }
      }
    }
    gbar(bar);  // every phase, incl. last -> gen ends at 65
  }
}

// ---------------- clsW f32->f16 conversion by consumer blocks ----------------
// nt loads (ext_vector type for the builtin): keep the 128 MB f32 stream out of L3.
__device__ __forceinline__ void conv_clsW(const float* __restrict__ src,
                                          _Float16* __restrict__ dst, int cb) {
  for (int i = cb * 512 + threadIdx.x; i < 4096000; i += 65536) {
    const f32x4* s = (const f32x4*)(src + (size_t)i * 8);
    f32x4 v0 = __builtin_nontemporal_load(s);
    f32x4 v1 = __builtin_nontemporal_load(s + 1);
    union { _Float16 h[8]; u64 q[2]; } o;
    o.h[0] = (_Float16)v0.x; o.h[1] = (_Float16)v0.y;
    o.h[2] = (_Float16)v0.z; o.h[3] = (_Float16)v0.w;
    o.h[4] = (_Float16)v1.x; o.h[5] = (_Float16)v1.y;
    o.h[6] = (_Float16)v1.z; o.h[7] = (_Float16)v1.w;
    u64* d = (u64*)(dst + (size_t)i * 8);
    ASTORE(d, o.q[0]);
    ASTORE(d + 1, o.q[1]);
  }
}

// ---------------- logits GEMM consumer: 256x256 tiles, dynamic work-steal ----------------
// 1000 tiles (m 0..7 x nt 0..124), m-major via atomic counter bar[576].
// m-tile m needs gen >= min(8m+9, 65). Conversion gate: bar[608] == 128.
// Logits written NON-TEMPORAL: the 256MB f32 stream must not thrash L3
// (keeps clsW_h L3-resident -> consumer B-reads are L3 hits, not HBM).
__device__ __forceinline__ void run_consumer(
    const _Float16* __restrict__ outs_h, const _Float16* __restrict__ clsW_h,
    const float* __restrict__ cls_b, float* __restrict__ out, int* bar, _Float16* lds) {
  __shared__ int tau_s;
  const int tid = threadIdx.x;
  const int lane = tid & 63;
  const int w = tid >> 6;
  const int wm = w >> 2, wn = w & 3;      // 2x4 wave grid; wave tile 128x64
  int* gen = bar + 544;
  int* wcnt = bar + 576;
  const int r0 = tid & 255, kb0 = tid >> 8;

  if (tid == 0) {
    while (ALOAD(bar + 608) < 128) __builtin_amdgcn_s_sleep(16);
  }
  __syncthreads();

  for (;;) {
    if (tid == 0) tau_s = __hip_atomic_fetch_add(wcnt, 1, __ATOMIC_RELAXED, __HIP_MEMORY_SCOPE_AGENT);
    __syncthreads();
    int tau = tau_s;
    if (tau >= 1000) break;
    int m = tau / 125, nt = tau - m * 125;
    if (tid == 0) {
      int need = 8 * m + 9; if (need > 65) need = 65;
      while (ALOAD(gen) < need) __builtin_amdgcn_s_sleep(64);
    }
    __syncthreads();

    const _Float16* Ab = outs_h + (size_t)m * 256 * 1024;
    const _Float16* Bb = clsW_h + (size_t)nt * 256 * 1024;
    f16x8 pa0, pa1, pb0, pb1;
    pa0 = *(const f16x8*)(Ab + r0 * 1024 + kb0 * 8);
    pa1 = *(const f16x8*)(Ab + r0 * 1024 + (kb0 + 2) * 8);
    pb0 = *(const f16x8*)(Bb + r0 * 1024 + kb0 * 8);
    pb1 = *(const f16x8*)(Bb + r0 * 1024 + (kb0 + 2) * 8);
    f32x4 acc[8][4] = {};
    for (int kc = 0; kc < 32; ++kc) {
      _Float16* Ac = lds + (kc & 1) * 8192;
      _Float16* Bc = lds + 16384 + (kc & 1) * 8192;
      *(f16x8*)(Ac + kb0 * 2048 + r0 * 8) = pa0;
      *(f16x8*)(Ac + (kb0 + 2) * 2048 + r0 * 8) = pa1;
      *(f16x8*)(Bc + kb0 * 2048 + r0 * 8) = pb0;
      *(f16x8*)(Bc + (kb0 + 2) * 2048 + r0 * 8) = pb1;
      if (kc + 1 < 32) {
        int ko = (kc + 1) * 32;
        pa0 = *(const f16x8*)(Ab + r0 * 1024 + ko + kb0 * 8);
        pa1 = *(const f16x8*)(Ab + r0 * 1024 + ko + (kb0 + 2) * 8);
        pb0 = *(const f16x8*)(Bb + r0 * 1024 + ko + kb0 * 8);
        pb1 = *(const f16x8*)(Bb + r0 * 1024 + ko + (kb0 + 2) * 8);
      }
      __syncthreads();
      const int kb = lane >> 4;
      f16x8 af[8], bf[4];
#pragma unroll
      for (int mf = 0; mf < 8; ++mf) {
        int row = wm * 128 + mf * 16 + (lane & 15);
        af[mf] = *(const f16x8*)(Ac + kb * 2048 + row * 8);
      }
#pragma unroll
      for (int nf = 0; nf < 4; ++nf) {
        int row = wn * 64 + nf * 16 + (lane & 15);
        bf[nf] = *(const f16x8*)(Bc + kb * 2048 + row * 8);
      }
#pragma unroll
      for (int mf = 0; mf < 8; ++mf)
#pragma unroll
        for (int nf = 0; nf < 4; ++nf)
          acc[mf][nf] = __builtin_amdgcn_mfma_f32_16x16x32_f16(af[mf], bf[nf], acc[mf][nf], 0, 0, 0);
    }
    const int rl = (lane >> 4) * 4;
#pragma unroll
    for (int mf = 0; mf < 8; ++mf) {
#pragma unroll
      for (int nf = 0; nf < 4; ++nf) {
#pragma unroll
        for (int j = 0; j < 4; ++j) {
          int rg = m * 256 + wm * 128 + mf * 16 + rl + j;
          int tt = rg >> 5, b = rg & 31;
          int ng = nt * 256 + wn * 64 + nf * 16 + (lane & 15);
          __builtin_nontemporal_store(acc[mf][nf][j] + cls_b[ng],
                                      &out[(size_t)(b * 64 + tt) * 32000 + ng]);
        }
      }
    }
  }
}

__global__ __launch_bounds__(512, 1) void k_lstm_fused(
    const _Float16* __restrict__ Pk0, const _Float16* __restrict__ Pk1,
    const float* __restrict__ gx, const float* __restrict__ x_f,
    float* __restrict__ c_f,
    _Float16* __restrict__ h0S, _Float16* __restrict__ h1S,
    float* __restrict__ ipfA, float* __restrict__ ipfB,
    float* __restrict__ outs_f, _Float16* __restrict__ outs_h,
    const float* __restrict__ cls_W, _Float16* __restrict__ clsW_h,
    const float* __restrict__ cls_b,
    float* __restrict__ out_logits,
    float* __restrict__ outHT, float* __restrict__ outCT,
    int* bar) {
  __shared__ _Float16 As[32 * 2056];  // 131,584 B (1 block/CU -> 256 blocks co-resident)
  const int bid = blockIdx.x;
  if (bid < 64) {
    run_phases<0>(bid & 63, Pk0, gx, x_f, c_f, h0S, h1S,
                  ipfA, ipfB, outs_f, outs_h, outHT, outCT, bar, As);
  } else if (bid < 128) {
    run_phases<1>(bid & 63, Pk1, gx, x_f, c_f, h0S, h1S,
                  ipfA, ipfB, outs_f, outs_h, outHT, outCT, bar, As);
  } else {
    conv_clsW(cls_W, clsW_h, bid - 128);
    __syncthreads();
    if (threadIdx.x == 0)
      __hip_atomic_fetch_add(bar + 608, 1, __ATOMIC_RELAXED, __HIP_MEMORY_SCOPE_AGENT);
  }
  run_consumer(outs_h, clsW_h, cls_b, out_logits, bar, As);
}

// ---------------- batched dot-attention + softmax ----------------
__global__ __launch_bounds__(256) void k_attn(const float* __restrict__ outs,
                                              const float* __restrict__ enc,
                                              float* __restrict__ att) {
  __shared__ float o_s[8][1024];
  __shared__ float sc[8][128];
  const int tid = threadIdx.x;
  const int lane = tid & 63;
  const int w = tid >> 6;
  const int b = blockIdx.x >> 3;
  const int t0 = (blockIdx.x & 7) * 8;
#pragma unroll
  for (int ii = 0; ii < 8; ++ii) {
    int idx = tid + ii * 256;
    int tt = idx >> 8, c4 = idx & 255;
    ((float4*)&o_s[tt][0])[c4] =
        *(const float4*)(outs + (size_t)((t0 + tt) * 32 + b) * 1024 + (size_t)c4 * 4);
  }
  __syncthreads();
  for (int si = 0; si < 32; ++si) {
    int s = w * 32 + si;
    float av[8] = {0, 0, 0, 0, 0, 0, 0, 0};
    const float* er = enc + (size_t)(b * 128 + s) * 1024;
#pragma unroll
    for (int i = 0; i < 4; ++i) {
      int k = i * 256 + lane * 4;
      float4 e = *(const float4*)(er + k);
#pragma unroll
      for (int tt = 0; tt < 8; ++tt) {
        float4 o = *(const float4*)&o_s[tt][k];
        av[tt] += e.x * o.x + e.y * o.y + e.z * o.z + e.w * o.w;
      }
    }
#pragma unroll
    for (int tt = 0; tt < 8; ++tt) {
      float v = av[tt];
#pragma unroll
      for (int off = 32; off > 0; off >>= 1) v += __shfl_down(v, off);
      if (lane == 0) sc[tt][s] = v;
    }
  }
  __syncthreads();
#pragma unroll
  for (int pp = 0; pp < 2; ++pp) {
    int tt = w + pp * 4;
    float a = sc[tt][lane], b2 = sc[tt][64 + lane];
    float m = fmaxf(a, b2);
#pragma unroll
    for (int off = 32; off > 0; off >>= 1) m = fmaxf(m, __shfl_xor(m, off));
    float e0 = expf(a - m), e1 = expf(b2 - m);
    float ss = e0 + e1;
#pragma unroll
    for (int off = 32; off > 0; off >>= 1) ss += __shfl_xor(ss, off);
    float r = 1.f / ss;
    att[(size_t)b * 8192 + (size_t)lane * 64 + t0 + tt] = e0 * r;
    att[(size_t)b * 8192 + (size_t)(64 + lane) * 64 + t0 + tt] = e1 * r;
  }
}

extern "C" void kernel_launch(void* const* d_in, const int* in_sizes, int n_in,
                              void* d_out, int out_size, void* d_ws, size_t ws_size,
                              hipStream_t stream) {
  const int*   dec   = (const int*)d_in[0];
  const float* h0    = (const float*)d_in[1];
  const float* c0    = (const float*)d_in[2];
  const float* enc   = (const float*)d_in[3];
  const float* emb   = (const float*)d_in[4];
  const float* W_ih  = (const float*)d_in[5];
  const float* W_hh  = (const float*)d_in[6];
  const float* b_ih  = (const float*)d_in[7];
  const float* b_hh  = (const float*)d_in[8];
  const float* cls_W = (const float*)d_in[9];
  const float* cls_b = (const float*)d_in[10];
  float* out = (float*)d_out;
  char* ws = (char*)d_ws;

  float*    x_f    = (float*)(ws + 0);                // [2048][1024] f32
  _Float16* x_h    = (_Float16*)(ws + 8388608);       // [2048][1024] f16 (dead after gx gemm)
  _Float16* Pk0    = (_Float16*)(ws + 8388608);       // 8MB packed Whh0 (written AFTER gx gemm)
  _Float16* Wih_h  = (_Float16*)(ws + 12582912);      // [8192][1024] f16 (dead after gx gemm)
  _Float16* h0S    = (_Float16*)(ws + 16777216);      // 65 x [32][1024] f16 rotating (after gemm0)
  _Float16* h1S    = (_Float16*)(ws + 21037056);      // 65 x [32][1024] f16 rotating
  _Float16* Pk1    = (_Float16*)(ws + 29360128);      // 16MB packed [Wih1|Whh1]
  _Float16* clsW_h = (_Float16*)(ws + 46137344);      // [32000][1024] f16 (filled in-kernel)
  float*    gx     = (float*)(ws + 111673344);        // [2048][8192] f32
  float*    outs_f = (float*)(ws + 178782208);        // [2048][1024] f32
  _Float16* outs_h = (_Float16*)(ws + 187170816);     // [2048][1024] f16
  float*    c_f    = (float*)(ws + 191627264);        // [2][32][1024] f32
  int*      bar    = (int*)(ws + 192151552);          // 640 ints
  float*    ipfA   = (float*)(ws + 192155648);        // [32][1024] f32
  float*    ipfB   = (float*)(ws + 192286720);        // end 192417792

  k_f32_to_f16<<<2048, 256, 0, stream>>>(W_ih, Wih_h, 2097152);
  k_embed<<<2048, 256, 0, stream>>>(dec, emb, x_f, x_h);
  k_pack1<<<4096, 256, 0, stream>>>(W_ih + (size_t)4096 * 1024, W_hh + (size_t)4096 * 1024, Pk1);
  // gx[r][0:4096] = x@Wih0^T + b_ih0 + b_hh0 ; gx[r][4096:8192] = x@Wih1^T + b_ih1 + b_hh1
  k_gemm0<<<dim3(64, 16), 256, 0, stream>>>(x_h, Wih_h, b_ih, b_hh, gx);
  k_pack0<<<2048, 256, 0, stream>>>(W_hh, Pk0);   // after gemm0: overwrites x_h region
  k_init<<<256, 256, 0, stream>>>(h0, c0, c_f, h0S, h1S, bar);  // after gemm0: h0S/h1S in old Wih_h region

  k_lstm_fused<<<256, 512, 0, stream>>>(Pk0, Pk1, gx, x_f, c_f,
                                        h0S, h1S, ipfA, ipfB,
                                        outs_f, outs_h, cls_W, clsW_h, cls_b, out,
                                        out + (size_t)65536000, out + (size_t)65601536,
                                        bar);

  k_attn<<<256, 256, 0, stream>>>(outs_f, enc, out + (size_t)65667072);
}

// Round 15
// 667.306 us; speedup vs baseline: 2.7298x; 1.0482x over previous
//
#include <hip/hip_runtime.h>
#include <math.h>

typedef _Float16 f16x8 __attribute__((ext_vector_type(8)));
typedef _Float16 f16x4 __attribute__((ext_vector_type(4)));
typedef float    f32x4 __attribute__((ext_vector_type(4)));
typedef unsigned long long u64;
typedef unsigned int u32;

#define ALOAD(p)    __hip_atomic_load((p), __ATOMIC_RELAXED, __HIP_MEMORY_SCOPE_AGENT)
#define ASTORE(p,v) __hip_atomic_store((p), (v), __ATOMIC_RELAXED, __HIP_MEMORY_SCOPE_AGENT)

// ---------------- merged prep: conv(W_ih) | embed | pack1 | pack0 | init ----------------
__global__ __launch_bounds__(256) void k_prep(
    const float* __restrict__ W_ih, _Float16* __restrict__ Wih_h,
    const int* __restrict__ dec, const float* __restrict__ emb,
    float* __restrict__ xf, _Float16* __restrict__ xh,
    const float* __restrict__ W_hh, _Float16* __restrict__ Pk0, _Float16* __restrict__ Pk1,
    const float* __restrict__ h0, const float* __restrict__ c0,
    float* __restrict__ c, _Float16* __restrict__ h0S, _Float16* __restrict__ h1S,
    int* __restrict__ bar) {
  const int bid = blockIdx.x;
  const int tid = threadIdx.x;
  if (bid < 2048) {
    // conv W_ih (f32->f16): 2,097,152 float4 units, four per thread
#pragma unroll
    for (int q = 0; q < 4; ++q) {
      int i = q * 524288 + bid * 256 + tid;
      float4 v = ((const float4*)W_ih)[i];
      f16x4 o;
      o.x = (_Float16)v.x; o.y = (_Float16)v.y; o.z = (_Float16)v.z; o.w = (_Float16)v.w;
      ((f16x4*)Wih_h)[i] = o;
    }
  } else if (bid < 4096) {
    // embedding + relu, 524,288 float4 units; row r = t*32 + b
    int i = (bid - 2048) * 256 + tid;
    int r = i >> 8, c4 = i & 255;
    int b = r & 31, t = r >> 5;
    int tok = dec[b * 64 + t];
    float4 v = ((const float4*)(emb + (size_t)tok * 1024))[c4];
    v.x = fmaxf(v.x, 0.f); v.y = fmaxf(v.y, 0.f); v.z = fmaxf(v.z, 0.f); v.w = fmaxf(v.w, 0.f);
    ((float4*)(xf + (size_t)r * 1024))[c4] = v;
    f16x4 o;
    o.x = (_Float16)v.x; o.y = (_Float16)v.y; o.z = (_Float16)v.z; o.w = (_Float16)v.w;
    ((f16x4*)(xh + (size_t)r * 1024))[c4] = o;
  } else if (bid < 8192) {
    // pack1: [Wih1|Whh1] -> Pk1, 1,048,576 units
    int li = (bid - 4096) * 256 + tid;
    int mat = li >> 19;
    int li2 = li & 524287;
    int row = li2 >> 7, k8l = li2 & 127;
    const float* s = (mat ? (W_hh + (size_t)4096 * 1024) : (W_ih + (size_t)4096 * 1024))
                     + (size_t)row * 1024 + k8l * 8;
    int g = row >> 10, u = row & 1023, jb = u >> 4, col = u & 15;
    int k8g = mat * 128 + k8l;
    int kh = k8g >> 5, rem = k8g & 31, st = rem >> 2, kslot = rem & 3;
    size_t idx = ((size_t)(((jb * 8 + kh) * 8 + st) * 4 + g)) * 64 + kslot * 16 + col;
    f16x8 o;
#pragma unroll
    for (int j = 0; j < 8; ++j) o[j] = (_Float16)s[j];
    *(f16x8*)(Pk1 + idx * 8) = o;
  } else if (bid < 10240) {
    // pack0: Whh0 -> Pk0, 524,288 units
    int li = (bid - 8192) * 256 + tid;
    int row = li >> 7, k8 = li & 127;
    const float* s = W_hh + (size_t)row * 1024 + k8 * 8;
    int g = row >> 10, u = row & 1023, jb = u >> 4, col = u & 15;
    int kh = k8 >> 4, rem = k8 & 15, st = rem >> 2, kslot = rem & 3;
    size_t idx = ((size_t)(((jb * 8 + kh) * 4 + st) * 4 + g)) * 64 + kslot * 16 + col;
    f16x8 o;
#pragma unroll
    for (int j = 0; j < 8; ++j) o[j] = (_Float16)s[j];
    *(f16x8*)(Pk0 + idx * 8) = o;
  } else {
    // init: state slot 0 + barrier reset, 65,536 elements
    int i = (bid - 10240) * 256 + tid;
    float hv = h0[i];
    c[i] = c0[i];
    if (i < 32768) h0S[i] = (_Float16)hv;
    else           h1S[i - 32768] = (_Float16)hv;
    if (i < 640) bar[i] = 0;
  }
}

// ---------------- gx GEMM, 256x256 tiles (proven consumer-tile body) ----------------
// gx[2048][8192] = x_h @ Wih_h^T + b_ih + b_hh; grid (32 n-tiles, 8 m-tiles), 512 thr.
__global__ __launch_bounds__(512) void k_gemm0b(const _Float16* __restrict__ A,
                                                const _Float16* __restrict__ Bm,
                                                const float* __restrict__ bias0,
                                                const float* __restrict__ bias1,
                                                float* __restrict__ C) {
  __shared__ _Float16 lds2[32768];  // A dbuf 2x8192 + B dbuf 2x8192 (64 KB)
  const int tid = threadIdx.x;
  const int lane = tid & 63;
  const int w = tid >> 6;
  const int wm = w >> 2, wn = w & 3;      // 2x4 waves; wave tile 128x64
  const int r0 = tid & 255, kb0 = tid >> 8;
  const int m = blockIdx.y, nt = blockIdx.x;
  const _Float16* Ab = A + (size_t)m * 256 * 1024;
  const _Float16* Bb = Bm + (size_t)nt * 256 * 1024;
  f16x8 pa0, pa1, pb0, pb1;
  pa0 = *(const f16x8*)(Ab + r0 * 1024 + kb0 * 8);
  pa1 = *(const f16x8*)(Ab + r0 * 1024 + (kb0 + 2) * 8);
  pb0 = *(const f16x8*)(Bb + r0 * 1024 + kb0 * 8);
  pb1 = *(const f16x8*)(Bb + r0 * 1024 + (kb0 + 2) * 8);
  f32x4 acc[8][4] = {};
  for (int kc = 0; kc < 32; ++kc) {
    _Float16* Ac = lds2 + (kc & 1) * 8192;
    _Float16* Bc = lds2 + 16384 + (kc & 1) * 8192;
    *(f16x8*)(Ac + kb0 * 2048 + r0 * 8) = pa0;
    *(f16x8*)(Ac + (kb0 + 2) * 2048 + r0 * 8) = pa1;
    *(f16x8*)(Bc + kb0 * 2048 + r0 * 8) = pb0;
    *(f16x8*)(Bc + (kb0 + 2) * 2048 + r0 * 8) = pb1;
    if (kc + 1 < 32) {
      int ko = (kc + 1) * 32;
      pa0 = *(const f16x8*)(Ab + r0 * 1024 + ko + kb0 * 8);
      pa1 = *(const f16x8*)(Ab + r0 * 1024 + ko + (kb0 + 2) * 8);
      pb0 = *(const f16x8*)(Bb + r0 * 1024 + ko + kb0 * 8);
      pb1 = *(const f16x8*)(Bb + r0 * 1024 + ko + (kb0 + 2) * 8);
    }
    __syncthreads();
    const int kb = lane >> 4;
    f16x8 af[8], bf[4];
#pragma unroll
    for (int mf = 0; mf < 8; ++mf) {
      int row = wm * 128 + mf * 16 + (lane & 15);
      af[mf] = *(const f16x8*)(Ac + kb * 2048 + row * 8);
    }
#pragma unroll
    for (int nf = 0; nf < 4; ++nf) {
      int row = wn * 64 + nf * 16 + (lane & 15);
      bf[nf] = *(const f16x8*)(Bc + kb * 2048 + row * 8);
    }
#pragma unroll
    for (int mf = 0; mf < 8; ++mf)
#pragma unroll
      for (int nf = 0; nf < 4; ++nf)
        acc[mf][nf] = __builtin_amdgcn_mfma_f32_16x16x32_f16(af[mf], bf[nf], acc[mf][nf], 0, 0, 0);
  }
  const int rl = (lane >> 4) * 4;
#pragma unroll
  for (int mf = 0; mf < 8; ++mf) {
#pragma unroll
    for (int nf = 0; nf < 4; ++nf) {
#pragma unroll
      for (int j = 0; j < 4; ++j) {
        int rg = m * 256 + wm * 128 + mf * 16 + rl + j;
        int ng = nt * 256 + wn * 64 + nf * 16 + (lane & 15);
        C[(size_t)rg * 8192 + ng] = acc[mf][nf][j] + bias0[ng] + bias1[ng];
      }
    }
  }
}

// ---------------- two-level tree barrier (RELAXED-only) ----------------
__device__ __forceinline__ void gbar(int* bar) {
  __syncthreads();
  if (threadIdx.x == 0) {
    int* gen = bar + 544;
    int g = ALOAD(gen);
    int grp = blockIdx.x >> 3;
    int a = __hip_atomic_fetch_add(bar + grp * 32, 1, __ATOMIC_RELAXED, __HIP_MEMORY_SCOPE_AGENT);
    if (a == 7) {
      ASTORE(bar + grp * 32, 0);
      int r = __hip_atomic_fetch_add(bar + 512, 1, __ATOMIC_RELAXED, __HIP_MEMORY_SCOPE_AGENT);
      if (r == 15) {
        ASTORE(bar + 512, 0);
        ASTORE(gen, g + 1);
      }
    }
    while (ALOAD(gen) == g) __builtin_amdgcn_s_sleep(1);
  }
  __syncthreads();
}

// ---------------- persistent LSTM phases (blocks 0..127) ----------------
// Write-once rotating state slots: sc1 writes, plain cached reads (addresses never
// read before their unique write; deterministic across replays).
template <int ROLE>
__device__ __forceinline__ void run_phases(
    int jb, const _Float16* __restrict__ Pk,
    const float* __restrict__ gx, const float* __restrict__ x_f,
    float* __restrict__ c_f,
    _Float16* __restrict__ h0S, _Float16* __restrict__ h1S,
    float* __restrict__ ipfA, float* __restrict__ ipfB,
    float* __restrict__ outs_f, _Float16* __restrict__ outs_h,
    float* __restrict__ outHT, float* __restrict__ outCT,
    int* bar, _Float16* As) {
  constexpr int S = ROLE ? 8 : 4;
  constexpr int NHALF = ROLE ? 2 : 1;
  constexpr int RSH = ROLE ? 8 : 7;
  constexpr int K8M = ROLE ? 255 : 127;
  const int u0 = jb * 16;
  const int tid = threadIdx.x;
  const int lane = tid & 63;
  const int kh = tid >> 6;
  const int col = lane & 15;
  const int kslot = lane >> 4;

  float* cst = c_f + ROLE * 32768;
  const float* gxbase = gx + (ROLE ? 4096 : 0);
  const int cb = tid >> 4, cul = tid & 15, cu = u0 + cul;

  const _Float16* pkbase = Pk + ((size_t)(jb * 8 + kh) * S) * 4 * 512 + lane * 8;
  const int a0off = col * 2056 + kh * S * 32 + kslot * 8;
  const int a1off = a0off + 16 * 2056;

  // weights pinned in registers for the whole recurrence
  f16x8 wreg[S * 4];
#pragma unroll
  for (int i = 0; i < S * 4; ++i) wreg[i] = *(const f16x8*)(pkbase + i * 512);

  for (int p = 0; p <= 64; ++p) {
    const bool active = (ROLE == 0) ? (p < 64) : (p > 0);
    if (active) {
      const int t = (ROLE == 0) ? p : p - 1;
      const _Float16* h0r = h0S + (size_t)p * 32768;
      _Float16* h0w = h0S + (size_t)(p + 1) * 32768;
      const _Float16* h1r = h1S + (size_t)(p - 1) * 32768;
      _Float16* h1w = h1S + (size_t)p * 32768;
      const float* ipfr; float* ipfw;
      if (p & 1) { ipfr = ipfA; ipfw = ipfB; }
      else       { ipfr = ipfB; ipfw = ipfA; }

      const float* gxr = gxbase + (size_t)(t * 32 + cb) * 8192;
      float pg0 = gxr[cu], pg1 = gxr[1024 + cu], pg2 = gxr[2048 + cu], pg3 = gxr[3072 + cu];
      float pc = cst[cb * 1024 + cu];
      float px = 0.f, pip = 0.f;
      if (ROLE == 0) px = x_f[(size_t)(t * 32 + cb) * 1024 + cu];
      else           pip = ALOAD(ipfr + cb * 1024 + cu);

      // ---- state -> LDS (plain cached loads; write-once-fresh addresses) ----
#pragma unroll
      for (int hf = 0; hf < NHALF; ++hf) {
        f16x8 sreg[8];
#pragma unroll
        for (int i = 0; i < 8; ++i) {
          int fr = (hf * 8 + i) * 512 + tid;
          int row = fr >> RSH, k8 = fr & K8M;
          const _Float16* s;
          if (ROLE == 0) s = h0r + row * 1024 + k8 * 8;
          else           s = (k8 < 128) ? (h0r + row * 1024 + k8 * 8)
                                        : (h1r + row * 1024 + (k8 - 128) * 8);
          sreg[i] = *(const f16x8*)s;
        }
#pragma unroll
        for (int i = 0; i < 8; ++i) {
          int fr = (hf * 8 + i) * 512 + tid;
          int row = fr >> RSH, k8 = fr & K8M;
          *(f16x8*)(As + row * 2056 + k8 * 8) = sreg[i];
        }
      }
      __syncthreads();

      f32x4 acc[2][4] = {};
#pragma unroll
      for (int s2 = 0; s2 < S; ++s2) {
        f16x8 a0 = *(const f16x8*)(As + a0off + s2 * 32);
        f16x8 a1 = *(const f16x8*)(As + a1off + s2 * 32);
        acc[0][0] = __builtin_amdgcn_mfma_f32_16x16x32_f16(a0, wreg[s2 * 4 + 0], acc[0][0], 0, 0, 0);
        acc[1][0] = __builtin_amdgcn_mfma_f32_16x16x32_f16(a1, wreg[s2 * 4 + 0], acc[1][0], 0, 0, 0);
        acc[0][1] = __builtin_amdgcn_mfma_f32_16x16x32_f16(a0, wreg[s2 * 4 + 1], acc[0][1], 0, 0, 0);
        acc[1][1] = __builtin_amdgcn_mfma_f32_16x16x32_f16(a1, wreg[s2 * 4 + 1], acc[1][1], 0, 0, 0);
        acc[0][2] = __builtin_amdgcn_mfma_f32_16x16x32_f16(a0, wreg[s2 * 4 + 2], acc[0][2], 0, 0, 0);
        acc[1][2] = __builtin_amdgcn_mfma_f32_16x16x32_f16(a1, wreg[s2 * 4 + 2], acc[1][2], 0, 0, 0);
        acc[0][3] = __builtin_amdgcn_mfma_f32_16x16x32_f16(a0, wreg[s2 * 4 + 3], acc[0][3], 0, 0, 0);
        acc[1][3] = __builtin_amdgcn_mfma_f32_16x16x32_f16(a1, wreg[s2 * 4 + 3], acc[1][3], 0, 0, 0);
      }
      __syncthreads();

      float (*gs)[32][68] = (float (*)[32][68])(void*)As;
      const int rl = kslot * 4;
      if (kh < 4) {
#pragma unroll
        for (int m = 0; m < 2; ++m)
#pragma unroll
          for (int g = 0; g < 4; ++g)
#pragma unroll
            for (int j = 0; j < 4; ++j)
              gs[kh][m * 16 + rl + j][g * 16 + col] = acc[m][g][j];
      }
      __syncthreads();
      if (kh >= 4) {
#pragma unroll
        for (int m = 0; m < 2; ++m)
#pragma unroll
          for (int g = 0; g < 4; ++g)
#pragma unroll
            for (int j = 0; j < 4; ++j)
              gs[kh - 4][m * 16 + rl + j][g * 16 + col] += acc[m][g][j];
      }
      __syncthreads();

      {
        float ig = pg0, fg = pg1, gg = pg2, og = pg3;
#pragma unroll
        for (int cc = 0; cc < 4; ++cc) {
          ig += gs[cc][cb][cul];
          fg += gs[cc][cb][16 + cul];
          gg += gs[cc][cb][32 + cul];
          og += gs[cc][cb][48 + cul];
        }
        float si = 1.f / (1.f + expf(-ig));
        float sf = 1.f / (1.f + expf(-fg));
        float so = 1.f / (1.f + expf(-og));
        float ci = sf * pc + si * tanhf(gg);
        float hi = so * tanhf(ci);
        cst[cb * 1024 + cu] = ci;
        if (t == 63) {
          outHT[ROLE * 32768 + cb * 1024 + cu] = hi;
          outCT[ROLE * 32768 + cb * 1024 + cu] = ci;
        }
        if (ROLE == 0) {
          float hn = __shfl_down(hi, 1);
          float ipv = hi + px;
          float ipn = __shfl_down(ipv, 1);
          if ((cul & 1) == 0) {
            union { _Float16 h[2]; u32 v; } ph;
            ph.h[0] = (_Float16)hi; ph.h[1] = (_Float16)hn;
            ASTORE((u32*)(h0w + cb * 1024 + cu), ph.v);
            union { float f[2]; u64 v; } pi;
            pi.f[0] = ipv; pi.f[1] = ipn;
            ASTORE((u64*)(ipfw + cb * 1024 + cu), pi.v);
          }
        } else {
          float hn = __shfl_down(hi, 1);
          float ro = hi + pip;
          float rn = __shfl_down(ro, 1);
          if ((cul & 1) == 0) {
            union { _Float16 h[2]; u32 v; } ph;
            ph.h[0] = (_Float16)hi; ph.h[1] = (_Float16)hn;
            ASTORE((u32*)(h1w + cb * 1024 + cu), ph.v);
            union { _Float16 h[2]; u32 v; } po;
            po.h[0] = (_Float16)ro; po.h[1] = (_Float16)rn;
            ASTORE((u32*)(outs_h + (size_t)(t * 32 + cb) * 1024 + cu), po.v);
          }
          outs_f[(size_t)(t * 32 + cb) * 1024 + cu] = ro;
        }
      }
    }
    gbar(bar);  // every phase, incl. last -> gen ends at 65
  }
}

// ---------------- clsW f32->f16 conversion by consumer blocks ----------------
__device__ __forceinline__ void conv_clsW(const float* __restrict__ src,
                                          _Float16* __restrict__ dst, int cb) {
  for (int i = cb * 512 + threadIdx.x; i < 4096000; i += 65536) {
    const f32x4* s = (const f32x4*)(src + (size_t)i * 8);
    f32x4 v0 = __builtin_nontemporal_load(s);
    f32x4 v1 = __builtin_nontemporal_load(s + 1);
    union { _Float16 h[8]; u64 q[2]; } o;
    o.h[0] = (_Float16)v0.x; o.h[1] = (_Float16)v0.y;
    o.h[2] = (_Float16)v0.z; o.h[3] = (_Float16)v0.w;
    o.h[4] = (_Float16)v1.x; o.h[5] = (_Float16)v1.y;
    o.h[6] = (_Float16)v1.z; o.h[7] = (_Float16)v1.w;
    u64* d = (u64*)(dst + (size_t)i * 8);
    ASTORE(d, o.q[0]);
    ASTORE(d + 1, o.q[1]);
  }
}

// ---------------- logits GEMM consumer: 256x256 tiles, dynamic work-steal ----------------
__device__ __forceinline__ void run_consumer(
    const _Float16* __restrict__ outs_h, const _Float16* __restrict__ clsW_h,
    const float* __restrict__ cls_b, float* __restrict__ out, int* bar, _Float16* lds) {
  __shared__ int tau_s;
  const int tid = threadIdx.x;
  const int lane = tid & 63;
  const int w = tid >> 6;
  const int wm = w >> 2, wn = w & 3;      // 2x4 wave grid; wave tile 128x64
  int* gen = bar + 544;
  int* wcnt = bar + 576;
  const int r0 = tid & 255, kb0 = tid >> 8;

  if (tid == 0) {
    while (ALOAD(bar + 608) < 128) __builtin_amdgcn_s_sleep(16);
  }
  __syncthreads();

  for (;;) {
    if (tid == 0) tau_s = __hip_atomic_fetch_add(wcnt, 1, __ATOMIC_RELAXED, __HIP_MEMORY_SCOPE_AGENT);
    __syncthreads();
    int tau = tau_s;
    if (tau >= 1000) break;
    int m = tau / 125, nt = tau - m * 125;
    if (tid == 0) {
      int need = 8 * m + 9; if (need > 65) need = 65;
      while (ALOAD(gen) < need) __builtin_amdgcn_s_sleep(64);
    }
    __syncthreads();

    const _Float16* Ab = outs_h + (size_t)m * 256 * 1024;
    const _Float16* Bb = clsW_h + (size_t)nt * 256 * 1024;
    f16x8 pa0, pa1, pb0, pb1;
    pa0 = *(const f16x8*)(Ab + r0 * 1024 + kb0 * 8);
    pa1 = *(const f16x8*)(Ab + r0 * 1024 + (kb0 + 2) * 8);
    pb0 = *(const f16x8*)(Bb + r0 * 1024 + kb0 * 8);
    pb1 = *(const f16x8*)(Bb + r0 * 1024 + (kb0 + 2) * 8);
    f32x4 acc[8][4] = {};
    for (int kc = 0; kc < 32; ++kc) {
      _Float16* Ac = lds + (kc & 1) * 8192;
      _Float16* Bc = lds + 16384 + (kc & 1) * 8192;
      *(f16x8*)(Ac + kb0 * 2048 + r0 * 8) = pa0;
      *(f16x8*)(Ac + (kb0 + 2) * 2048 + r0 * 8) = pa1;
      *(f16x8*)(Bc + kb0 * 2048 + r0 * 8) = pb0;
      *(f16x8*)(Bc + (kb0 + 2) * 2048 + r0 * 8) = pb1;
      if (kc + 1 < 32) {
        int ko = (kc + 1) * 32;
        pa0 = *(const f16x8*)(Ab + r0 * 1024 + ko + kb0 * 8);
        pa1 = *(const f16x8*)(Ab + r0 * 1024 + ko + (kb0 + 2) * 8);
        pb0 = *(const f16x8*)(Bb + r0 * 1024 + ko + kb0 * 8);
        pb1 = *(const f16x8*)(Bb + r0 * 1024 + ko + (kb0 + 2) * 8);
      }
      __syncthreads();
      const int kb = lane >> 4;
      f16x8 af[8], bf[4];
#pragma unroll
      for (int mf = 0; mf < 8; ++mf) {
        int row = wm * 128 + mf * 16 + (lane & 15);
        af[mf] = *(const f16x8*)(Ac + kb * 2048 + row * 8);
      }
#pragma unroll
      for (int nf = 0; nf < 4; ++nf) {
        int row = wn * 64 + nf * 16 + (lane & 15);
        bf[nf] = *(const f16x8*)(Bc + kb * 2048 + row * 8);
      }
#pragma unroll
      for (int mf = 0; mf < 8; ++mf)
#pragma unroll
        for (int nf = 0; nf < 4; ++nf)
          acc[mf][nf] = __builtin_amdgcn_mfma_f32_16x16x32_f16(af[mf], bf[nf], acc[mf][nf], 0, 0, 0);
    }
    const int rl = (lane >> 4) * 4;
#pragma unroll
    for (int mf = 0; mf < 8; ++mf) {
#pragma unroll
      for (int nf = 0; nf < 4; ++nf) {
#pragma unroll
        for (int j = 0; j < 4; ++j) {
          int rg = m * 256 + wm * 128 + mf * 16 + rl + j;
          int tt = rg >> 5, b = rg & 31;
          int ng = nt * 256 + wn * 64 + nf * 16 + (lane & 15);
          __builtin_nontemporal_store(acc[mf][nf][j] + cls_b[ng],
                                      &out[(size_t)(b * 64 + tt) * 32000 + ng]);
        }
      }
    }
  }
}

__global__ __launch_bounds__(512, 1) void k_lstm_fused(
    const _Float16* __restrict__ Pk0, const _Float16* __restrict__ Pk1,
    const float* __restrict__ gx, const float* __restrict__ x_f,
    float* __restrict__ c_f,
    _Float16* __restrict__ h0S, _Float16* __restrict__ h1S,
    float* __restrict__ ipfA, float* __restrict__ ipfB,
    float* __restrict__ outs_f, _Float16* __restrict__ outs_h,
    const float* __restrict__ cls_W, _Float16* __restrict__ clsW_h,
    const float* __restrict__ cls_b,
    float* __restrict__ out_logits,
    float* __restrict__ outHT, float* __restrict__ outCT,
    int* bar) {
  __shared__ _Float16 As[32 * 2056];  // 131,584 B (1 block/CU -> 256 blocks co-resident)
  const int bid = blockIdx.x;
  if (bid < 64) {
    run_phases<0>(bid & 63, Pk0, gx, x_f, c_f, h0S, h1S,
                  ipfA, ipfB, outs_f, outs_h, outHT, outCT, bar, As);
  } else if (bid < 128) {
    run_phases<1>(bid & 63, Pk1, gx, x_f, c_f, h0S, h1S,
                  ipfA, ipfB, outs_f, outs_h, outHT, outCT, bar, As);
  } else {
    conv_clsW(cls_W, clsW_h, bid - 128);
    __syncthreads();
    if (threadIdx.x == 0)
      __hip_atomic_fetch_add(bar + 608, 1, __ATOMIC_RELAXED, __HIP_MEMORY_SCOPE_AGENT);
  }
  run_consumer(outs_h, clsW_h, cls_b, out_logits, bar, As);
}

// ---------------- batched dot-attention + softmax ----------------
__global__ __launch_bounds__(256) void k_attn(const float* __restrict__ outs,
                                              const float* __restrict__ enc,
                                              float* __restrict__ att) {
  __shared__ float o_s[8][1024];
  __shared__ float sc[8][128];
  const int tid = threadIdx.x;
  const int lane = tid & 63;
  const int w = tid >> 6;
  const int b = blockIdx.x >> 3;
  const int t0 = (blockIdx.x & 7) * 8;
#pragma unroll
  for (int ii = 0; ii < 8; ++ii) {
    int idx = tid + ii * 256;
    int tt = idx >> 8, c4 = idx & 255;
    ((float4*)&o_s[tt][0])[c4] =
        *(const float4*)(outs + (size_t)((t0 + tt) * 32 + b) * 1024 + (size_t)c4 * 4);
  }
  __syncthreads();
  for (int si = 0; si < 32; ++si) {
    int s = w * 32 + si;
    float av[8] = {0, 0, 0, 0, 0, 0, 0, 0};
    const float* er = enc + (size_t)(b * 128 + s) * 1024;
#pragma unroll
    for (int i = 0; i < 4; ++i) {
      int k = i * 256 + lane * 4;
      float4 e = *(const float4*)(er + k);
#pragma unroll
      for (int tt = 0; tt < 8; ++tt) {
        float4 o = *(const float4*)&o_s[tt][k];
        av[tt] += e.x * o.x + e.y * o.y + e.z * o.z + e.w * o.w;
      }
    }
#pragma unroll
    for (int tt = 0; tt < 8; ++tt) {
      float v = av[tt];
#pragma unroll
      for (int off = 32; off > 0; off >>= 1) v += __shfl_down(v, off);
      if (lane == 0) sc[tt][s] = v;
    }
  }
  __syncthreads();
#pragma unroll
  for (int pp = 0; pp < 2; ++pp) {
    int tt = w + pp * 4;
    float a = sc[tt][lane], b2 = sc[tt][64 + lane];
    float m = fmaxf(a, b2);
#pragma unroll
    for (int off = 32; off > 0; off >>= 1) m = fmaxf(m, __shfl_xor(m, off));
    float e0 = expf(a - m), e1 = expf(b2 - m);
    float ss = e0 + e1;
#pragma unroll
    for (int off = 32; off > 0; off >>= 1) ss += __shfl_xor(ss, off);
    float r = 1.f / ss;
    att[(size_t)b * 8192 + (size_t)lane * 64 + t0 + tt] = e0 * r;
    att[(size_t)b * 8192 + (size_t)(64 + lane) * 64 + t0 + tt] = e1 * r;
  }
}

extern "C" void kernel_launch(void* const* d_in, const int* in_sizes, int n_in,
                              void* d_out, int out_size, void* d_ws, size_t ws_size,
                              hipStream_t stream) {
  const int*   dec   = (const int*)d_in[0];
  const float* h0    = (const float*)d_in[1];
  const float* c0    = (const float*)d_in[2];
  const float* enc   = (const float*)d_in[3];
  const float* emb   = (const float*)d_in[4];
  const float* W_ih  = (const float*)d_in[5];
  const float* W_hh  = (const float*)d_in[6];
  const float* b_ih  = (const float*)d_in[7];
  const float* b_hh  = (const float*)d_in[8];
  const float* cls_W = (const float*)d_in[9];
  const float* cls_b = (const float*)d_in[10];
  float* out = (float*)d_out;
  char* ws = (char*)d_ws;

  float*    x_f    = (float*)(ws + 0);                // [2048][1024] f32, ends 8388608
  _Float16* Pk0    = (_Float16*)(ws + 8388608);       // 8MB packed Whh0, ends 16777216
  _Float16* h0S    = (_Float16*)(ws + 16777216);      // 65 slots, ends 21037056
  _Float16* h1S    = (_Float16*)(ws + 21037056);      // 65 slots, ends 25296896
  _Float16* Pk1    = (_Float16*)(ws + 29360128);      // 16MB, ends 46137344
  _Float16* clsW_h = (_Float16*)(ws + 46137344);      // 65.5MB, ends 111673344 (filled in-kernel)
  _Float16* Wih_h  = (_Float16*)(ws + 54657024);      // 16.7MB inside clsW_h, ends 71434240
  _Float16* x_h    = (_Float16*)(ws + 71434240);      // 4MB inside clsW_h, ends 75628544
                                                      // (Wih_h/x_h dead after k_gemm0b; conv_clsW
                                                      //  overwrites them during fused — consumers
                                                      //  read clsW_h only after bar[608]==128)
  float*    gx     = (float*)(ws + 111673344);        // [2048][8192] f32, ends 178782208
  float*    outs_f = (float*)(ws + 178782208);        // 8MB, ends 187170816
  _Float16* outs_h = (_Float16*)(ws + 187170816);     // 4MB, ends 191365120
  float*    c_f    = (float*)(ws + 191627264);        // [2][32][1024] f32
  int*      bar    = (int*)(ws + 192151552);          // 640 ints
  float*    ipfA   = (float*)(ws + 192155648);        // [32][1024] f32
  float*    ipfB   = (float*)(ws + 192286720);        // end 192417792

  k_prep<<<10496, 256, 0, stream>>>(W_ih, Wih_h, dec, emb, x_f, x_h,
                                    W_hh, Pk0, Pk1, h0, c0, c_f, h0S, h1S, bar);
  k_gemm0b<<<dim3(32, 8), 512, 0, stream>>>(x_h, Wih_h, b_ih, b_hh, gx);

  k_lstm_fused<<<256, 512, 0, stream>>>(Pk0, Pk1, gx, x_f, c_f,
                                        h0S, h1S, ipfA, ipfB,
                                        outs_f, outs_h, cls_W, clsW_h, cls_b, out,
                                        out + (size_t)65536000, out + (size_t)65601536,
                                        bar);

  k_attn<<<256, 256, 0, stream>>>(outs_f, enc, out + (size_t)65667072);
}